// Round 3
// baseline (1429.689 us; speedup 1.0000x reference)
//
#include <hip/hip_runtime.h>
#include <stdint.h>

typedef __bf16 bf16x8 __attribute__((ext_vector_type(8)));
typedef float f32x4 __attribute__((ext_vector_type(4)));

__device__ __forceinline__ float b2f(uint32_t u) {
  union { uint32_t i; float f; } v; v.i = u << 16; return v.f;
}
__device__ __forceinline__ uint16_t f2b(float f) {
  union { float f; uint32_t i; } v; v.f = f;
  uint32_t r = (v.i + 0x7fffu + ((v.i >> 16) & 1u)) >> 16;
  return (uint16_t)r;
}
__device__ __forceinline__ void unpack8(uint4 u, float* f) {
  f[0] = b2f(u.x & 0xffffu); f[1] = b2f(u.x >> 16);
  f[2] = b2f(u.y & 0xffffu); f[3] = b2f(u.y >> 16);
  f[4] = b2f(u.z & 0xffffu); f[5] = b2f(u.z >> 16);
  f[6] = b2f(u.w & 0xffffu); f[7] = b2f(u.w >> 16);
}

__device__ __forceinline__ void gl2lds16(const void* g, void* l) {
  __builtin_amdgcn_global_load_lds(
      (const __attribute__((address_space(1))) void*)g,
      (__attribute__((address_space(3))) void*)l, 16, 0, 0);
}

// ================= 256x256 pipelined 8-phase bf16 GEMM: C = A(MxK,lda)*Bt(NxK)^T =========
// M=8192 (32 m-tiles). 512 threads = 8 waves (2M x 4N), BK=64, 128 KiB LDS, 1 block/CU.
// Per K-tile: 4 phases (kk,qm); frag ds_reads are issued ONE PHASE AHEAD (double-buffered
// aA/aB, bA/bB) so the compiler's counted lgkmcnt lets reads complete under the MFMA
// cluster. ONE raw s_barrier per phase. Staging via global_load_lds with counted vmcnt:
//   p1: stage B1 -> nxt buf    p2: stage A-H1 -> nxt buf
//   p3: stage B0(t+2) -> cur   p4: vmcnt(2)+bar, pre-read next tile frags, stage A-H0(t+2)
// Write-after-read safety: every restaged region's last read completes >=2 barriers
// before the restage issue (reads are lgkm-waited before the intervening MFMA).
// mode 0: outb[r*N+c] = bf16(acc + bias[c])
// mode 1: outf[r*N+c] = resid[r*N+c] + gate[(r>>12)*10368 + c] * (acc + bias[c])
__global__ __launch_bounds__(512, 2) void gemm256_k(
    const uint16_t* __restrict__ A, int lda,
    const uint16_t* __restrict__ Bt,
    const float* __restrict__ bias,
    uint16_t* __restrict__ outb,
    float* __restrict__ outf, const float* __restrict__ resid,
    const float* __restrict__ gate,
    int N, int K, int mode)
{
  __shared__ __align__(16) uint16_t L[65536];  // 2 bufs x {A 16384, B0 8192, B1 8192} elems
  const int tid = threadIdx.x;
  const int lane = tid & 63, wave = tid >> 6;
  const int l15 = lane & 15, quad = lane >> 4;
  const int wm = (wave >> 2) * 128, wn = (wave & 3) * 64;

  const int xcd = blockIdx.x & 7;
  const int slot = blockIdx.x >> 3;
  const int mt = xcd * 4 + (slot & 3);
  const int nt = slot >> 2;
  const int row0 = mt * 256, col0 = nt * 256;

  const int NTk = K >> 6;

  const uint16_t* Ag = A + (size_t)row0 * lda;
  const uint16_t* Bg = Bt + (size_t)col0 * K;

  // staging lane constants (linear LDS dest; inverse-swizzled global source)
  const int sX = (lane & 7) ^ (lane >> 3);
  const int laneRowA = lane >> 3;
  const int laneK8A = sX * 8;
  const int laneRowB = 2 * (lane >> 3) + ((sX >> 2) & 1);
  const int laneK8B = (sX & 3) * 8;
  const int rA0 = ((wave * 16) & 63) + (((wave * 16) >> 6) << 7);
  const int rB0 = wave * 32;

#define STAGE_A(BUF, SUB, KT) do { \
    const uint16_t* g_ = Ag + (size_t)(rA0 + (SUB) * 64 + laneRowA) * lda + (size_t)(KT) * 64 + laneK8A; \
    uint16_t* l_ = (uint16_t*)&L[(BUF) * 32768 + (rA0 + (SUB) * 64) * 64]; \
    gl2lds16(g_, l_); \
    gl2lds16(g_ + (size_t)8 * lda, l_ + 512); \
  } while (0)

#define STAGE_B(BUF, HALF, KT) do { \
    const uint16_t* g_ = Bg + (size_t)(rB0 + laneRowB) * K + (size_t)(KT) * 64 + (HALF) * 32 + laneK8B; \
    uint16_t* l_ = (uint16_t*)&L[(BUF) * 32768 + 16384 + (HALF) * 8192 + rB0 * 32]; \
    gl2lds16(g_, l_); \
    gl2lds16(g_ + (size_t)16 * K, l_ + 512); \
  } while (0)

  f32x4 acc[8][4];
#pragma unroll
  for (int i = 0; i < 8; i++)
#pragma unroll
    for (int j = 0; j < 4; j++)
      acc[i][j] = (f32x4){0.f, 0.f, 0.f, 0.f};

  bf16x8 aA[4], aB[4], bA[4], bB[4];

#define READ_A(BUF, DST, QM, KK) do { \
    _Pragma("unroll") for (int mi = 0; mi < 4; mi++) \
      DST[mi] = *(const bf16x8*)&L[(BUF) * 32768 + (wm + (QM) * 64 + mi * 16 + l15) * 64 + \
                                   ((((KK) * 4 + quad) ^ (l15 & 7)) * 8)]; \
  } while (0)

#define READ_B(BUF, DST, KK) do { \
    _Pragma("unroll") for (int ni = 0; ni < 4; ni++) \
      DST[ni] = *(const bf16x8*)&L[(BUF) * 32768 + 16384 + (KK) * 8192 + \
                                   ((wn >> 1) + ni * 8 + (l15 >> 1)) * 64 + \
                                   ((((((l15 & 1) << 2) | quad)) ^ (l15 >> 1)) * 8)]; \
  } while (0)

#define MFMA16(QM, AF, BF) do { \
    __builtin_amdgcn_s_setprio(1); \
    _Pragma("unroll") for (int mi = 0; mi < 4; mi++) \
      _Pragma("unroll") for (int ni = 0; ni < 4; ni++) \
        acc[(QM) * 4 + mi][ni] = __builtin_amdgcn_mfma_f32_16x16x32_bf16( \
            AF[mi], BF[ni], acc[(QM) * 4 + mi][ni], 0, 0, 0); \
    __builtin_amdgcn_s_setprio(0); \
  } while (0)

#define SB __builtin_amdgcn_sched_barrier(0)
#define BAR __builtin_amdgcn_s_barrier()

#define TILE(CUR, T) do { \
    /* p1: (kk0,qm0) use aA,bA; pre-read p2 frags */ \
    READ_A(CUR, aB, 1, 0); SB; \
    MFMA16(0, aA, bA); \
    if ((T) + 1 < NTk) STAGE_B((CUR) ^ 1, 1, (T) + 1); \
    SB; BAR; SB; \
    /* p2: (kk0,qm1) use aB,bA; pre-read p3 frags */ \
    READ_A(CUR, aA, 0, 1); READ_B(CUR, bB, 1); SB; \
    MFMA16(1, aB, bA); \
    if ((T) + 1 < NTk) STAGE_A((CUR) ^ 1, 1, (T) + 1); \
    SB; BAR; SB; \
    /* p3: (kk1,qm0) use aA,bB; pre-read p4 frags */ \
    READ_A(CUR, aB, 1, 1); SB; \
    MFMA16(0, aA, bB); \
    if ((T) + 2 < NTk) STAGE_B((CUR), 0, (T) + 2); \
    SB; BAR; SB; \
    /* p4: (kk1,qm1) use aB,bB; drain next-tile buf, pre-read its p1 frags */ \
    if ((T) + 2 < NTk) { asm volatile("s_waitcnt vmcnt(2)" ::: "memory"); } \
    else               { asm volatile("s_waitcnt vmcnt(0)" ::: "memory"); } \
    SB; BAR; SB; \
    READ_A((CUR) ^ 1, aA, 0, 0); READ_B((CUR) ^ 1, bA, 0); SB; \
    MFMA16(1, aB, bB); \
    if ((T) + 2 < NTk) STAGE_A((CUR), 0, (T) + 2); \
    SB; BAR; SB; \
  } while (0)

  // prologue: tile0 fully + tile1 {A-H0, B0}; drain tile0, pre-read its p1 frags
  STAGE_A(0, 0, 0); STAGE_A(0, 1, 0); STAGE_B(0, 0, 0); STAGE_B(0, 1, 0);
  STAGE_A(1, 0, 1); STAGE_B(1, 0, 1);
  asm volatile("s_waitcnt vmcnt(4)" ::: "memory");
  SB; BAR; SB;
  READ_A(0, aA, 0, 0); READ_B(0, bA, 0); SB;

  for (int t = 0; t < NTk; t += 2) {
    TILE(0, t);
    TILE(1, t + 1);
  }

#undef TILE
#undef READ_A
#undef READ_B
#undef MFMA16
#undef STAGE_A
#undef STAGE_B
#undef SB
#undef BAR

  // epilogue
#pragma unroll
  for (int mi = 0; mi < 8; mi++) {
#pragma unroll
    for (int ni = 0; ni < 4; ni++) {
      const int colg = col0 + wn + ni * 16 + l15;
      if (colg < N) {
        const float bv = bias ? bias[colg] : 0.f;
#pragma unroll
        for (int i = 0; i < 4; i++) {
          const int rowg = row0 + wm + mi * 16 + quad * 4 + i;
          const float v = acc[mi][ni][i] + bv;
          const size_t idx = (size_t)rowg * N + colg;
          if (mode == 0) {
            outb[idx] = f2b(v);
          } else {
            const int b = rowg >> 12;  // T*L = 4096 rows per batch
            outf[idx] = resid[idx] + gate[b * 10368 + colg] * v;
          }
        }
      }
    }
  }
}

// ---------------- RMS + adaLN modulate ----------------
__global__ __launch_bounds__(256) void rmsnorm_k(
    const float* __restrict__ x, const float* __restrict__ w,
    const float* __restrict__ chv, int shsel, int scsel,
    uint16_t* __restrict__ xn)
{
  const int row = blockIdx.x;
  const int b = row >> 12;
  const float* xr = x + (size_t)row * 1152;
  float ss = 0.f;
  for (int d = threadIdx.x; d < 1152; d += 256) { const float v = xr[d]; ss += v * v; }
  for (int off = 32; off > 0; off >>= 1) ss += __shfl_down(ss, off);
  __shared__ float red[4];
  if ((threadIdx.x & 63) == 0) red[threadIdx.x >> 6] = ss;
  __syncthreads();
  const float tot = red[0] + red[1] + red[2] + red[3];
  const float rs = rsqrtf(tot * (1.f / 1152.f) + 1e-6f);
  const float* sh = chv + b * 10368 + shsel * 1152;
  const float* sc = chv + b * 10368 + scsel * 1152;
  uint16_t* xo = xn + (size_t)row * 1152;
  for (int d = threadIdx.x; d < 1152; d += 256)
    xo[d] = f2b(xr[d] * rs * w[d] * (1.f + sc[d]) + sh[d]);
}

// ---------------- per-head RMS norm of q,k in qkv (in place) ----------------
__global__ __launch_bounds__(256) void qknorm_k(
    uint16_t* __restrict__ qkv, const float* __restrict__ qn, const float* __restrict__ kn)
{
  const int tid = threadIdx.x;
  const int rl = tid >> 5, unit = tid & 31;
  const int h = unit & 15, isK = unit >> 4;
  const size_t row = (size_t)blockIdx.x * 8 + rl;
  uint16_t* p = qkv + row * 3456 + isK * 1152 + h * 72;
  const float* w = isK ? kn : qn;
  float v[72];
#pragma unroll
  for (int i = 0; i < 9; i++) unpack8(((const uint4*)p)[i], v + i * 8);
  float ss = 0.f;
#pragma unroll
  for (int d = 0; d < 72; d++) ss += v[d] * v[d];
  const float rs = rsqrtf(ss * (1.f / 72.f) + 1e-6f);
#pragma unroll
  for (int d = 0; d < 72; d++) p[d] = f2b(v[d] * rs * w[d]);
}

// ---------------- spatial attention, MFMA flash: block=(bt,h), 4 waves x 64 queries ----------------
#define AK_STRIDE 104
#define VT_STRIDE 88
#define PS_STRIDE 72
__global__ __launch_bounds__(256) void attn_s_k(
    const uint16_t* __restrict__ qkv, uint16_t* __restrict__ out)
{
  __shared__ __align__(16) uint16_t Ks[64 * AK_STRIDE];
  __shared__ __align__(16) uint16_t Vt[80 * VT_STRIDE];
  __shared__ __align__(16) uint16_t Ps[4 * 64 * PS_STRIDE];
  const int bh = blockIdx.x;
  const int bt = bh >> 4, h = bh & 15;
  const int tid = threadIdx.x;
  const int lane = tid & 63, wave = tid >> 6;
  const int l15 = lane & 15, quad = lane >> 4;
  const size_t rowbase = (size_t)bt * 256;
  const float scale = 0.1178511301977579f;  // 1/sqrt(72)

  union { uint4 u; bf16x8 v; } zu; zu.u = make_uint4(0, 0, 0, 0);
  const bf16x8 zero8 = zu.v;

  bf16x8 qf[4][3];
#pragma unroll
  for (int mi = 0; mi < 4; mi++) {
    const uint16_t* qp = qkv + (rowbase + wave * 64 + mi * 16 + l15) * 3456 + h * 72;
    qf[mi][0] = *(const bf16x8*)(qp + quad * 8);
    qf[mi][1] = *(const bf16x8*)(qp + 32 + quad * 8);
    qf[mi][2] = (quad == 0) ? *(const bf16x8*)(qp + 64) : zero8;
  }

  f32x4 oacc[4][5];
#pragma unroll
  for (int mi = 0; mi < 4; mi++)
#pragma unroll
    for (int dt = 0; dt < 5; dt++)
      oacc[mi][dt] = (f32x4){0.f, 0.f, 0.f, 0.f};
  float mrun[4][4], lrun[4][4];
#pragma unroll
  for (int mi = 0; mi < 4; mi++)
#pragma unroll
    for (int i = 0; i < 4; i++) { mrun[mi][i] = -1e30f; lrun[mi][i] = 0.f; }

  uint16_t* psw = &Ps[wave * 64 * PS_STRIDE];

  for (int c = 0; c < 4; c++) {
    __syncthreads();
    for (int idx = tid; idx < 576; idx += 256) {
      const int rr = idx / 9, cc = idx - rr * 9;
      const uint16_t* kg = qkv + (rowbase + c * 64 + rr) * 3456 + 1152 + h * 72 + cc * 8;
      *(uint4*)&Ks[rr * AK_STRIDE + cc * 8] = *(const uint4*)kg;
      uint4 vv = *(const uint4*)(kg + 1152);
      const uint16_t* e = (const uint16_t*)&vv;
#pragma unroll
      for (int j = 0; j < 8; j++) Vt[(cc * 8 + j) * VT_STRIDE + rr] = e[j];
    }
    __syncthreads();

    f32x4 s[4][4];
#pragma unroll
    for (int mi = 0; mi < 4; mi++)
#pragma unroll
      for (int ni = 0; ni < 4; ni++)
        s[mi][ni] = (f32x4){0.f, 0.f, 0.f, 0.f};
#pragma unroll
    for (int ni = 0; ni < 4; ni++) {
      bf16x8 kf0 = *(const bf16x8*)&Ks[(ni * 16 + l15) * AK_STRIDE + quad * 8];
      bf16x8 kf1 = *(const bf16x8*)&Ks[(ni * 16 + l15) * AK_STRIDE + 32 + quad * 8];
      bf16x8 kf2 = (quad == 0) ? *(const bf16x8*)&Ks[(ni * 16 + l15) * AK_STRIDE + 64] : zero8;
#pragma unroll
      for (int mi = 0; mi < 4; mi++) {
        s[mi][ni] = __builtin_amdgcn_mfma_f32_16x16x32_bf16(qf[mi][0], kf0, s[mi][ni], 0, 0, 0);
        s[mi][ni] = __builtin_amdgcn_mfma_f32_16x16x32_bf16(qf[mi][1], kf1, s[mi][ni], 0, 0, 0);
        s[mi][ni] = __builtin_amdgcn_mfma_f32_16x16x32_bf16(qf[mi][2], kf2, s[mi][ni], 0, 0, 0);
      }
    }

#pragma unroll
    for (int mi = 0; mi < 4; mi++) {
#pragma unroll
      for (int i = 0; i < 4; i++) {
        float mx = fmaxf(fmaxf(s[mi][0][i], s[mi][1][i]), fmaxf(s[mi][2][i], s[mi][3][i])) * scale;
#pragma unroll
        for (int d = 1; d < 16; d <<= 1) mx = fmaxf(mx, __shfl_xor(mx, d));
        const float mnew = fmaxf(mrun[mi][i], mx);
        const float corr = __expf(mrun[mi][i] - mnew);
        mrun[mi][i] = mnew;
        float psum = 0.f;
#pragma unroll
        for (int ni = 0; ni < 4; ni++) {
          const float p = __expf(s[mi][ni][i] * scale - mnew);
          s[mi][ni][i] = p;
          psum += p;
        }
#pragma unroll
        for (int d = 1; d < 16; d <<= 1) psum += __shfl_xor(psum, d);
        lrun[mi][i] = lrun[mi][i] * corr + psum;
#pragma unroll
        for (int dt = 0; dt < 5; dt++) oacc[mi][dt][i] *= corr;
      }
    }

#pragma unroll
    for (int mi = 0; mi < 4; mi++)
#pragma unroll
      for (int ni = 0; ni < 4; ni++)
#pragma unroll
        for (int i = 0; i < 4; i++)
          psw[(mi * 16 + quad * 4 + i) * PS_STRIDE + ni * 16 + l15] = f2b(s[mi][ni][i]);

#pragma unroll
    for (int kk = 0; kk < 2; kk++) {
      bf16x8 pf[4];
#pragma unroll
      for (int mi = 0; mi < 4; mi++)
        pf[mi] = *(const bf16x8*)&psw[(mi * 16 + l15) * PS_STRIDE + kk * 32 + quad * 8];
#pragma unroll
      for (int dt = 0; dt < 5; dt++) {
        bf16x8 vf = *(const bf16x8*)&Vt[(dt * 16 + l15) * VT_STRIDE + kk * 32 + quad * 8];
#pragma unroll
        for (int mi = 0; mi < 4; mi++)
          oacc[mi][dt] = __builtin_amdgcn_mfma_f32_16x16x32_bf16(pf[mi], vf, oacc[mi][dt], 0, 0, 0);
      }
    }
  }

#pragma unroll
  for (int mi = 0; mi < 4; mi++) {
#pragma unroll
    for (int i = 0; i < 4; i++) {
      const float inv = 1.f / lrun[mi][i];
      const size_t orow = rowbase + wave * 64 + mi * 16 + quad * 4 + i;
#pragma unroll
      for (int dt = 0; dt < 5; dt++) {
        const int d = dt * 16 + l15;
        if (d < 72) out[orow * 1152 + h * 72 + d] = f2b(oacc[mi][dt][i] * inv);
      }
    }
  }
}

// ---------------- temporal attention (T=16): scalar, small FLOPs ----------------
__global__ __launch_bounds__(128) void attn_t_k(
    const uint16_t* __restrict__ qkv, uint16_t* __restrict__ out)
{
  const int blk = blockIdx.x;
  const int bl = blk >> 1, hg = blk & 1;
  const int b = bl >> 8, l = bl & 255;
  const int tid = threadIdx.x;
  const int hh = tid >> 4, tq = tid & 15;
  const int h = hg * 8 + hh;
  __shared__ __align__(16) uint16_t kb[8 * 16 * 72];
  __shared__ __align__(16) uint16_t vb[8 * 16 * 72];

#pragma unroll
  for (int it = 0; it < 9; it++) {
    const int idx = tid + it * 128;
    const int rowL = idx / 9, cc = idx % 9;
    const int hhL = rowL >> 4, tL = rowL & 15;
    const size_t grow = (size_t)b * 4096 + (size_t)tL * 256 + l;
    const int colk = 1152 + (hg * 8 + hhL) * 72 + cc * 8;
    ((uint4*)&kb[rowL * 72])[cc] = *(const uint4*)(qkv + grow * 3456 + colk);
    ((uint4*)&vb[rowL * 72])[cc] = *(const uint4*)(qkv + grow * 3456 + colk + 1152);
  }
  __syncthreads();

  float q[72];
  const size_t qrow = (size_t)b * 4096 + (size_t)tq * 256 + l;
  {
    const uint16_t* qp = qkv + qrow * 3456 + h * 72;
#pragma unroll
    for (int i = 0; i < 9; i++) unpack8(((const uint4*)qp)[i], q + i * 8);
  }
  const float scale = 0.1178511301977579f;
  float s[16];
#pragma unroll
  for (int m = 0; m < 16; m++) {
    const uint4* kr = (const uint4*)&kb[(hh * 16 + m) * 72];
    float a = 0.f;
#pragma unroll
    for (int i = 0; i < 9; i++) {
      float kf[8]; unpack8(kr[i], kf);
#pragma unroll
      for (int j = 0; j < 8; j++) a += q[i * 8 + j] * kf[j];
    }
    s[m] = a * scale;
  }
  float mx = -1e30f;
#pragma unroll
  for (int m = 0; m < 16; m++) mx = fmaxf(mx, s[m]);
  float sum = 0.f;
#pragma unroll
  for (int m = 0; m < 16; m++) { s[m] = __expf(s[m] - mx); sum += s[m]; }
  const float inv = 1.f / sum;
  float o[72];
#pragma unroll
  for (int d = 0; d < 72; d++) o[d] = 0.f;
#pragma unroll
  for (int m = 0; m < 16; m++) {
    const float p = s[m];
    const uint4* vr = (const uint4*)&vb[(hh * 16 + m) * 72];
#pragma unroll
    for (int i = 0; i < 9; i++) {
      float vf[8]; unpack8(vr[i], vf);
#pragma unroll
      for (int j = 0; j < 8; j++) o[i * 8 + j] += p * vf[j];
    }
  }
  uint16_t* op = out + qrow * 1152 + h * 72;
#pragma unroll
  for (int d = 0; d < 72; d++) op[d] = f2b(o[d] * inv);
}

// ---------------- transpose + fp32->bf16: in(KxN) -> out(NxK) ----------------
__global__ __launch_bounds__(256) void transcvt_k(
    const float* __restrict__ in, uint16_t* __restrict__ out, int K, int N)
{
  __shared__ float t[32][33];
  const int n0 = blockIdx.x * 32, k0 = blockIdx.y * 32;
  const int tx = threadIdx.x & 31, ty = threadIdx.x >> 5;
#pragma unroll
  for (int i = 0; i < 32; i += 8)
    t[ty + i][tx] = in[(size_t)(k0 + ty + i) * N + n0 + tx];
  __syncthreads();
#pragma unroll
  for (int i = 0; i < 32; i += 8)
    out[(size_t)(n0 + ty + i) * K + k0 + tx] = f2b(t[tx][ty + i]);
}

// ---------------- swiglu (in-place on fused x12, row stride 6144) ----------------
__global__ __launch_bounds__(256) void swiglu_k(uint16_t* __restrict__ x12)
{
  const size_t gid = (size_t)blockIdx.x * 256 + threadIdx.x;  // over 8192*384
  const size_t row = gid / 384, c8 = gid - row * 384;
  uint4* base = (uint4*)(x12 + row * 6144);
  float a[8], bb[8];
  unpack8(base[c8], a);
  unpack8(base[384 + c8], bb);
  uint32_t r[4];
#pragma unroll
  for (int j = 0; j < 4; j++) {
    const float s0 = a[2 * j]     / (1.f + __expf(-a[2 * j]))     * bb[2 * j];
    const float s1 = a[2 * j + 1] / (1.f + __expf(-a[2 * j + 1])) * bb[2 * j + 1];
    r[j] = (uint32_t)f2b(s0) | ((uint32_t)f2b(s1) << 16);
  }
  base[c8] = make_uint4(r[0], r[1], r[2], r[3]);
}

// ---------------- ada path ----------------
__global__ void siluc_k(const float* __restrict__ c, float* __restrict__ cs) {
  const int i = blockIdx.x * 256 + threadIdx.x;
  if (i < 2304) { const float v = c[i]; cs[i] = v / (1.f + __expf(-v)); }
}

#define ADA_KS 18
#define ADA_RK 64
__global__ __launch_bounds__(256) void ada_part_k(
    const float* __restrict__ cs, const float* __restrict__ W,
    float* __restrict__ part)
{
  const int col = blockIdx.x * 256 + threadIdx.x;
  const int ks = blockIdx.y;
  const int k0 = ks * ADA_RK;
  __shared__ float sc0[ADA_RK], sc1[ADA_RK];
  if (threadIdx.x < ADA_RK) sc0[threadIdx.x] = cs[k0 + threadIdx.x];
  else if (threadIdx.x < 2 * ADA_RK) sc1[threadIdx.x - ADA_RK] = cs[1152 + k0 + threadIdx.x - ADA_RK];
  __syncthreads();
  if (col >= 10368) return;
  const float* Wp = W + (size_t)k0 * 10368 + col;
  float s0 = 0.f, s1 = 0.f;
#pragma unroll 8
  for (int r = 0; r < ADA_RK; r++) {
    const float wv = Wp[(size_t)r * 10368];
    s0 += sc0[r] * wv;
    s1 += sc1[r] * wv;
  }
  part[(size_t)(ks * 2 + 0) * 10368 + col] = s0;
  part[(size_t)(ks * 2 + 1) * 10368 + col] = s1;
}

__global__ __launch_bounds__(256) void ada_reduce_k(
    const float* __restrict__ part, const float* __restrict__ bias,
    float* __restrict__ chv)
{
  const int col = blockIdx.x * 256 + threadIdx.x;
  if (col >= 10368) return;
  float s0 = bias[col], s1 = bias[col];
#pragma unroll
  for (int ks = 0; ks < ADA_KS; ks++) {
    s0 += part[(size_t)(ks * 2 + 0) * 10368 + col];
    s1 += part[(size_t)(ks * 2 + 1) * 10368 + col];
  }
  chv[col] = s0;
  chv[10368 + col] = s1;
}

extern "C" void kernel_launch(void* const* d_in, const int* in_sizes, int n_in,
                              void* d_out, int out_size, void* d_ws, size_t ws_size,
                              hipStream_t stream)
{
  const float* c_in    = (const float*)d_in[1];
  const float* norm1w  = (const float*)d_in[2];
  const float* norm2w  = (const float*)d_in[3];
  const float* norm3w  = (const float*)d_in[4];
  const float* qn_s    = (const float*)d_in[5];
  const float* kn_s    = (const float*)d_in[6];
  const float* qkv_s_w = (const float*)d_in[7];
  const float* qkv_s_b = (const float*)d_in[8];
  const float* proj_s_w= (const float*)d_in[9];
  const float* proj_s_b= (const float*)d_in[10];
  const float* qn_t    = (const float*)d_in[11];
  const float* kn_t    = (const float*)d_in[12];
  const float* qkv_t_w = (const float*)d_in[13];
  const float* qkv_t_b = (const float*)d_in[14];
  const float* proj_t_w= (const float*)d_in[15];
  const float* proj_t_b= (const float*)d_in[16];
  const float* w12_w   = (const float*)d_in[17];
  const float* w12_b   = (const float*)d_in[18];
  const float* w3_w    = (const float*)d_in[19];
  const float* w3_b    = (const float*)d_in[20];
  const float* ada_w   = (const float*)d_in[21];
  const float* ada_b   = (const float*)d_in[22];

  float* X = (float*)d_out;  // fp32 residual accumulator; also final output

  char* wsb = (char*)d_ws; size_t off = 0;
  auto alloc = [&](size_t bytes) -> void* {
    void* p = wsb + off; off += bytes; off = (off + 255) & ~(size_t)255; return p;
  };
  uint16_t* XN    = (uint16_t*)alloc((size_t)8192 * 1152 * 2);  // xn / attn_out
  uint16_t* QKV   = (uint16_t*)alloc((size_t)8192 * 6144 * 2);  // qkv (stride 3456) / x12 (stride 6144, aliased)
  uint16_t* X12   = QKV;
  uint16_t* WqkvS = (uint16_t*)alloc((size_t)3584 * 1152 * 2);  // padded to 14*256 rows
  uint16_t* WprojS= (uint16_t*)alloc((size_t)1280 * 1152 * 2);  // padded to 5*256 rows
  uint16_t* WqkvT = (uint16_t*)alloc((size_t)3584 * 1152 * 2);
  uint16_t* WprojT= (uint16_t*)alloc((size_t)1280 * 1152 * 2);
  uint16_t* W12T  = (uint16_t*)alloc((size_t)6144 * 1152 * 2);  // exact 24*256
  uint16_t* W3T   = (uint16_t*)alloc((size_t)1280 * 3072 * 2);  // padded to 5*256 rows
  float* CH = (float*)alloc((size_t)2 * 10368 * 4);
  float* CS = (float*)alloc((size_t)2 * 1152 * 4);
  float* APART = (float*)alloc((size_t)ADA_KS * 2 * 10368 * 4);

  hipMemcpyAsync(X, d_in[0], (size_t)8192 * 1152 * 4, hipMemcpyDeviceToDevice, stream);
  siluc_k<<<9, 256, 0, stream>>>(c_in, CS);
  ada_part_k<<<dim3(41, ADA_KS), 256, 0, stream>>>(CS, ada_w, APART);
  ada_reduce_k<<<41, 256, 0, stream>>>(APART, ada_b, CH);

  transcvt_k<<<dim3(3456 / 32, 1152 / 32), 256, 0, stream>>>(qkv_s_w, WqkvS, 1152, 3456);
  transcvt_k<<<dim3(1152 / 32, 1152 / 32), 256, 0, stream>>>(proj_s_w, WprojS, 1152, 1152);
  transcvt_k<<<dim3(3456 / 32, 1152 / 32), 256, 0, stream>>>(qkv_t_w, WqkvT, 1152, 3456);
  transcvt_k<<<dim3(1152 / 32, 1152 / 32), 256, 0, stream>>>(proj_t_w, WprojT, 1152, 1152);
  transcvt_k<<<dim3(6144 / 32, 1152 / 32), 256, 0, stream>>>(w12_w, W12T, 1152, 6144);
  transcvt_k<<<dim3(1152 / 32, 3072 / 32), 256, 0, stream>>>(w3_w, W3T, 3072, 1152);

  // ---- spatial attention ----
  rmsnorm_k<<<8192, 256, 0, stream>>>(X, norm1w, CH, 0, 1, XN);
  gemm256_k<<<32 * 14, 512, 0, stream>>>(XN, 1152, WqkvS, qkv_s_b, QKV, nullptr, nullptr, nullptr,
                                         3456, 1152, 0);
  qknorm_k<<<1024, 256, 0, stream>>>(QKV, qn_s, kn_s);
  attn_s_k<<<512, 256, 0, stream>>>(QKV, XN);
  gemm256_k<<<32 * 5, 512, 0, stream>>>(XN, 1152, WprojS, proj_s_b, nullptr, X, X, CH + 2 * 1152,
                                        1152, 1152, 1);

  // ---- temporal attention ----
  rmsnorm_k<<<8192, 256, 0, stream>>>(X, norm2w, CH, 3, 4, XN);
  gemm256_k<<<32 * 14, 512, 0, stream>>>(XN, 1152, WqkvT, qkv_t_b, QKV, nullptr, nullptr, nullptr,
                                         3456, 1152, 0);
  qknorm_k<<<1024, 256, 0, stream>>>(QKV, qn_t, kn_t);
  attn_t_k<<<1024, 128, 0, stream>>>(QKV, XN);
  gemm256_k<<<32 * 5, 512, 0, stream>>>(XN, 1152, WprojT, proj_t_b, nullptr, X, X, CH + 5 * 1152,
                                        1152, 1152, 1);

  // ---- MLP (fused w12: N=6144, then in-place swiglu, then w3 with lda=6144) ----
  rmsnorm_k<<<8192, 256, 0, stream>>>(X, norm3w, CH, 6, 7, XN);
  gemm256_k<<<32 * 24, 512, 0, stream>>>(XN, 1152, W12T, w12_b, X12, nullptr, nullptr, nullptr,
                                         6144, 1152, 0);
  swiglu_k<<<12288, 256, 0, stream>>>(X12);
  gemm256_k<<<32 * 5, 512, 0, stream>>>(X12, 6144, W3T, w3_b, nullptr, X, X, CH + 8 * 1152,
                                        1152, 3072, 1);
}

// Round 4
// 993.829 us; speedup vs baseline: 1.4386x; 1.4386x over previous
//
#include <hip/hip_runtime.h>
#include <stdint.h>

typedef __bf16 bf16x8 __attribute__((ext_vector_type(8)));
typedef float f32x4 __attribute__((ext_vector_type(4)));

__device__ __forceinline__ float b2f(uint32_t u) {
  union { uint32_t i; float f; } v; v.i = u << 16; return v.f;
}
__device__ __forceinline__ uint16_t f2b(float f) {
  union { float f; uint32_t i; } v; v.f = f;
  uint32_t r = (v.i + 0x7fffu + ((v.i >> 16) & 1u)) >> 16;
  return (uint16_t)r;
}
__device__ __forceinline__ void unpack8(uint4 u, float* f) {
  f[0] = b2f(u.x & 0xffffu); f[1] = b2f(u.x >> 16);
  f[2] = b2f(u.y & 0xffffu); f[3] = b2f(u.y >> 16);
  f[4] = b2f(u.z & 0xffffu); f[5] = b2f(u.z >> 16);
  f[6] = b2f(u.w & 0xffffu); f[7] = b2f(u.w >> 16);
}

__device__ __forceinline__ void gl2lds16(const void* g, void* l) {
  __builtin_amdgcn_global_load_lds(
      (const __attribute__((address_space(1))) void*)g,
      (__attribute__((address_space(3))) void*)l, 16, 0, 0);
}

// ---------------- 128x128 bf16 GEMM: C(MxN) = A(MxK,lda) * Bt(NxK)^T ----------------
// M fixed at 8192 (64 m-tiles). XCD-aware swizzle. Double-buffered async staging.
// LDS granule XOR-swizzle (2-bit): slot s of row r holds global k-granule
// s ^ (r&3) ^ ((r>>2)&3); applied on the per-lane GLOBAL source (linear gl2lds dest)
// and on the fragment read -> read conflicts 8-way -> 2-way (free).
// mode 0: outb[r*N+c] = bf16(acc + bias[c])
// mode 1: outf[r*N+c] = resid[r*N+c] + gate[(r>>12)*10368 + c] * (acc + bias[c])
__global__ __launch_bounds__(256) void gemm_k(
    const uint16_t* __restrict__ A, int lda,
    const uint16_t* __restrict__ Bt,
    const float* __restrict__ bias,
    uint16_t* __restrict__ outb,
    float* __restrict__ outf, const float* __restrict__ resid,
    const float* __restrict__ gate,
    int N, int K, int mode)
{
  __shared__ __align__(16) uint16_t As[2][128 * 32];
  __shared__ __align__(16) uint16_t Bs[2][128 * 32];
  const int tid = threadIdx.x;
  // XCD-aware mapping (blocks round-robin XCDs by blockIdx%8)
  const int xcd = blockIdx.x & 7;
  const int slot = blockIdx.x >> 3;
  const int mt = xcd * 8 + (slot & 7);
  const int nt = slot >> 3;
  const int row0 = mt * 128, col0 = nt * 128;

  const int lane = tid & 63, wave = tid >> 6;
  const int l15 = lane & 15, quad = lane >> 4;
  const int wm = (wave & 1) * 64, wn = (wave >> 1) * 64;

  f32x4 acc[4][4];
  const f32x4 zero = {0.f, 0.f, 0.f, 0.f};
  for (int i = 0; i < 4; i++)
    for (int j = 0; j < 4; j++)
      acc[i][j] = zero;

  // staging: wave covers tile rows [wave*32, wave*32+32), two 16-row segments;
  // lane -> (row = seg*16 + lane>>2, swizzled 16B granule)
  const int rseg = wave * 32 + (lane >> 2);
  const int kseg8 = (((lane & 3) ^ ((lane >> 2) & 3) ^ ((lane >> 4) & 3))) * 8;
  const uint16_t* gA = A + (size_t)(row0 + rseg) * lda + kseg8;
  const uint16_t* gB = Bt + (size_t)(col0 + rseg) * K + kseg8;
  const size_t rowA16 = (size_t)16 * lda;
  const size_t rowB16 = (size_t)16 * K;
  const int woff = wave * 2048;

  // read-side granule swizzle (matches source swizzle; wm/wn/i*16 are 0 mod 64)
  const int gsw = ((quad ^ (l15 & 3) ^ ((l15 >> 2) & 3))) * 8;

  // prologue: stage k0=0 into buffer 0
  gl2lds16(gA,          (char*)As[0] + woff);
  gl2lds16(gA + rowA16, (char*)As[0] + woff + 1024);
  gl2lds16(gB,          (char*)Bs[0] + woff);
  gl2lds16(gB + rowB16, (char*)Bs[0] + woff + 1024);

  for (int k0 = 0; k0 < K; k0 += 32) {
    const int cur = (k0 >> 5) & 1;
    __syncthreads();  // drains prefetch issued one iteration ago (full overlap)
    if (k0 + 32 < K) {
      const int nxt = cur ^ 1;
      gl2lds16(gA + k0 + 32,          (char*)As[nxt] + woff);
      gl2lds16(gA + rowA16 + k0 + 32, (char*)As[nxt] + woff + 1024);
      gl2lds16(gB + k0 + 32,          (char*)Bs[nxt] + woff);
      gl2lds16(gB + rowB16 + k0 + 32, (char*)Bs[nxt] + woff + 1024);
    }

    bf16x8 af[4], bfr[4];
#pragma unroll
    for (int i = 0; i < 4; i++) {
      af[i]  = *(const bf16x8*)&As[cur][(wm + i * 16 + l15) * 32 + gsw];
      bfr[i] = *(const bf16x8*)&Bs[cur][(wn + i * 16 + l15) * 32 + gsw];
    }
#pragma unroll
    for (int mi = 0; mi < 4; mi++)
#pragma unroll
      for (int ni = 0; ni < 4; ni++)
        acc[mi][ni] = __builtin_amdgcn_mfma_f32_16x16x32_bf16(af[mi], bfr[ni], acc[mi][ni], 0, 0, 0);
  }

#pragma unroll
  for (int mi = 0; mi < 4; mi++) {
#pragma unroll
    for (int ni = 0; ni < 4; ni++) {
      const int colg = col0 + wn + ni * 16 + l15;
      const float bv = bias ? bias[colg] : 0.f;
#pragma unroll
      for (int i = 0; i < 4; i++) {
        const int rowg = row0 + wm + mi * 16 + quad * 4 + i;
        const float v = acc[mi][ni][i] + bv;
        const size_t idx = (size_t)rowg * N + colg;
        if (mode == 0) {
          outb[idx] = f2b(v);
        } else {
          const int b = rowg >> 12;  // T*L = 4096 rows per batch
          outf[idx] = resid[idx] + gate[b * 10368 + colg] * v;
        }
      }
    }
  }
}

// ================= 256x256 lockstep 8-phase bf16 GEMM (round-2 version, w12 only) ======
// Used ONLY for the fused w12 GEMM (N=6144): grid 768 = 3 full CU-rounds.
__global__ __launch_bounds__(512, 2) void gemm256_k(
    const uint16_t* __restrict__ A, int lda,
    const uint16_t* __restrict__ Bt,
    const float* __restrict__ bias,
    uint16_t* __restrict__ outb,
    int N, int K)
{
  __shared__ __align__(16) uint16_t L[65536];  // 2 bufs x {A 16384, B0 8192, B1 8192} elems
  const int tid = threadIdx.x;
  const int lane = tid & 63, wave = tid >> 6;
  const int l15 = lane & 15, quad = lane >> 4;
  const int wm = (wave >> 2) * 128, wn = (wave & 3) * 64;

  const int xcd = blockIdx.x & 7;
  const int slot = blockIdx.x >> 3;
  const int mt = xcd * 4 + (slot & 3);
  const int nt = slot >> 2;
  const int row0 = mt * 256, col0 = nt * 256;

  const int NTk = K >> 6;

  const uint16_t* Ag = A + (size_t)row0 * lda;
  const uint16_t* Bg = Bt + (size_t)col0 * K;

  const int sX = (lane & 7) ^ (lane >> 3);
  const int laneRowA = lane >> 3;
  const int laneK8A = sX * 8;
  const int laneRowB = 2 * (lane >> 3) + ((sX >> 2) & 1);
  const int laneK8B = (sX & 3) * 8;
  const int rA0 = ((wave * 16) & 63) + (((wave * 16) >> 6) << 7);
  const int rB0 = wave * 32;

#define STAGE_A(BUF, SUB, KT) do { \
    const uint16_t* g_ = Ag + (size_t)(rA0 + (SUB) * 64 + laneRowA) * lda + (size_t)(KT) * 64 + laneK8A; \
    uint16_t* l_ = (uint16_t*)&L[(BUF) * 32768 + (rA0 + (SUB) * 64) * 64]; \
    gl2lds16(g_, l_); \
    gl2lds16(g_ + (size_t)8 * lda, l_ + 512); \
  } while (0)

#define STAGE_B(BUF, HALF, KT) do { \
    const uint16_t* g_ = Bg + (size_t)(rB0 + laneRowB) * K + (size_t)(KT) * 64 + (HALF) * 32 + laneK8B; \
    uint16_t* l_ = (uint16_t*)&L[(BUF) * 32768 + 16384 + (HALF) * 8192 + rB0 * 32]; \
    gl2lds16(g_, l_); \
    gl2lds16(g_ + (size_t)16 * K, l_ + 512); \
  } while (0)

  f32x4 acc[8][4];
#pragma unroll
  for (int i = 0; i < 8; i++)
#pragma unroll
    for (int j = 0; j < 4; j++)
      acc[i][j] = (f32x4){0.f, 0.f, 0.f, 0.f};

  bf16x8 a_[4], b_[4];

#define PHASE(CUR, KK, QM, READB, STAGE_STMT, VM_STMT) do { \
    _Pragma("unroll") for (int mi = 0; mi < 4; mi++) \
      a_[mi] = *(const bf16x8*)&L[(CUR) * 32768 + (wm + (QM) * 64 + mi * 16 + l15) * 64 + \
                                  ((((KK) * 4 + quad) ^ (l15 & 7)) * 8)]; \
    if (READB) { \
      _Pragma("unroll") for (int ni = 0; ni < 4; ni++) \
        b_[ni] = *(const bf16x8*)&L[(CUR) * 32768 + 16384 + (KK) * 8192 + \
                                    ((wn >> 1) + ni * 8 + (l15 >> 1)) * 64 + \
                                    ((((((l15 & 1) << 2) | quad)) ^ (l15 >> 1)) * 8)]; \
    } \
    STAGE_STMT; \
    __builtin_amdgcn_sched_barrier(0); \
    __builtin_amdgcn_s_barrier(); \
    asm volatile("s_waitcnt lgkmcnt(0)" ::: "memory"); \
    __builtin_amdgcn_sched_barrier(0); \
    __builtin_amdgcn_s_setprio(1); \
    _Pragma("unroll") for (int mi = 0; mi < 4; mi++) \
      _Pragma("unroll") for (int ni = 0; ni < 4; ni++) \
        acc[(QM) * 4 + mi][ni] = __builtin_amdgcn_mfma_f32_16x16x32_bf16( \
            a_[mi], b_[ni], acc[(QM) * 4 + mi][ni], 0, 0, 0); \
    __builtin_amdgcn_s_setprio(0); \
    __builtin_amdgcn_sched_barrier(0); \
    VM_STMT; \
    __builtin_amdgcn_sched_barrier(0); \
    __builtin_amdgcn_s_barrier(); \
    __builtin_amdgcn_sched_barrier(0); \
  } while (0)

#define TILE(CUR, T) do { \
    PHASE(CUR, 0, 0, 1, { if ((T) + 1 < NTk) STAGE_B((CUR) ^ 1, 1, (T) + 1); }, {}); \
    PHASE(CUR, 0, 1, 0, { if ((T) + 1 < NTk) STAGE_A((CUR) ^ 1, 1, (T) + 1); }, {}); \
    PHASE(CUR, 1, 0, 1, { if ((T) + 2 < NTk) STAGE_B((CUR), 0, (T) + 2); }, {}); \
    PHASE(CUR, 1, 1, 0, { if ((T) + 2 < NTk) STAGE_A((CUR), 0, (T) + 2); }, \
      { if ((T) + 2 < NTk) { asm volatile("s_waitcnt vmcnt(4)" ::: "memory"); } \
        else               { asm volatile("s_waitcnt vmcnt(0)" ::: "memory"); } }); \
  } while (0)

  // prologue: tile0 fully + tile1 {A-H0, B0}
  STAGE_A(0, 0, 0); STAGE_A(0, 1, 0); STAGE_B(0, 0, 0); STAGE_B(0, 1, 0);
  STAGE_A(1, 0, 1); STAGE_B(1, 0, 1);
  asm volatile("s_waitcnt vmcnt(4)" ::: "memory");
  __builtin_amdgcn_sched_barrier(0);
  __builtin_amdgcn_s_barrier();
  __builtin_amdgcn_sched_barrier(0);

  for (int t = 0; t < NTk; t += 2) {
    TILE(0, t);
    TILE(1, t + 1);
  }

#undef PHASE
#undef TILE
#undef STAGE_A
#undef STAGE_B

  // epilogue (mode 0 only)
#pragma unroll
  for (int mi = 0; mi < 8; mi++) {
#pragma unroll
    for (int ni = 0; ni < 4; ni++) {
      const int colg = col0 + wn + ni * 16 + l15;
      const float bv = bias[colg];
#pragma unroll
      for (int i = 0; i < 4; i++) {
        const int rowg = row0 + wm + mi * 16 + quad * 4 + i;
        outb[(size_t)rowg * N + colg] = f2b(acc[mi][ni][i] + bv);
      }
    }
  }
}

// ---------------- RMS + adaLN modulate ----------------
__global__ __launch_bounds__(256) void rmsnorm_k(
    const float* __restrict__ x, const float* __restrict__ w,
    const float* __restrict__ chv, int shsel, int scsel,
    uint16_t* __restrict__ xn)
{
  const int row = blockIdx.x;
  const int b = row >> 12;
  const float* xr = x + (size_t)row * 1152;
  float ss = 0.f;
  for (int d = threadIdx.x; d < 1152; d += 256) { const float v = xr[d]; ss += v * v; }
  for (int off = 32; off > 0; off >>= 1) ss += __shfl_down(ss, off);
  __shared__ float red[4];
  if ((threadIdx.x & 63) == 0) red[threadIdx.x >> 6] = ss;
  __syncthreads();
  const float tot = red[0] + red[1] + red[2] + red[3];
  const float rs = rsqrtf(tot * (1.f / 1152.f) + 1e-6f);
  const float* sh = chv + b * 10368 + shsel * 1152;
  const float* sc = chv + b * 10368 + scsel * 1152;
  uint16_t* xo = xn + (size_t)row * 1152;
  for (int d = threadIdx.x; d < 1152; d += 256)
    xo[d] = f2b(xr[d] * rs * w[d] * (1.f + sc[d]) + sh[d]);
}

// ---------------- per-head RMS norm of q,k in qkv (in place) ----------------
__global__ __launch_bounds__(256) void qknorm_k(
    uint16_t* __restrict__ qkv, const float* __restrict__ qn, const float* __restrict__ kn)
{
  const int tid = threadIdx.x;
  const int rl = tid >> 5, unit = tid & 31;
  const int h = unit & 15, isK = unit >> 4;
  const size_t row = (size_t)blockIdx.x * 8 + rl;
  uint16_t* p = qkv + row * 3456 + isK * 1152 + h * 72;
  const float* w = isK ? kn : qn;
  float v[72];
#pragma unroll
  for (int i = 0; i < 9; i++) unpack8(((const uint4*)p)[i], v + i * 8);
  float ss = 0.f;
#pragma unroll
  for (int d = 0; d < 72; d++) ss += v[d] * v[d];
  const float rs = rsqrtf(ss * (1.f / 72.f) + 1e-6f);
#pragma unroll
  for (int d = 0; d < 72; d++) p[d] = f2b(v[d] * rs * w[d]);
}

// ---------------- spatial attention, MFMA flash: block=(bt,h), 4 waves x 64 queries ----------------
#define AK_STRIDE 104
#define VT_STRIDE 88
#define PS_STRIDE 72
__global__ __launch_bounds__(256) void attn_s_k(
    const uint16_t* __restrict__ qkv, uint16_t* __restrict__ out)
{
  __shared__ __align__(16) uint16_t Ks[64 * AK_STRIDE];
  __shared__ __align__(16) uint16_t Vt[80 * VT_STRIDE];
  __shared__ __align__(16) uint16_t Ps[4 * 64 * PS_STRIDE];
  const int bh = blockIdx.x;
  const int bt = bh >> 4, h = bh & 15;
  const int tid = threadIdx.x;
  const int lane = tid & 63, wave = tid >> 6;
  const int l15 = lane & 15, quad = lane >> 4;
  const size_t rowbase = (size_t)bt * 256;
  const float scale = 0.1178511301977579f;  // 1/sqrt(72)

  union { uint4 u; bf16x8 v; } zu; zu.u = make_uint4(0, 0, 0, 0);
  const bf16x8 zero8 = zu.v;

  bf16x8 qf[4][3];
#pragma unroll
  for (int mi = 0; mi < 4; mi++) {
    const uint16_t* qp = qkv + (rowbase + wave * 64 + mi * 16 + l15) * 3456 + h * 72;
    qf[mi][0] = *(const bf16x8*)(qp + quad * 8);
    qf[mi][1] = *(const bf16x8*)(qp + 32 + quad * 8);
    qf[mi][2] = (quad == 0) ? *(const bf16x8*)(qp + 64) : zero8;
  }

  f32x4 oacc[4][5];
#pragma unroll
  for (int mi = 0; mi < 4; mi++)
#pragma unroll
    for (int dt = 0; dt < 5; dt++)
      oacc[mi][dt] = (f32x4){0.f, 0.f, 0.f, 0.f};
  float mrun[4][4], lrun[4][4];
#pragma unroll
  for (int mi = 0; mi < 4; mi++)
#pragma unroll
    for (int i = 0; i < 4; i++) { mrun[mi][i] = -1e30f; lrun[mi][i] = 0.f; }

  uint16_t* psw = &Ps[wave * 64 * PS_STRIDE];

  for (int c = 0; c < 4; c++) {
    __syncthreads();
    for (int idx = tid; idx < 576; idx += 256) {
      const int rr = idx / 9, cc = idx - rr * 9;
      const uint16_t* kg = qkv + (rowbase + c * 64 + rr) * 3456 + 1152 + h * 72 + cc * 8;
      *(uint4*)&Ks[rr * AK_STRIDE + cc * 8] = *(const uint4*)kg;
      uint4 vv = *(const uint4*)(kg + 1152);
      const uint16_t* e = (const uint16_t*)&vv;
#pragma unroll
      for (int j = 0; j < 8; j++) Vt[(cc * 8 + j) * VT_STRIDE + rr] = e[j];
    }
    __syncthreads();

    f32x4 s[4][4];
#pragma unroll
    for (int mi = 0; mi < 4; mi++)
#pragma unroll
      for (int ni = 0; ni < 4; ni++)
        s[mi][ni] = (f32x4){0.f, 0.f, 0.f, 0.f};
#pragma unroll
    for (int ni = 0; ni < 4; ni++) {
      bf16x8 kf0 = *(const bf16x8*)&Ks[(ni * 16 + l15) * AK_STRIDE + quad * 8];
      bf16x8 kf1 = *(const bf16x8*)&Ks[(ni * 16 + l15) * AK_STRIDE + 32 + quad * 8];
      bf16x8 kf2 = (quad == 0) ? *(const bf16x8*)&Ks[(ni * 16 + l15) * AK_STRIDE + 64] : zero8;
#pragma unroll
      for (int mi = 0; mi < 4; mi++) {
        s[mi][ni] = __builtin_amdgcn_mfma_f32_16x16x32_bf16(qf[mi][0], kf0, s[mi][ni], 0, 0, 0);
        s[mi][ni] = __builtin_amdgcn_mfma_f32_16x16x32_bf16(qf[mi][1], kf1, s[mi][ni], 0, 0, 0);
        s[mi][ni] = __builtin_amdgcn_mfma_f32_16x16x32_bf16(qf[mi][2], kf2, s[mi][ni], 0, 0, 0);
      }
    }

#pragma unroll
    for (int mi = 0; mi < 4; mi++) {
#pragma unroll
      for (int i = 0; i < 4; i++) {
        float mx = fmaxf(fmaxf(s[mi][0][i], s[mi][1][i]), fmaxf(s[mi][2][i], s[mi][3][i])) * scale;
#pragma unroll
        for (int d = 1; d < 16; d <<= 1) mx = fmaxf(mx, __shfl_xor(mx, d));
        const float mnew = fmaxf(mrun[mi][i], mx);
        const float corr = __expf(mrun[mi][i] - mnew);
        mrun[mi][i] = mnew;
        float psum = 0.f;
#pragma unroll
        for (int ni = 0; ni < 4; ni++) {
          const float p = __expf(s[mi][ni][i] * scale - mnew);
          s[mi][ni][i] = p;
          psum += p;
        }
#pragma unroll
        for (int d = 1; d < 16; d <<= 1) psum += __shfl_xor(psum, d);
        lrun[mi][i] = lrun[mi][i] * corr + psum;
#pragma unroll
        for (int dt = 0; dt < 5; dt++) oacc[mi][dt][i] *= corr;
      }
    }

#pragma unroll
    for (int mi = 0; mi < 4; mi++)
#pragma unroll
      for (int ni = 0; ni < 4; ni++)
#pragma unroll
        for (int i = 0; i < 4; i++)
          psw[(mi * 16 + quad * 4 + i) * PS_STRIDE + ni * 16 + l15] = f2b(s[mi][ni][i]);

#pragma unroll
    for (int kk = 0; kk < 2; kk++) {
      bf16x8 pf[4];
#pragma unroll
      for (int mi = 0; mi < 4; mi++)
        pf[mi] = *(const bf16x8*)&psw[(mi * 16 + l15) * PS_STRIDE + kk * 32 + quad * 8];
#pragma unroll
      for (int dt = 0; dt < 5; dt++) {
        bf16x8 vf = *(const bf16x8*)&Vt[(dt * 16 + l15) * VT_STRIDE + kk * 32 + quad * 8];
#pragma unroll
        for (int mi = 0; mi < 4; mi++)
          oacc[mi][dt] = __builtin_amdgcn_mfma_f32_16x16x32_bf16(pf[mi], vf, oacc[mi][dt], 0, 0, 0);
      }
    }
  }

#pragma unroll
  for (int mi = 0; mi < 4; mi++) {
#pragma unroll
    for (int i = 0; i < 4; i++) {
      const float inv = 1.f / lrun[mi][i];
      const size_t orow = rowbase + wave * 64 + mi * 16 + quad * 4 + i;
#pragma unroll
      for (int dt = 0; dt < 5; dt++) {
        const int d = dt * 16 + l15;
        if (d < 72) out[orow * 1152 + h * 72 + d] = f2b(oacc[mi][dt][i] * inv);
      }
    }
  }
}

// ---------------- temporal attention (T=16): scalar, small FLOPs ----------------
__global__ __launch_bounds__(128) void attn_t_k(
    const uint16_t* __restrict__ qkv, uint16_t* __restrict__ out)
{
  const int blk = blockIdx.x;
  const int bl = blk >> 1, hg = blk & 1;
  const int b = bl >> 8, l = bl & 255;
  const int tid = threadIdx.x;
  const int hh = tid >> 4, tq = tid & 15;
  const int h = hg * 8 + hh;
  __shared__ __align__(16) uint16_t kb[8 * 16 * 72];
  __shared__ __align__(16) uint16_t vb[8 * 16 * 72];

#pragma unroll
  for (int it = 0; it < 9; it++) {
    const int idx = tid + it * 128;
    const int rowL = idx / 9, cc = idx % 9;
    const int hhL = rowL >> 4, tL = rowL & 15;
    const size_t grow = (size_t)b * 4096 + (size_t)tL * 256 + l;
    const int colk = 1152 + (hg * 8 + hhL) * 72 + cc * 8;
    ((uint4*)&kb[rowL * 72])[cc] = *(const uint4*)(qkv + grow * 3456 + colk);
    ((uint4*)&vb[rowL * 72])[cc] = *(const uint4*)(qkv + grow * 3456 + colk + 1152);
  }
  __syncthreads();

  float q[72];
  const size_t qrow = (size_t)b * 4096 + (size_t)tq * 256 + l;
  {
    const uint16_t* qp = qkv + qrow * 3456 + h * 72;
#pragma unroll
    for (int i = 0; i < 9; i++) unpack8(((const uint4*)qp)[i], q + i * 8);
  }
  const float scale = 0.1178511301977579f;
  float s[16];
#pragma unroll
  for (int m = 0; m < 16; m++) {
    const uint4* kr = (const uint4*)&kb[(hh * 16 + m) * 72];
    float a = 0.f;
#pragma unroll
    for (int i = 0; i < 9; i++) {
      float kf[8]; unpack8(kr[i], kf);
#pragma unroll
      for (int j = 0; j < 8; j++) a += q[i * 8 + j] * kf[j];
    }
    s[m] = a * scale;
  }
  float mx = -1e30f;
#pragma unroll
  for (int m = 0; m < 16; m++) mx = fmaxf(mx, s[m]);
  float sum = 0.f;
#pragma unroll
  for (int m = 0; m < 16; m++) { s[m] = __expf(s[m] - mx); sum += s[m]; }
  const float inv = 1.f / sum;
  float o[72];
#pragma unroll
  for (int d = 0; d < 72; d++) o[d] = 0.f;
#pragma unroll
  for (int m = 0; m < 16; m++) {
    const float p = s[m];
    const uint4* vr = (const uint4*)&vb[(hh * 16 + m) * 72];
#pragma unroll
    for (int i = 0; i < 9; i++) {
      float vf[8]; unpack8(vr[i], vf);
#pragma unroll
      for (int j = 0; j < 8; j++) o[i * 8 + j] += p * vf[j];
    }
  }
  uint16_t* op = out + qrow * 1152 + h * 72;
#pragma unroll
  for (int d = 0; d < 72; d++) op[d] = f2b(o[d] * inv);
}

// ---------------- transpose + fp32->bf16: in(KxN) -> out(NxK) ----------------
__global__ __launch_bounds__(256) void transcvt_k(
    const float* __restrict__ in, uint16_t* __restrict__ out, int K, int N)
{
  __shared__ float t[32][33];
  const int n0 = blockIdx.x * 32, k0 = blockIdx.y * 32;
  const int tx = threadIdx.x & 31, ty = threadIdx.x >> 5;
#pragma unroll
  for (int i = 0; i < 32; i += 8)
    t[ty + i][tx] = in[(size_t)(k0 + ty + i) * N + n0 + tx];
  __syncthreads();
#pragma unroll
  for (int i = 0; i < 32; i += 8)
    out[(size_t)(n0 + ty + i) * K + k0 + tx] = f2b(t[tx][ty + i]);
}

// ---------------- swiglu (in-place on fused x12, row stride 6144) ----------------
__global__ __launch_bounds__(256) void swiglu_k(uint16_t* __restrict__ x12)
{
  const size_t gid = (size_t)blockIdx.x * 256 + threadIdx.x;  // over 8192*384
  const size_t row = gid / 384, c8 = gid - row * 384;
  uint4* base = (uint4*)(x12 + row * 6144);
  float a[8], bb[8];
  unpack8(base[c8], a);
  unpack8(base[384 + c8], bb);
  uint32_t r[4];
#pragma unroll
  for (int j = 0; j < 4; j++) {
    const float s0 = a[2 * j]     / (1.f + __expf(-a[2 * j]))     * bb[2 * j];
    const float s1 = a[2 * j + 1] / (1.f + __expf(-a[2 * j + 1])) * bb[2 * j + 1];
    r[j] = (uint32_t)f2b(s0) | ((uint32_t)f2b(s1) << 16);
  }
  base[c8] = make_uint4(r[0], r[1], r[2], r[3]);
}

// ---------------- ada path ----------------
__global__ void siluc_k(const float* __restrict__ c, float* __restrict__ cs) {
  const int i = blockIdx.x * 256 + threadIdx.x;
  if (i < 2304) { const float v = c[i]; cs[i] = v / (1.f + __expf(-v)); }
}

#define ADA_KS 18
#define ADA_RK 64
__global__ __launch_bounds__(256) void ada_part_k(
    const float* __restrict__ cs, const float* __restrict__ W,
    float* __restrict__ part)
{
  const int col = blockIdx.x * 256 + threadIdx.x;
  const int ks = blockIdx.y;
  const int k0 = ks * ADA_RK;
  __shared__ float sc0[ADA_RK], sc1[ADA_RK];
  if (threadIdx.x < ADA_RK) sc0[threadIdx.x] = cs[k0 + threadIdx.x];
  else if (threadIdx.x < 2 * ADA_RK) sc1[threadIdx.x - ADA_RK] = cs[1152 + k0 + threadIdx.x - ADA_RK];
  __syncthreads();
  if (col >= 10368) return;
  const float* Wp = W + (size_t)k0 * 10368 + col;
  float s0 = 0.f, s1 = 0.f;
#pragma unroll 8
  for (int r = 0; r < ADA_RK; r++) {
    const float wv = Wp[(size_t)r * 10368];
    s0 += sc0[r] * wv;
    s1 += sc1[r] * wv;
  }
  part[(size_t)(ks * 2 + 0) * 10368 + col] = s0;
  part[(size_t)(ks * 2 + 1) * 10368 + col] = s1;
}

__global__ __launch_bounds__(256) void ada_reduce_k(
    const float* __restrict__ part, const float* __restrict__ bias,
    float* __restrict__ chv)
{
  const int col = blockIdx.x * 256 + threadIdx.x;
  if (col >= 10368) return;
  float s0 = bias[col], s1 = bias[col];
#pragma unroll
  for (int ks = 0; ks < ADA_KS; ks++) {
    s0 += part[(size_t)(ks * 2 + 0) * 10368 + col];
    s1 += part[(size_t)(ks * 2 + 1) * 10368 + col];
  }
  chv[col] = s0;
  chv[10368 + col] = s1;
}

extern "C" void kernel_launch(void* const* d_in, const int* in_sizes, int n_in,
                              void* d_out, int out_size, void* d_ws, size_t ws_size,
                              hipStream_t stream)
{
  const float* c_in    = (const float*)d_in[1];
  const float* norm1w  = (const float*)d_in[2];
  const float* norm2w  = (const float*)d_in[3];
  const float* norm3w  = (const float*)d_in[4];
  const float* qn_s    = (const float*)d_in[5];
  const float* kn_s    = (const float*)d_in[6];
  const float* qkv_s_w = (const float*)d_in[7];
  const float* qkv_s_b = (const float*)d_in[8];
  const float* proj_s_w= (const float*)d_in[9];
  const float* proj_s_b= (const float*)d_in[10];
  const float* qn_t    = (const float*)d_in[11];
  const float* kn_t    = (const float*)d_in[12];
  const float* qkv_t_w = (const float*)d_in[13];
  const float* qkv_t_b = (const float*)d_in[14];
  const float* proj_t_w= (const float*)d_in[15];
  const float* proj_t_b= (const float*)d_in[16];
  const float* w12_w   = (const float*)d_in[17];
  const float* w12_b   = (const float*)d_in[18];
  const float* w3_w    = (const float*)d_in[19];
  const float* w3_b    = (const float*)d_in[20];
  const float* ada_w   = (const float*)d_in[21];
  const float* ada_b   = (const float*)d_in[22];

  float* X = (float*)d_out;  // fp32 residual accumulator; also final output

  char* wsb = (char*)d_ws; size_t off = 0;
  auto alloc = [&](size_t bytes) -> void* {
    void* p = wsb + off; off += bytes; off = (off + 255) & ~(size_t)255; return p;
  };
  uint16_t* XN    = (uint16_t*)alloc((size_t)8192 * 1152 * 2);  // xn / attn_out
  uint16_t* QKV   = (uint16_t*)alloc((size_t)8192 * 6144 * 2);  // qkv (stride 3456) / x12 (stride 6144)
  uint16_t* X12   = QKV;
  uint16_t* WqkvS = (uint16_t*)alloc((size_t)3456 * 1152 * 2);
  uint16_t* WprojS= (uint16_t*)alloc((size_t)1152 * 1152 * 2);
  uint16_t* WqkvT = (uint16_t*)alloc((size_t)3456 * 1152 * 2);
  uint16_t* WprojT= (uint16_t*)alloc((size_t)1152 * 1152 * 2);
  uint16_t* W12T  = (uint16_t*)alloc((size_t)6144 * 1152 * 2);
  uint16_t* W3T   = (uint16_t*)alloc((size_t)1152 * 3072 * 2);
  float* CH = (float*)alloc((size_t)2 * 10368 * 4);
  float* CS = (float*)alloc((size_t)2 * 1152 * 4);
  float* APART = (float*)alloc((size_t)ADA_KS * 2 * 10368 * 4);

  hipMemcpyAsync(X, d_in[0], (size_t)8192 * 1152 * 4, hipMemcpyDeviceToDevice, stream);
  siluc_k<<<9, 256, 0, stream>>>(c_in, CS);
  ada_part_k<<<dim3(41, ADA_KS), 256, 0, stream>>>(CS, ada_w, APART);
  ada_reduce_k<<<41, 256, 0, stream>>>(APART, ada_b, CH);

  transcvt_k<<<dim3(3456 / 32, 1152 / 32), 256, 0, stream>>>(qkv_s_w, WqkvS, 1152, 3456);
  transcvt_k<<<dim3(1152 / 32, 1152 / 32), 256, 0, stream>>>(proj_s_w, WprojS, 1152, 1152);
  transcvt_k<<<dim3(3456 / 32, 1152 / 32), 256, 0, stream>>>(qkv_t_w, WqkvT, 1152, 3456);
  transcvt_k<<<dim3(1152 / 32, 1152 / 32), 256, 0, stream>>>(proj_t_w, WprojT, 1152, 1152);
  transcvt_k<<<dim3(6144 / 32, 1152 / 32), 256, 0, stream>>>(w12_w, W12T, 1152, 6144);
  transcvt_k<<<dim3(1152 / 32, 3072 / 32), 256, 0, stream>>>(w3_w, W3T, 3072, 1152);

  // ---- spatial attention ----
  rmsnorm_k<<<8192, 256, 0, stream>>>(X, norm1w, CH, 0, 1, XN);
  gemm_k<<<27 * 64, 256, 0, stream>>>(XN, 1152, WqkvS, qkv_s_b, QKV, nullptr, nullptr, nullptr,
                                      3456, 1152, 0);
  qknorm_k<<<1024, 256, 0, stream>>>(QKV, qn_s, kn_s);
  attn_s_k<<<512, 256, 0, stream>>>(QKV, XN);
  gemm_k<<<9 * 64, 256, 0, stream>>>(XN, 1152, WprojS, proj_s_b, nullptr, X, X, CH + 2 * 1152,
                                     1152, 1152, 1);

  // ---- temporal attention ----
  rmsnorm_k<<<8192, 256, 0, stream>>>(X, norm2w, CH, 3, 4, XN);
  gemm_k<<<27 * 64, 256, 0, stream>>>(XN, 1152, WqkvT, qkv_t_b, QKV, nullptr, nullptr, nullptr,
                                      3456, 1152, 0);
  qknorm_k<<<1024, 256, 0, stream>>>(QKV, qn_t, kn_t);
  attn_t_k<<<1024, 128, 0, stream>>>(QKV, XN);
  gemm_k<<<9 * 64, 256, 0, stream>>>(XN, 1152, WprojT, proj_t_b, nullptr, X, X, CH + 5 * 1152,
                                     1152, 1152, 1);

  // ---- MLP (fused w12 via 256^2 kernel, in-place swiglu, w3 via 128^2 with lda=6144) ----
  rmsnorm_k<<<8192, 256, 0, stream>>>(X, norm3w, CH, 6, 7, XN);
  gemm256_k<<<32 * 24, 512, 0, stream>>>(XN, 1152, W12T, w12_b, X12, 6144, 1152);
  swiglu_k<<<12288, 256, 0, stream>>>(X12);
  gemm_k<<<9 * 64, 256, 0, stream>>>(X12, 6144, W3T, w3_b, nullptr, X, X, CH + 8 * 1152,
                                     1152, 3072, 1);
}

// Round 5
// 976.086 us; speedup vs baseline: 1.4647x; 1.0182x over previous
//
#include <hip/hip_runtime.h>
#include <stdint.h>

typedef __bf16 bf16x8 __attribute__((ext_vector_type(8)));
typedef float f32x4 __attribute__((ext_vector_type(4)));

__device__ __forceinline__ float b2f(uint32_t u) {
  union { uint32_t i; float f; } v; v.i = u << 16; return v.f;
}
__device__ __forceinline__ uint16_t f2b(float f) {
  union { float f; uint32_t i; } v; v.f = f;
  uint32_t r = (v.i + 0x7fffu + ((v.i >> 16) & 1u)) >> 16;
  return (uint16_t)r;
}
__device__ __forceinline__ void unpack8(uint4 u, float* f) {
  f[0] = b2f(u.x & 0xffffu); f[1] = b2f(u.x >> 16);
  f[2] = b2f(u.y & 0xffffu); f[3] = b2f(u.y >> 16);
  f[4] = b2f(u.z & 0xffffu); f[5] = b2f(u.z >> 16);
  f[6] = b2f(u.w & 0xffffu); f[7] = b2f(u.w >> 16);
}

__device__ __forceinline__ void gl2lds16(const void* g, void* l) {
  __builtin_amdgcn_global_load_lds(
      (const __attribute__((address_space(1))) void*)g,
      (__attribute__((address_space(3))) void*)l, 16, 0, 0);
}

// ---------------- 128x128 bf16 GEMM: C(MxN) = A(MxK,lda) * Bt(NxK)^T ----------------
// M fixed at 8192 (64 m-tiles). XCD-aware swizzle. Double-buffered async staging.
// LDS granule XOR-swizzle (2-bit) applied on per-lane GLOBAL source + fragment read.
// mode 0: outb[r*N+c] = bf16(acc + bias[c])
// mode 1: outf[r*N+c] = resid[r*N+c] + gate[(r>>12)*10368 + c] * (acc + bias[c])
__global__ __launch_bounds__(256) void gemm_k(
    const uint16_t* __restrict__ A, int lda,
    const uint16_t* __restrict__ Bt,
    const float* __restrict__ bias,
    uint16_t* __restrict__ outb,
    float* __restrict__ outf, const float* __restrict__ resid,
    const float* __restrict__ gate,
    int N, int K, int mode)
{
  __shared__ __align__(16) uint16_t As[2][128 * 32];
  __shared__ __align__(16) uint16_t Bs[2][128 * 32];
  const int tid = threadIdx.x;
  const int xcd = blockIdx.x & 7;
  const int slot = blockIdx.x >> 3;
  const int mt = xcd * 8 + (slot & 7);
  const int nt = slot >> 3;
  const int row0 = mt * 128, col0 = nt * 128;

  const int lane = tid & 63, wave = tid >> 6;
  const int l15 = lane & 15, quad = lane >> 4;
  const int wm = (wave & 1) * 64, wn = (wave >> 1) * 64;

  f32x4 acc[4][4];
  const f32x4 zero = {0.f, 0.f, 0.f, 0.f};
  for (int i = 0; i < 4; i++)
    for (int j = 0; j < 4; j++)
      acc[i][j] = zero;

  const int rseg = wave * 32 + (lane >> 2);
  const int kseg8 = (((lane & 3) ^ ((lane >> 2) & 3) ^ ((lane >> 4) & 3))) * 8;
  const uint16_t* gA = A + (size_t)(row0 + rseg) * lda + kseg8;
  const uint16_t* gB = Bt + (size_t)(col0 + rseg) * K + kseg8;
  const size_t rowA16 = (size_t)16 * lda;
  const size_t rowB16 = (size_t)16 * K;
  const int woff = wave * 2048;

  const int gsw = ((quad ^ (l15 & 3) ^ ((l15 >> 2) & 3))) * 8;

  gl2lds16(gA,          (char*)As[0] + woff);
  gl2lds16(gA + rowA16, (char*)As[0] + woff + 1024);
  gl2lds16(gB,          (char*)Bs[0] + woff);
  gl2lds16(gB + rowB16, (char*)Bs[0] + woff + 1024);

  for (int k0 = 0; k0 < K; k0 += 32) {
    const int cur = (k0 >> 5) & 1;
    __syncthreads();
    if (k0 + 32 < K) {
      const int nxt = cur ^ 1;
      gl2lds16(gA + k0 + 32,          (char*)As[nxt] + woff);
      gl2lds16(gA + rowA16 + k0 + 32, (char*)As[nxt] + woff + 1024);
      gl2lds16(gB + k0 + 32,          (char*)Bs[nxt] + woff);
      gl2lds16(gB + rowB16 + k0 + 32, (char*)Bs[nxt] + woff + 1024);
    }

    bf16x8 af[4], bfr[4];
#pragma unroll
    for (int i = 0; i < 4; i++) {
      af[i]  = *(const bf16x8*)&As[cur][(wm + i * 16 + l15) * 32 + gsw];
      bfr[i] = *(const bf16x8*)&Bs[cur][(wn + i * 16 + l15) * 32 + gsw];
    }
#pragma unroll
    for (int mi = 0; mi < 4; mi++)
#pragma unroll
      for (int ni = 0; ni < 4; ni++)
        acc[mi][ni] = __builtin_amdgcn_mfma_f32_16x16x32_bf16(af[mi], bfr[ni], acc[mi][ni], 0, 0, 0);
  }

#pragma unroll
  for (int mi = 0; mi < 4; mi++) {
#pragma unroll
    for (int ni = 0; ni < 4; ni++) {
      const int colg = col0 + wn + ni * 16 + l15;
      const float bv = bias ? bias[colg] : 0.f;
#pragma unroll
      for (int i = 0; i < 4; i++) {
        const int rowg = row0 + wm + mi * 16 + quad * 4 + i;
        const float v = acc[mi][ni][i] + bv;
        const size_t idx = (size_t)rowg * N + colg;
        if (mode == 0) {
          outb[idx] = f2b(v);
        } else {
          const int b = rowg >> 12;  // T*L = 4096 rows per batch
          outf[idx] = resid[idx] + gate[b * 10368 + colg] * v;
        }
      }
    }
  }
}

// ================= 256x256 lockstep 8-phase bf16 GEMM + fused swiglu (w12 only) ======
// N fixed 6144 (interleaved x1/x2 columns: col 2p = x1_p, col 2p+1 = x2_p).
// Epilogue: v = acc + bias[interleave(col)]; partner via shfl_xor(v,1);
// h = silu(x1)*x2 written by even lanes to outh (8192 x 3072, stride 3072).
__global__ __launch_bounds__(512, 2) void gemm256_sw_k(
    const uint16_t* __restrict__ A, int lda,
    const uint16_t* __restrict__ Bt,
    const float* __restrict__ bias,
    uint16_t* __restrict__ outh,
    int K)
{
  __shared__ __align__(16) uint16_t L[65536];  // 2 bufs x {A 16384, B0 8192, B1 8192} elems
  const int tid = threadIdx.x;
  const int lane = tid & 63, wave = tid >> 6;
  const int l15 = lane & 15, quad = lane >> 4;
  const int wm = (wave >> 2) * 128, wn = (wave & 3) * 64;

  const int xcd = blockIdx.x & 7;
  const int slot = blockIdx.x >> 3;
  const int mt = xcd * 4 + (slot & 3);
  const int nt = slot >> 2;
  const int row0 = mt * 256, col0 = nt * 256;

  const int NTk = K >> 6;

  const uint16_t* Ag = A + (size_t)row0 * lda;
  const uint16_t* Bg = Bt + (size_t)col0 * K;

  const int sX = (lane & 7) ^ (lane >> 3);
  const int laneRowA = lane >> 3;
  const int laneK8A = sX * 8;
  const int laneRowB = 2 * (lane >> 3) + ((sX >> 2) & 1);
  const int laneK8B = (sX & 3) * 8;
  const int rA0 = ((wave * 16) & 63) + (((wave * 16) >> 6) << 7);
  const int rB0 = wave * 32;

#define STAGE_A(BUF, SUB, KT) do { \
    const uint16_t* g_ = Ag + (size_t)(rA0 + (SUB) * 64 + laneRowA) * lda + (size_t)(KT) * 64 + laneK8A; \
    uint16_t* l_ = (uint16_t*)&L[(BUF) * 32768 + (rA0 + (SUB) * 64) * 64]; \
    gl2lds16(g_, l_); \
    gl2lds16(g_ + (size_t)8 * lda, l_ + 512); \
  } while (0)

#define STAGE_B(BUF, HALF, KT) do { \
    const uint16_t* g_ = Bg + (size_t)(rB0 + laneRowB) * K + (size_t)(KT) * 64 + (HALF) * 32 + laneK8B; \
    uint16_t* l_ = (uint16_t*)&L[(BUF) * 32768 + 16384 + (HALF) * 8192 + rB0 * 32]; \
    gl2lds16(g_, l_); \
    gl2lds16(g_ + (size_t)16 * K, l_ + 512); \
  } while (0)

  f32x4 acc[8][4];
#pragma unroll
  for (int i = 0; i < 8; i++)
#pragma unroll
    for (int j = 0; j < 4; j++)
      acc[i][j] = (f32x4){0.f, 0.f, 0.f, 0.f};

  bf16x8 a_[4], b_[4];

#define PHASE(CUR, KK, QM, READB, STAGE_STMT, VM_STMT) do { \
    _Pragma("unroll") for (int mi = 0; mi < 4; mi++) \
      a_[mi] = *(const bf16x8*)&L[(CUR) * 32768 + (wm + (QM) * 64 + mi * 16 + l15) * 64 + \
                                  ((((KK) * 4 + quad) ^ (l15 & 7)) * 8)]; \
    if (READB) { \
      _Pragma("unroll") for (int ni = 0; ni < 4; ni++) \
        b_[ni] = *(const bf16x8*)&L[(CUR) * 32768 + 16384 + (KK) * 8192 + \
                                    ((wn >> 1) + ni * 8 + (l15 >> 1)) * 64 + \
                                    ((((((l15 & 1) << 2) | quad)) ^ (l15 >> 1)) * 8)]; \
    } \
    STAGE_STMT; \
    __builtin_amdgcn_sched_barrier(0); \
    __builtin_amdgcn_s_barrier(); \
    asm volatile("s_waitcnt lgkmcnt(0)" ::: "memory"); \
    __builtin_amdgcn_sched_barrier(0); \
    __builtin_amdgcn_s_setprio(1); \
    _Pragma("unroll") for (int mi = 0; mi < 4; mi++) \
      _Pragma("unroll") for (int ni = 0; ni < 4; ni++) \
        acc[(QM) * 4 + mi][ni] = __builtin_amdgcn_mfma_f32_16x16x32_bf16( \
            a_[mi], b_[ni], acc[(QM) * 4 + mi][ni], 0, 0, 0); \
    __builtin_amdgcn_s_setprio(0); \
    __builtin_amdgcn_sched_barrier(0); \
    VM_STMT; \
    __builtin_amdgcn_sched_barrier(0); \
    __builtin_amdgcn_s_barrier(); \
    __builtin_amdgcn_sched_barrier(0); \
  } while (0)

#define TILE(CUR, T) do { \
    PHASE(CUR, 0, 0, 1, { if ((T) + 1 < NTk) STAGE_B((CUR) ^ 1, 1, (T) + 1); }, {}); \
    PHASE(CUR, 0, 1, 0, { if ((T) + 1 < NTk) STAGE_A((CUR) ^ 1, 1, (T) + 1); }, {}); \
    PHASE(CUR, 1, 0, 1, { if ((T) + 2 < NTk) STAGE_B((CUR), 0, (T) + 2); }, {}); \
    PHASE(CUR, 1, 1, 0, { if ((T) + 2 < NTk) STAGE_A((CUR), 0, (T) + 2); }, \
      { if ((T) + 2 < NTk) { asm volatile("s_waitcnt vmcnt(4)" ::: "memory"); } \
        else               { asm volatile("s_waitcnt vmcnt(0)" ::: "memory"); } }); \
  } while (0)

  STAGE_A(0, 0, 0); STAGE_A(0, 1, 0); STAGE_B(0, 0, 0); STAGE_B(0, 1, 0);
  STAGE_A(1, 0, 1); STAGE_B(1, 0, 1);
  asm volatile("s_waitcnt vmcnt(4)" ::: "memory");
  __builtin_amdgcn_sched_barrier(0);
  __builtin_amdgcn_s_barrier();
  __builtin_amdgcn_sched_barrier(0);

  for (int t = 0; t < NTk; t += 2) {
    TILE(0, t);
    TILE(1, t + 1);
  }

#undef PHASE
#undef TILE
#undef STAGE_A
#undef STAGE_B

  // epilogue: fused swiglu. colg even = x1, odd = x2 (interleaved W12T).
#pragma unroll
  for (int mi = 0; mi < 8; mi++) {
#pragma unroll
    for (int ni = 0; ni < 4; ni++) {
      const int colg = col0 + wn + ni * 16 + l15;
      const float bv = bias[(colg & 1) * 3072 + (colg >> 1)];
      const int hcol = ((col0 + wn + ni * 16) >> 1) + (l15 >> 1);
#pragma unroll
      for (int i = 0; i < 4; i++) {
        const int rowg = row0 + wm + mi * 16 + quad * 4 + i;
        const float v = acc[mi][ni][i] + bv;
        const float o = __shfl_xor(v, 1);
        if ((l15 & 1) == 0) {
          const float hres = v / (1.f + __expf(-v)) * o;
          outh[(size_t)rowg * 3072 + hcol] = f2b(hres);
        }
      }
    }
  }
}

// ---------------- RMS + adaLN modulate (float4 vectorized) ----------------
__global__ __launch_bounds__(256) void rmsnorm_k(
    const float* __restrict__ x, const float* __restrict__ w,
    const float* __restrict__ chv, int shsel, int scsel,
    uint16_t* __restrict__ xn)
{
  const int row = blockIdx.x;
  const int b = row >> 12;
  const int tid = threadIdx.x;
  const float4* x4 = (const float4*)(x + (size_t)row * 1152);  // 288 float4
  float4 a = x4[tid];
  float ss = a.x * a.x + a.y * a.y + a.z * a.z + a.w * a.w;
  float4 a2 = {0.f, 0.f, 0.f, 0.f};
  if (tid < 32) {
    a2 = x4[256 + tid];
    ss += a2.x * a2.x + a2.y * a2.y + a2.z * a2.z + a2.w * a2.w;
  }
  for (int off = 32; off > 0; off >>= 1) ss += __shfl_down(ss, off);
  __shared__ float red[4];
  if ((tid & 63) == 0) red[tid >> 6] = ss;
  __syncthreads();
  const float tot = red[0] + red[1] + red[2] + red[3];
  const float rs = rsqrtf(tot * (1.f / 1152.f) + 1e-6f);
  const float4* w4 = (const float4*)w;
  const float4* sh4 = (const float4*)(chv + b * 10368 + shsel * 1152);
  const float4* sc4 = (const float4*)(chv + b * 10368 + scsel * 1152);
  uint2* xo = (uint2*)(xn + (size_t)row * 1152);
  auto proc = [&](float4 av, int idx) {
    const float4 wv = w4[idx], shv = sh4[idx], scv = sc4[idx];
    const float r0 = av.x * rs * wv.x * (1.f + scv.x) + shv.x;
    const float r1 = av.y * rs * wv.y * (1.f + scv.y) + shv.y;
    const float r2 = av.z * rs * wv.z * (1.f + scv.z) + shv.z;
    const float r3 = av.w * rs * wv.w * (1.f + scv.w) + shv.w;
    uint2 o;
    o.x = (uint32_t)f2b(r0) | ((uint32_t)f2b(r1) << 16);
    o.y = (uint32_t)f2b(r2) | ((uint32_t)f2b(r3) << 16);
    xo[idx] = o;
  };
  proc(a, tid);
  if (tid < 32) proc(a2, 256 + tid);
}

// ---------------- per-head RMS norm of q,k in qkv (in place) ----------------
__global__ __launch_bounds__(256) void qknorm_k(
    uint16_t* __restrict__ qkv, const float* __restrict__ qn, const float* __restrict__ kn)
{
  const int tid = threadIdx.x;
  const int rl = tid >> 5, unit = tid & 31;
  const int h = unit & 15, isK = unit >> 4;
  const size_t row = (size_t)blockIdx.x * 8 + rl;
  uint16_t* p = qkv + row * 3456 + isK * 1152 + h * 72;
  const float* w = isK ? kn : qn;
  float v[72];
#pragma unroll
  for (int i = 0; i < 9; i++) unpack8(((const uint4*)p)[i], v + i * 8);
  float ss = 0.f;
#pragma unroll
  for (int d = 0; d < 72; d++) ss += v[d] * v[d];
  const float rs = rsqrtf(ss * (1.f / 72.f) + 1e-6f);
#pragma unroll
  for (int d = 0; d < 72; d++) p[d] = f2b(v[d] * rs * w[d]);
}

// ---------------- spatial attention, MFMA flash: block=(bt,h), 4 waves x 64 queries ----------------
#define AK_STRIDE 104
#define VT_STRIDE 88
#define PS_STRIDE 72
__global__ __launch_bounds__(256) void attn_s_k(
    const uint16_t* __restrict__ qkv, uint16_t* __restrict__ out)
{
  __shared__ __align__(16) uint16_t Ks[64 * AK_STRIDE];
  __shared__ __align__(16) uint16_t Vt[80 * VT_STRIDE];
  __shared__ __align__(16) uint16_t Ps[4 * 64 * PS_STRIDE];
  const int bh = blockIdx.x;
  const int bt = bh >> 4, h = bh & 15;
  const int tid = threadIdx.x;
  const int lane = tid & 63, wave = tid >> 6;
  const int l15 = lane & 15, quad = lane >> 4;
  const size_t rowbase = (size_t)bt * 256;
  const float scale = 0.1178511301977579f;  // 1/sqrt(72)

  union { uint4 u; bf16x8 v; } zu; zu.u = make_uint4(0, 0, 0, 0);
  const bf16x8 zero8 = zu.v;

  bf16x8 qf[4][3];
#pragma unroll
  for (int mi = 0; mi < 4; mi++) {
    const uint16_t* qp = qkv + (rowbase + wave * 64 + mi * 16 + l15) * 3456 + h * 72;
    qf[mi][0] = *(const bf16x8*)(qp + quad * 8);
    qf[mi][1] = *(const bf16x8*)(qp + 32 + quad * 8);
    qf[mi][2] = (quad == 0) ? *(const bf16x8*)(qp + 64) : zero8;
  }

  f32x4 oacc[4][5];
#pragma unroll
  for (int mi = 0; mi < 4; mi++)
#pragma unroll
    for (int dt = 0; dt < 5; dt++)
      oacc[mi][dt] = (f32x4){0.f, 0.f, 0.f, 0.f};
  float mrun[4][4], lrun[4][4];
#pragma unroll
  for (int mi = 0; mi < 4; mi++)
#pragma unroll
    for (int i = 0; i < 4; i++) { mrun[mi][i] = -1e30f; lrun[mi][i] = 0.f; }

  uint16_t* psw = &Ps[wave * 64 * PS_STRIDE];

  for (int c = 0; c < 4; c++) {
    __syncthreads();
    for (int idx = tid; idx < 576; idx += 256) {
      const int rr = idx / 9, cc = idx - rr * 9;
      const uint16_t* kg = qkv + (rowbase + c * 64 + rr) * 3456 + 1152 + h * 72 + cc * 8;
      *(uint4*)&Ks[rr * AK_STRIDE + cc * 8] = *(const uint4*)kg;
      uint4 vv = *(const uint4*)(kg + 1152);
      const uint16_t* e = (const uint16_t*)&vv;
#pragma unroll
      for (int j = 0; j < 8; j++) Vt[(cc * 8 + j) * VT_STRIDE + rr] = e[j];
    }
    __syncthreads();

    f32x4 s[4][4];
#pragma unroll
    for (int mi = 0; mi < 4; mi++)
#pragma unroll
      for (int ni = 0; ni < 4; ni++)
        s[mi][ni] = (f32x4){0.f, 0.f, 0.f, 0.f};
#pragma unroll
    for (int ni = 0; ni < 4; ni++) {
      bf16x8 kf0 = *(const bf16x8*)&Ks[(ni * 16 + l15) * AK_STRIDE + quad * 8];
      bf16x8 kf1 = *(const bf16x8*)&Ks[(ni * 16 + l15) * AK_STRIDE + 32 + quad * 8];
      bf16x8 kf2 = (quad == 0) ? *(const bf16x8*)&Ks[(ni * 16 + l15) * AK_STRIDE + 64] : zero8;
#pragma unroll
      for (int mi = 0; mi < 4; mi++) {
        s[mi][ni] = __builtin_amdgcn_mfma_f32_16x16x32_bf16(qf[mi][0], kf0, s[mi][ni], 0, 0, 0);
        s[mi][ni] = __builtin_amdgcn_mfma_f32_16x16x32_bf16(qf[mi][1], kf1, s[mi][ni], 0, 0, 0);
        s[mi][ni] = __builtin_amdgcn_mfma_f32_16x16x32_bf16(qf[mi][2], kf2, s[mi][ni], 0, 0, 0);
      }
    }

#pragma unroll
    for (int mi = 0; mi < 4; mi++) {
#pragma unroll
      for (int i = 0; i < 4; i++) {
        float mx = fmaxf(fmaxf(s[mi][0][i], s[mi][1][i]), fmaxf(s[mi][2][i], s[mi][3][i])) * scale;
#pragma unroll
        for (int d = 1; d < 16; d <<= 1) mx = fmaxf(mx, __shfl_xor(mx, d));
        const float mnew = fmaxf(mrun[mi][i], mx);
        const float corr = __expf(mrun[mi][i] - mnew);
        mrun[mi][i] = mnew;
        float psum = 0.f;
#pragma unroll
        for (int ni = 0; ni < 4; ni++) {
          const float p = __expf(s[mi][ni][i] * scale - mnew);
          s[mi][ni][i] = p;
          psum += p;
        }
#pragma unroll
        for (int d = 1; d < 16; d <<= 1) psum += __shfl_xor(psum, d);
        lrun[mi][i] = lrun[mi][i] * corr + psum;
#pragma unroll
        for (int dt = 0; dt < 5; dt++) oacc[mi][dt][i] *= corr;
      }
    }

#pragma unroll
    for (int mi = 0; mi < 4; mi++)
#pragma unroll
      for (int ni = 0; ni < 4; ni++)
#pragma unroll
        for (int i = 0; i < 4; i++)
          psw[(mi * 16 + quad * 4 + i) * PS_STRIDE + ni * 16 + l15] = f2b(s[mi][ni][i]);

#pragma unroll
    for (int kk = 0; kk < 2; kk++) {
      bf16x8 pf[4];
#pragma unroll
      for (int mi = 0; mi < 4; mi++)
        pf[mi] = *(const bf16x8*)&psw[(mi * 16 + l15) * PS_STRIDE + kk * 32 + quad * 8];
#pragma unroll
      for (int dt = 0; dt < 5; dt++) {
        bf16x8 vf = *(const bf16x8*)&Vt[(dt * 16 + l15) * VT_STRIDE + kk * 32 + quad * 8];
#pragma unroll
        for (int mi = 0; mi < 4; mi++)
          oacc[mi][dt] = __builtin_amdgcn_mfma_f32_16x16x32_bf16(pf[mi], vf, oacc[mi][dt], 0, 0, 0);
      }
    }
  }

#pragma unroll
  for (int mi = 0; mi < 4; mi++) {
#pragma unroll
    for (int i = 0; i < 4; i++) {
      const float inv = 1.f / lrun[mi][i];
      const size_t orow = rowbase + wave * 64 + mi * 16 + quad * 4 + i;
#pragma unroll
      for (int dt = 0; dt < 5; dt++) {
        const int d = dt * 16 + l15;
        if (d < 72) out[orow * 1152 + h * 72 + d] = f2b(oacc[mi][dt][i] * inv);
      }
    }
  }
}

// ---------------- temporal attention (T=16): scalar, small FLOPs ----------------
__global__ __launch_bounds__(128) void attn_t_k(
    const uint16_t* __restrict__ qkv, uint16_t* __restrict__ out)
{
  const int blk = blockIdx.x;
  const int bl = blk >> 1, hg = blk & 1;
  const int b = bl >> 8, l = bl & 255;
  const int tid = threadIdx.x;
  const int hh = tid >> 4, tq = tid & 15;
  const int h = hg * 8 + hh;
  __shared__ __align__(16) uint16_t kb[8 * 16 * 72];
  __shared__ __align__(16) uint16_t vb[8 * 16 * 72];

#pragma unroll
  for (int it = 0; it < 9; it++) {
    const int idx = tid + it * 128;
    const int rowL = idx / 9, cc = idx % 9;
    const int hhL = rowL >> 4, tL = rowL & 15;
    const size_t grow = (size_t)b * 4096 + (size_t)tL * 256 + l;
    const int colk = 1152 + (hg * 8 + hhL) * 72 + cc * 8;
    ((uint4*)&kb[rowL * 72])[cc] = *(const uint4*)(qkv + grow * 3456 + colk);
    ((uint4*)&vb[rowL * 72])[cc] = *(const uint4*)(qkv + grow * 3456 + colk + 1152);
  }
  __syncthreads();

  float q[72];
  const size_t qrow = (size_t)b * 4096 + (size_t)tq * 256 + l;
  {
    const uint16_t* qp = qkv + qrow * 3456 + h * 72;
#pragma unroll
    for (int i = 0; i < 9; i++) unpack8(((const uint4*)qp)[i], q + i * 8);
  }
  const float scale = 0.1178511301977579f;
  float s[16];
#pragma unroll
  for (int m = 0; m < 16; m++) {
    const uint4* kr = (const uint4*)&kb[(hh * 16 + m) * 72];
    float a = 0.f;
#pragma unroll
    for (int i = 0; i < 9; i++) {
      float kf[8]; unpack8(kr[i], kf);
#pragma unroll
      for (int j = 0; j < 8; j++) a += q[i * 8 + j] * kf[j];
    }
    s[m] = a * scale;
  }
  float mx = -1e30f;
#pragma unroll
  for (int m = 0; m < 16; m++) mx = fmaxf(mx, s[m]);
  float sum = 0.f;
#pragma unroll
  for (int m = 0; m < 16; m++) { s[m] = __expf(s[m] - mx); sum += s[m]; }
  const float inv = 1.f / sum;
  float o[72];
#pragma unroll
  for (int d = 0; d < 72; d++) o[d] = 0.f;
#pragma unroll
  for (int m = 0; m < 16; m++) {
    const float p = s[m];
    const uint4* vr = (const uint4*)&vb[(hh * 16 + m) * 72];
#pragma unroll
    for (int i = 0; i < 9; i++) {
      float vf[8]; unpack8(vr[i], vf);
#pragma unroll
      for (int j = 0; j < 8; j++) o[i * 8 + j] += p * vf[j];
    }
  }
  uint16_t* op = out + qrow * 1152 + h * 72;
#pragma unroll
  for (int d = 0; d < 72; d++) op[d] = f2b(o[d] * inv);
}

// ---------------- transpose + fp32->bf16: in(KxN) -> out(NxK) ----------------
__global__ __launch_bounds__(256) void transcvt_k(
    const float* __restrict__ in, uint16_t* __restrict__ out, int K, int N)
{
  __shared__ float t[32][33];
  const int n0 = blockIdx.x * 32, k0 = blockIdx.y * 32;
  const int tx = threadIdx.x & 31, ty = threadIdx.x >> 5;
#pragma unroll
  for (int i = 0; i < 32; i += 8)
    t[ty + i][tx] = in[(size_t)(k0 + ty + i) * N + n0 + tx];
  __syncthreads();
#pragma unroll
  for (int i = 0; i < 32; i += 8)
    out[(size_t)(n0 + ty + i) * K + k0 + tx] = f2b(t[tx][ty + i]);
}

// ---------------- transpose + cvt + x1/x2 interleave for W12: in(1152x6144) -> out(6144x1152) ----
// out row n corresponds to source column s(n) = (n&1)*3072 + (n>>1).
__global__ __launch_bounds__(256) void transcvt_w12i_k(
    const float* __restrict__ in, uint16_t* __restrict__ out)
{
  __shared__ float t[32][33];
  const int n0 = blockIdx.x * 32, k0 = blockIdx.y * 32;
  const int tx = threadIdx.x & 31, ty = threadIdx.x >> 5;
  const int scol = ((tx & 1) * 3072) + (n0 >> 1) + (tx >> 1);
#pragma unroll
  for (int i = 0; i < 32; i += 8)
    t[ty + i][tx] = in[(size_t)(k0 + ty + i) * 6144 + scol];
  __syncthreads();
#pragma unroll
  for (int i = 0; i < 32; i += 8)
    out[(size_t)(n0 + ty + i) * 1152 + k0 + tx] = f2b(t[tx][ty + i]);
}

// ---------------- ada path ----------------
__global__ void siluc_k(const float* __restrict__ c, float* __restrict__ cs) {
  const int i = blockIdx.x * 256 + threadIdx.x;
  if (i < 2304) { const float v = c[i]; cs[i] = v / (1.f + __expf(-v)); }
}

#define ADA_KS 18
#define ADA_RK 64
__global__ __launch_bounds__(256) void ada_part_k(
    const float* __restrict__ cs, const float* __restrict__ W,
    float* __restrict__ part)
{
  const int col = blockIdx.x * 256 + threadIdx.x;
  const int ks = blockIdx.y;
  const int k0 = ks * ADA_RK;
  __shared__ float sc0[ADA_RK], sc1[ADA_RK];
  if (threadIdx.x < ADA_RK) sc0[threadIdx.x] = cs[k0 + threadIdx.x];
  else if (threadIdx.x < 2 * ADA_RK) sc1[threadIdx.x - ADA_RK] = cs[1152 + k0 + threadIdx.x - ADA_RK];
  __syncthreads();
  if (col >= 10368) return;
  const float* Wp = W + (size_t)k0 * 10368 + col;
  float s0 = 0.f, s1 = 0.f;
#pragma unroll 8
  for (int r = 0; r < ADA_RK; r++) {
    const float wv = Wp[(size_t)r * 10368];
    s0 += sc0[r] * wv;
    s1 += sc1[r] * wv;
  }
  part[(size_t)(ks * 2 + 0) * 10368 + col] = s0;
  part[(size_t)(ks * 2 + 1) * 10368 + col] = s1;
}

__global__ __launch_bounds__(256) void ada_reduce_k(
    const float* __restrict__ part, const float* __restrict__ bias,
    float* __restrict__ chv)
{
  const int col = blockIdx.x * 256 + threadIdx.x;
  if (col >= 10368) return;
  float s0 = bias[col], s1 = bias[col];
#pragma unroll
  for (int ks = 0; ks < ADA_KS; ks++) {
    s0 += part[(size_t)(ks * 2 + 0) * 10368 + col];
    s1 += part[(size_t)(ks * 2 + 1) * 10368 + col];
  }
  chv[col] = s0;
  chv[10368 + col] = s1;
}

extern "C" void kernel_launch(void* const* d_in, const int* in_sizes, int n_in,
                              void* d_out, int out_size, void* d_ws, size_t ws_size,
                              hipStream_t stream)
{
  const float* Xin     = (const float*)d_in[0];
  const float* c_in    = (const float*)d_in[1];
  const float* norm1w  = (const float*)d_in[2];
  const float* norm2w  = (const float*)d_in[3];
  const float* norm3w  = (const float*)d_in[4];
  const float* qn_s    = (const float*)d_in[5];
  const float* kn_s    = (const float*)d_in[6];
  const float* qkv_s_w = (const float*)d_in[7];
  const float* qkv_s_b = (const float*)d_in[8];
  const float* proj_s_w= (const float*)d_in[9];
  const float* proj_s_b= (const float*)d_in[10];
  const float* qn_t    = (const float*)d_in[11];
  const float* kn_t    = (const float*)d_in[12];
  const float* qkv_t_w = (const float*)d_in[13];
  const float* qkv_t_b = (const float*)d_in[14];
  const float* proj_t_w= (const float*)d_in[15];
  const float* proj_t_b= (const float*)d_in[16];
  const float* w12_w   = (const float*)d_in[17];
  const float* w12_b   = (const float*)d_in[18];
  const float* w3_w    = (const float*)d_in[19];
  const float* w3_b    = (const float*)d_in[20];
  const float* ada_w   = (const float*)d_in[21];
  const float* ada_b   = (const float*)d_in[22];

  float* X = (float*)d_out;  // fp32 residual accumulator; first written by proj_s

  char* wsb = (char*)d_ws; size_t off = 0;
  auto alloc = [&](size_t bytes) -> void* {
    void* p = wsb + off; off += bytes; off = (off + 255) & ~(size_t)255; return p;
  };
  uint16_t* XN    = (uint16_t*)alloc((size_t)8192 * 1152 * 2);  // xn / attn_out
  uint16_t* QKV   = (uint16_t*)alloc((size_t)8192 * 3456 * 2);  // qkv; later reused as H (8192x3072)
  uint16_t* H     = QKV;
  uint16_t* WqkvS = (uint16_t*)alloc((size_t)3456 * 1152 * 2);
  uint16_t* WprojS= (uint16_t*)alloc((size_t)1152 * 1152 * 2);
  uint16_t* WqkvT = (uint16_t*)alloc((size_t)3456 * 1152 * 2);
  uint16_t* WprojT= (uint16_t*)alloc((size_t)1152 * 1152 * 2);
  uint16_t* W12T  = (uint16_t*)alloc((size_t)6144 * 1152 * 2);  // interleaved x1/x2
  uint16_t* W3T   = (uint16_t*)alloc((size_t)1152 * 3072 * 2);
  float* CH = (float*)alloc((size_t)2 * 10368 * 4);
  float* CS = (float*)alloc((size_t)2 * 1152 * 4);
  float* APART = (float*)alloc((size_t)ADA_KS * 2 * 10368 * 4);

  siluc_k<<<9, 256, 0, stream>>>(c_in, CS);
  ada_part_k<<<dim3(41, ADA_KS), 256, 0, stream>>>(CS, ada_w, APART);
  ada_reduce_k<<<41, 256, 0, stream>>>(APART, ada_b, CH);

  transcvt_k<<<dim3(3456 / 32, 1152 / 32), 256, 0, stream>>>(qkv_s_w, WqkvS, 1152, 3456);
  transcvt_k<<<dim3(1152 / 32, 1152 / 32), 256, 0, stream>>>(proj_s_w, WprojS, 1152, 1152);
  transcvt_k<<<dim3(3456 / 32, 1152 / 32), 256, 0, stream>>>(qkv_t_w, WqkvT, 1152, 3456);
  transcvt_k<<<dim3(1152 / 32, 1152 / 32), 256, 0, stream>>>(proj_t_w, WprojT, 1152, 1152);
  transcvt_w12i_k<<<dim3(6144 / 32, 1152 / 32), 256, 0, stream>>>(w12_w, W12T);
  transcvt_k<<<dim3(1152 / 32, 3072 / 32), 256, 0, stream>>>(w3_w, W3T, 3072, 1152);

  // ---- spatial attention ----
  rmsnorm_k<<<8192, 256, 0, stream>>>(Xin, norm1w, CH, 0, 1, XN);
  gemm_k<<<27 * 64, 256, 0, stream>>>(XN, 1152, WqkvS, qkv_s_b, QKV, nullptr, nullptr, nullptr,
                                      3456, 1152, 0);
  qknorm_k<<<1024, 256, 0, stream>>>(QKV, qn_s, kn_s);
  attn_s_k<<<512, 256, 0, stream>>>(QKV, XN);
  gemm_k<<<9 * 64, 256, 0, stream>>>(XN, 1152, WprojS, proj_s_b, nullptr, X, Xin, CH + 2 * 1152,
                                     1152, 1152, 1);

  // ---- temporal attention ----
  rmsnorm_k<<<8192, 256, 0, stream>>>(X, norm2w, CH, 3, 4, XN);
  gemm_k<<<27 * 64, 256, 0, stream>>>(XN, 1152, WqkvT, qkv_t_b, QKV, nullptr, nullptr, nullptr,
                                      3456, 1152, 0);
  qknorm_k<<<1024, 256, 0, stream>>>(QKV, qn_t, kn_t);
  attn_t_k<<<1024, 128, 0, stream>>>(QKV, XN);
  gemm_k<<<9 * 64, 256, 0, stream>>>(XN, 1152, WprojT, proj_t_b, nullptr, X, X, CH + 5 * 1152,
                                     1152, 1152, 1);

  // ---- MLP: fused w12+swiglu (H = silu(x1)*x2, 8192x3072), then w3 ----
  rmsnorm_k<<<8192, 256, 0, stream>>>(X, norm3w, CH, 6, 7, XN);
  gemm256_sw_k<<<32 * 24, 512, 0, stream>>>(XN, 1152, W12T, w12_b, H, 1152);
  gemm_k<<<9 * 64, 256, 0, stream>>>(H, 3072, W3T, w3_b, nullptr, X, X, CH + 8 * 1152,
                                     1152, 3072, 1);
}

// Round 6
// 915.772 us; speedup vs baseline: 1.5612x; 1.0659x over previous
//
#include <hip/hip_runtime.h>
#include <stdint.h>

typedef __bf16 bf16x8 __attribute__((ext_vector_type(8)));
typedef float f32x4 __attribute__((ext_vector_type(4)));

__device__ __forceinline__ float b2f(uint32_t u) {
  union { uint32_t i; float f; } v; v.i = u << 16; return v.f;
}
__device__ __forceinline__ uint16_t f2b(float f) {
  union { float f; uint32_t i; } v; v.f = f;
  uint32_t r = (v.i + 0x7fffu + ((v.i >> 16) & 1u)) >> 16;
  return (uint16_t)r;
}
__device__ __forceinline__ void unpack8(uint4 u, float* f) {
  f[0] = b2f(u.x & 0xffffu); f[1] = b2f(u.x >> 16);
  f[2] = b2f(u.y & 0xffffu); f[3] = b2f(u.y >> 16);
  f[4] = b2f(u.z & 0xffffu); f[5] = b2f(u.z >> 16);
  f[6] = b2f(u.w & 0xffffu); f[7] = b2f(u.w >> 16);
}
__device__ __forceinline__ bf16x8 pack8(const float* f) {
  union { uint4 u; bf16x8 v; } r;
  r.u.x = (uint32_t)f2b(f[0]) | ((uint32_t)f2b(f[1]) << 16);
  r.u.y = (uint32_t)f2b(f[2]) | ((uint32_t)f2b(f[3]) << 16);
  r.u.z = (uint32_t)f2b(f[4]) | ((uint32_t)f2b(f[5]) << 16);
  r.u.w = (uint32_t)f2b(f[6]) | ((uint32_t)f2b(f[7]) << 16);
  return r.v;
}

__device__ __forceinline__ void gl2lds16(const void* g, void* l) {
  __builtin_amdgcn_global_load_lds(
      (const __attribute__((address_space(1))) void*)g,
      (__attribute__((address_space(3))) void*)l, 16, 0, 0);
}

// ---------------- 128x128 bf16 GEMM: C(MxN) = A(MxK,lda) * Bt(NxK)^T ----------------
// M fixed at 8192 (64 m-tiles). XCD-aware swizzle. Double-buffered async staging.
// LDS granule XOR-swizzle (2-bit) applied on per-lane GLOBAL source + fragment read.
// mode 0: outb[r*N+c] = bf16(acc + bias[c])
// mode 1: outf[r*N+c] = resid[r*N+c] + gate[(r>>12)*10368 + c] * (acc + bias[c])
__global__ __launch_bounds__(256) void gemm_k(
    const uint16_t* __restrict__ A, int lda,
    const uint16_t* __restrict__ Bt,
    const float* __restrict__ bias,
    uint16_t* __restrict__ outb,
    float* __restrict__ outf, const float* __restrict__ resid,
    const float* __restrict__ gate,
    int N, int K, int mode)
{
  __shared__ __align__(16) uint16_t As[2][128 * 32];
  __shared__ __align__(16) uint16_t Bs[2][128 * 32];
  const int tid = threadIdx.x;
  const int xcd = blockIdx.x & 7;
  const int slot = blockIdx.x >> 3;
  const int mt = xcd * 8 + (slot & 7);
  const int nt = slot >> 3;
  const int row0 = mt * 128, col0 = nt * 128;

  const int lane = tid & 63, wave = tid >> 6;
  const int l15 = lane & 15, quad = lane >> 4;
  const int wm = (wave & 1) * 64, wn = (wave >> 1) * 64;

  f32x4 acc[4][4];
  const f32x4 zero = {0.f, 0.f, 0.f, 0.f};
  for (int i = 0; i < 4; i++)
    for (int j = 0; j < 4; j++)
      acc[i][j] = zero;

  const int rseg = wave * 32 + (lane >> 2);
  const int kseg8 = (((lane & 3) ^ ((lane >> 2) & 3) ^ ((lane >> 4) & 3))) * 8;
  const uint16_t* gA = A + (size_t)(row0 + rseg) * lda + kseg8;
  const uint16_t* gB = Bt + (size_t)(col0 + rseg) * K + kseg8;
  const size_t rowA16 = (size_t)16 * lda;
  const size_t rowB16 = (size_t)16 * K;
  const int woff = wave * 2048;

  const int gsw = ((quad ^ (l15 & 3) ^ ((l15 >> 2) & 3))) * 8;

  gl2lds16(gA,          (char*)As[0] + woff);
  gl2lds16(gA + rowA16, (char*)As[0] + woff + 1024);
  gl2lds16(gB,          (char*)Bs[0] + woff);
  gl2lds16(gB + rowB16, (char*)Bs[0] + woff + 1024);

  for (int k0 = 0; k0 < K; k0 += 32) {
    const int cur = (k0 >> 5) & 1;
    __syncthreads();
    if (k0 + 32 < K) {
      const int nxt = cur ^ 1;
      gl2lds16(gA + k0 + 32,          (char*)As[nxt] + woff);
      gl2lds16(gA + rowA16 + k0 + 32, (char*)As[nxt] + woff + 1024);
      gl2lds16(gB + k0 + 32,          (char*)Bs[nxt] + woff);
      gl2lds16(gB + rowB16 + k0 + 32, (char*)Bs[nxt] + woff + 1024);
    }

    bf16x8 af[4], bfr[4];
#pragma unroll
    for (int i = 0; i < 4; i++) {
      af[i]  = *(const bf16x8*)&As[cur][(wm + i * 16 + l15) * 32 + gsw];
      bfr[i] = *(const bf16x8*)&Bs[cur][(wn + i * 16 + l15) * 32 + gsw];
    }
#pragma unroll
    for (int mi = 0; mi < 4; mi++)
#pragma unroll
      for (int ni = 0; ni < 4; ni++)
        acc[mi][ni] = __builtin_amdgcn_mfma_f32_16x16x32_bf16(af[mi], bfr[ni], acc[mi][ni], 0, 0, 0);
  }

#pragma unroll
  for (int mi = 0; mi < 4; mi++) {
#pragma unroll
    for (int ni = 0; ni < 4; ni++) {
      const int colg = col0 + wn + ni * 16 + l15;
      const float bv = bias ? bias[colg] : 0.f;
#pragma unroll
      for (int i = 0; i < 4; i++) {
        const int rowg = row0 + wm + mi * 16 + quad * 4 + i;
        const float v = acc[mi][ni][i] + bv;
        const size_t idx = (size_t)rowg * N + colg;
        if (mode == 0) {
          outb[idx] = f2b(v);
        } else {
          const int b = rowg >> 12;  // T*L = 4096 rows per batch
          outf[idx] = resid[idx] + gate[b * 10368 + colg] * v;
        }
      }
    }
  }
}

// ================= 256x256 lockstep 8-phase bf16 GEMM + fused swiglu (w12 only) ======
// W12T row layout: n = group*64 + local; local<32 -> x1 col (group*32+local),
// local>=32 -> x2 col (3072 + group*32 + local-32). So a wave's ni in {0,1} frags
// hold x1, ni in {2,3} hold the MATCHING x2 -> pair in-register, no shfl, no
// divergence. h = silu(x1+b1)*(x2+b2) written to outh (8192 x 3072).
__global__ __launch_bounds__(512, 2) void gemm256_sw_k(
    const uint16_t* __restrict__ A, int lda,
    const uint16_t* __restrict__ Bt,
    const float* __restrict__ bias,
    uint16_t* __restrict__ outh,
    int K)
{
  __shared__ __align__(16) uint16_t L[65536];  // 2 bufs x {A 16384, B0 8192, B1 8192} elems
  const int tid = threadIdx.x;
  const int lane = tid & 63, wave = tid >> 6;
  const int l15 = lane & 15, quad = lane >> 4;
  const int wm = (wave >> 2) * 128, wn = (wave & 3) * 64;

  const int xcd = blockIdx.x & 7;
  const int slot = blockIdx.x >> 3;
  const int mt = xcd * 4 + (slot & 3);
  const int nt = slot >> 2;
  const int row0 = mt * 256, col0 = nt * 256;

  const int NTk = K >> 6;

  const uint16_t* Ag = A + (size_t)row0 * lda;
  const uint16_t* Bg = Bt + (size_t)col0 * K;

  const int sX = (lane & 7) ^ (lane >> 3);
  const int laneRowA = lane >> 3;
  const int laneK8A = sX * 8;
  const int laneRowB = 2 * (lane >> 3) + ((sX >> 2) & 1);
  const int laneK8B = (sX & 3) * 8;
  const int rA0 = ((wave * 16) & 63) + (((wave * 16) >> 6) << 7);
  const int rB0 = wave * 32;

#define STAGE_A(BUF, SUB, KT) do { \
    const uint16_t* g_ = Ag + (size_t)(rA0 + (SUB) * 64 + laneRowA) * lda + (size_t)(KT) * 64 + laneK8A; \
    uint16_t* l_ = (uint16_t*)&L[(BUF) * 32768 + (rA0 + (SUB) * 64) * 64]; \
    gl2lds16(g_, l_); \
    gl2lds16(g_ + (size_t)8 * lda, l_ + 512); \
  } while (0)

#define STAGE_B(BUF, HALF, KT) do { \
    const uint16_t* g_ = Bg + (size_t)(rB0 + laneRowB) * K + (size_t)(KT) * 64 + (HALF) * 32 + laneK8B; \
    uint16_t* l_ = (uint16_t*)&L[(BUF) * 32768 + 16384 + (HALF) * 8192 + rB0 * 32]; \
    gl2lds16(g_, l_); \
    gl2lds16(g_ + (size_t)16 * K, l_ + 512); \
  } while (0)

  f32x4 acc[8][4];
#pragma unroll
  for (int i = 0; i < 8; i++)
#pragma unroll
    for (int j = 0; j < 4; j++)
      acc[i][j] = (f32x4){0.f, 0.f, 0.f, 0.f};

  bf16x8 a_[4], b_[4];

#define PHASE(CUR, KK, QM, READB, STAGE_STMT, VM_STMT) do { \
    _Pragma("unroll") for (int mi = 0; mi < 4; mi++) \
      a_[mi] = *(const bf16x8*)&L[(CUR) * 32768 + (wm + (QM) * 64 + mi * 16 + l15) * 64 + \
                                  ((((KK) * 4 + quad) ^ (l15 & 7)) * 8)]; \
    if (READB) { \
      _Pragma("unroll") for (int ni = 0; ni < 4; ni++) \
        b_[ni] = *(const bf16x8*)&L[(CUR) * 32768 + 16384 + (KK) * 8192 + \
                                    ((wn >> 1) + ni * 8 + (l15 >> 1)) * 64 + \
                                    ((((((l15 & 1) << 2) | quad)) ^ (l15 >> 1)) * 8)]; \
    } \
    STAGE_STMT; \
    __builtin_amdgcn_sched_barrier(0); \
    __builtin_amdgcn_s_barrier(); \
    asm volatile("s_waitcnt lgkmcnt(0)" ::: "memory"); \
    __builtin_amdgcn_sched_barrier(0); \
    __builtin_amdgcn_s_setprio(1); \
    _Pragma("unroll") for (int mi = 0; mi < 4; mi++) \
      _Pragma("unroll") for (int ni = 0; ni < 4; ni++) \
        acc[(QM) * 4 + mi][ni] = __builtin_amdgcn_mfma_f32_16x16x32_bf16( \
            a_[mi], b_[ni], acc[(QM) * 4 + mi][ni], 0, 0, 0); \
    __builtin_amdgcn_s_setprio(0); \
    __builtin_amdgcn_sched_barrier(0); \
    VM_STMT; \
    __builtin_amdgcn_sched_barrier(0); \
    __builtin_amdgcn_s_barrier(); \
    __builtin_amdgcn_sched_barrier(0); \
  } while (0)

#define TILE(CUR, T) do { \
    PHASE(CUR, 0, 0, 1, { if ((T) + 1 < NTk) STAGE_B((CUR) ^ 1, 1, (T) + 1); }, {}); \
    PHASE(CUR, 0, 1, 0, { if ((T) + 1 < NTk) STAGE_A((CUR) ^ 1, 1, (T) + 1); }, {}); \
    PHASE(CUR, 1, 0, 1, { if ((T) + 2 < NTk) STAGE_B((CUR), 0, (T) + 2); }, {}); \
    PHASE(CUR, 1, 1, 0, { if ((T) + 2 < NTk) STAGE_A((CUR), 0, (T) + 2); }, \
      { if ((T) + 2 < NTk) { asm volatile("s_waitcnt vmcnt(4)" ::: "memory"); } \
        else               { asm volatile("s_waitcnt vmcnt(0)" ::: "memory"); } }); \
  } while (0)

  STAGE_A(0, 0, 0); STAGE_A(0, 1, 0); STAGE_B(0, 0, 0); STAGE_B(0, 1, 0);
  STAGE_A(1, 0, 1); STAGE_B(1, 0, 1);
  asm volatile("s_waitcnt vmcnt(4)" ::: "memory");
  __builtin_amdgcn_sched_barrier(0);
  __builtin_amdgcn_s_barrier();
  __builtin_amdgcn_sched_barrier(0);

  for (int t = 0; t < NTk; t += 2) {
    TILE(0, t);
    TILE(1, t + 1);
  }

#undef PHASE
#undef TILE
#undef STAGE_A
#undef STAGE_B

  // epilogue: fused swiglu, x1 in ni, x2 in ni+2 (same thread) -> no shfl/divergence
  const int hbase = ((col0 + wn) >> 6) * 32;
#pragma unroll
  for (int mi = 0; mi < 8; mi++) {
#pragma unroll
    for (int ni = 0; ni < 2; ni++) {
      const int p = hbase + ni * 16 + l15;  // h-col; bias idx p (x1) / 3072+p (x2)
      const float b1 = bias[p];
      const float b2 = bias[3072 + p];
#pragma unroll
      for (int i = 0; i < 4; i++) {
        const int rowg = row0 + wm + mi * 16 + quad * 4 + i;
        const float v1 = acc[mi][ni][i] + b1;
        const float v2 = acc[mi][ni + 2][i] + b2;
        const float hres = v1 / (1.f + __expf(-v1)) * v2;
        outh[(size_t)rowg * 3072 + p] = f2b(hres);
      }
    }
  }
}

// ---------------- RMS + adaLN modulate (float4 vectorized) ----------------
__global__ __launch_bounds__(256) void rmsnorm_k(
    const float* __restrict__ x, const float* __restrict__ w,
    const float* __restrict__ chv, int shsel, int scsel,
    uint16_t* __restrict__ xn)
{
  const int row = blockIdx.x;
  const int b = row >> 12;
  const int tid = threadIdx.x;
  const float4* x4 = (const float4*)(x + (size_t)row * 1152);  // 288 float4
  float4 a = x4[tid];
  float ss = a.x * a.x + a.y * a.y + a.z * a.z + a.w * a.w;
  float4 a2 = {0.f, 0.f, 0.f, 0.f};
  if (tid < 32) {
    a2 = x4[256 + tid];
    ss += a2.x * a2.x + a2.y * a2.y + a2.z * a2.z + a2.w * a2.w;
  }
  for (int off = 32; off > 0; off >>= 1) ss += __shfl_down(ss, off);
  __shared__ float red[4];
  if ((tid & 63) == 0) red[tid >> 6] = ss;
  __syncthreads();
  const float tot = red[0] + red[1] + red[2] + red[3];
  const float rs = rsqrtf(tot * (1.f / 1152.f) + 1e-6f);
  const float4* w4 = (const float4*)w;
  const float4* sh4 = (const float4*)(chv + b * 10368 + shsel * 1152);
  const float4* sc4 = (const float4*)(chv + b * 10368 + scsel * 1152);
  uint2* xo = (uint2*)(xn + (size_t)row * 1152);
  auto proc = [&](float4 av, int idx) {
    const float4 wv = w4[idx], shv = sh4[idx], scv = sc4[idx];
    const float r0 = av.x * rs * wv.x * (1.f + scv.x) + shv.x;
    const float r1 = av.y * rs * wv.y * (1.f + scv.y) + shv.y;
    const float r2 = av.z * rs * wv.z * (1.f + scv.z) + shv.z;
    const float r3 = av.w * rs * wv.w * (1.f + scv.w) + shv.w;
    uint2 o;
    o.x = (uint32_t)f2b(r0) | ((uint32_t)f2b(r1) << 16);
    o.y = (uint32_t)f2b(r2) | ((uint32_t)f2b(r3) << 16);
    xo[idx] = o;
  };
  proc(a, tid);
  if (tid < 32) proc(a2, 256 + tid);
}

// ---------------- spatial attention + fused qk-RMS: block=(bt,h), 4 waves x 64 queries ----------------
#define AK_STRIDE 104
#define VT_STRIDE 88
#define PS_STRIDE 72
__global__ __launch_bounds__(256) void attn_s_k(
    const uint16_t* __restrict__ qkv, uint16_t* __restrict__ out,
    const float* __restrict__ qn, const float* __restrict__ kn)
{
  __shared__ __align__(16) uint16_t Ks[64 * AK_STRIDE];
  __shared__ __align__(16) uint16_t Vt[80 * VT_STRIDE];
  __shared__ __align__(16) uint16_t Ps[4 * 64 * PS_STRIDE];
  const int bh = blockIdx.x;
  const int bt = bh >> 4, h = bh & 15;
  const int tid = threadIdx.x;
  const int lane = tid & 63, wave = tid >> 6;
  const int l15 = lane & 15, quad = lane >> 4;
  const size_t rowbase = (size_t)bt * 256;
  const float scale = 0.1178511301977579f;  // 1/sqrt(72)

  union { uint4 u; bf16x8 v; } zu; zu.u = make_uint4(0, 0, 0, 0);
  const bf16x8 zero8 = zu.v;

  // per-lane qn weights for this lane's fragment slots
  float qw0[8], qw1[8], qw2[8];
#pragma unroll
  for (int j = 0; j < 8; j++) {
    qw0[j] = qn[quad * 8 + j];
    qw1[j] = qn[32 + quad * 8 + j];
    qw2[j] = (quad == 0) ? qn[64 + j] : 0.f;
  }
  // kn weights for the K-normalize pass (4 threads/row, 18 elems each)
  const int knpart = tid & 3;
  float knw[18];
#pragma unroll
  for (int j = 0; j < 18; j++) knw[j] = kn[knpart * 18 + j];

  // Q load + fused per-head RMS (row spread across 4 quads; shfl-reduce)
  bf16x8 qf[4][3];
#pragma unroll
  for (int mi = 0; mi < 4; mi++) {
    const uint16_t* qp = qkv + (rowbase + wave * 64 + mi * 16 + l15) * 3456 + h * 72;
    float f0[8], f1[8], f2[8];
    unpack8(((const uint4*)qp)[quad], f0);
    unpack8(((const uint4*)qp)[4 + quad], f1);
    uint4 u2 = (quad == 0) ? ((const uint4*)qp)[8] : make_uint4(0, 0, 0, 0);
    unpack8(u2, f2);
    float ss = 0.f;
#pragma unroll
    for (int j = 0; j < 8; j++) ss += f0[j] * f0[j] + f1[j] * f1[j] + f2[j] * f2[j];
    ss += __shfl_xor(ss, 16);
    ss += __shfl_xor(ss, 32);
    const float rs = rsqrtf(ss * (1.f / 72.f) + 1e-6f);
#pragma unroll
    for (int j = 0; j < 8; j++) {
      f0[j] *= rs * qw0[j];
      f1[j] *= rs * qw1[j];
      f2[j] *= rs * qw2[j];
    }
    qf[mi][0] = pack8(f0);
    qf[mi][1] = pack8(f1);
    qf[mi][2] = (quad == 0) ? pack8(f2) : zero8;
  }

  f32x4 oacc[4][5];
#pragma unroll
  for (int mi = 0; mi < 4; mi++)
#pragma unroll
    for (int dt = 0; dt < 5; dt++)
      oacc[mi][dt] = (f32x4){0.f, 0.f, 0.f, 0.f};
  float mrun[4][4], lrun[4][4];
#pragma unroll
  for (int mi = 0; mi < 4; mi++)
#pragma unroll
    for (int i = 0; i < 4; i++) { mrun[mi][i] = -1e30f; lrun[mi][i] = 0.f; }

  uint16_t* psw = &Ps[wave * 64 * PS_STRIDE];

  for (int c = 0; c < 4; c++) {
    __syncthreads();
    for (int idx = tid; idx < 576; idx += 256) {
      const int rr = idx / 9, cc = idx - rr * 9;
      const uint16_t* kg = qkv + (rowbase + c * 64 + rr) * 3456 + 1152 + h * 72 + cc * 8;
      *(uint4*)&Ks[rr * AK_STRIDE + cc * 8] = *(const uint4*)kg;
      uint4 vv = *(const uint4*)(kg + 1152);
      const uint16_t* e = (const uint16_t*)&vv;
#pragma unroll
      for (int j = 0; j < 8; j++) Vt[(cc * 8 + j) * VT_STRIDE + rr] = e[j];
    }
    __syncthreads();

    // fused K per-head RMS in LDS: 64 rows, 4 threads/row x 18 elems
    {
      const int r = tid >> 2;
      uint16_t* kr = &Ks[r * AK_STRIDE + knpart * 18];
      float loc[18];
      float ss = 0.f;
#pragma unroll
      for (int j = 0; j < 18; j++) { loc[j] = b2f(kr[j]); ss += loc[j] * loc[j]; }
      ss += __shfl_xor(ss, 1);
      ss += __shfl_xor(ss, 2);
      const float rs = rsqrtf(ss * (1.f / 72.f) + 1e-6f);
#pragma unroll
      for (int j = 0; j < 18; j++) kr[j] = f2b(loc[j] * rs * knw[j]);
    }
    __syncthreads();

    f32x4 s[4][4];
#pragma unroll
    for (int mi = 0; mi < 4; mi++)
#pragma unroll
      for (int ni = 0; ni < 4; ni++)
        s[mi][ni] = (f32x4){0.f, 0.f, 0.f, 0.f};
#pragma unroll
    for (int ni = 0; ni < 4; ni++) {
      bf16x8 kf0 = *(const bf16x8*)&Ks[(ni * 16 + l15) * AK_STRIDE + quad * 8];
      bf16x8 kf1 = *(const bf16x8*)&Ks[(ni * 16 + l15) * AK_STRIDE + 32 + quad * 8];
      bf16x8 kf2 = (quad == 0) ? *(const bf16x8*)&Ks[(ni * 16 + l15) * AK_STRIDE + 64] : zero8;
#pragma unroll
      for (int mi = 0; mi < 4; mi++) {
        s[mi][ni] = __builtin_amdgcn_mfma_f32_16x16x32_bf16(qf[mi][0], kf0, s[mi][ni], 0, 0, 0);
        s[mi][ni] = __builtin_amdgcn_mfma_f32_16x16x32_bf16(qf[mi][1], kf1, s[mi][ni], 0, 0, 0);
        s[mi][ni] = __builtin_amdgcn_mfma_f32_16x16x32_bf16(qf[mi][2], kf2, s[mi][ni], 0, 0, 0);
      }
    }

#pragma unroll
    for (int mi = 0; mi < 4; mi++) {
#pragma unroll
      for (int i = 0; i < 4; i++) {
        float mx = fmaxf(fmaxf(s[mi][0][i], s[mi][1][i]), fmaxf(s[mi][2][i], s[mi][3][i])) * scale;
#pragma unroll
        for (int d = 1; d < 16; d <<= 1) mx = fmaxf(mx, __shfl_xor(mx, d));
        const float mnew = fmaxf(mrun[mi][i], mx);
        const float corr = __expf(mrun[mi][i] - mnew);
        mrun[mi][i] = mnew;
        float psum = 0.f;
#pragma unroll
        for (int ni = 0; ni < 4; ni++) {
          const float p = __expf(s[mi][ni][i] * scale - mnew);
          s[mi][ni][i] = p;
          psum += p;
        }
#pragma unroll
        for (int d = 1; d < 16; d <<= 1) psum += __shfl_xor(psum, d);
        lrun[mi][i] = lrun[mi][i] * corr + psum;
#pragma unroll
        for (int dt = 0; dt < 5; dt++) oacc[mi][dt][i] *= corr;
      }
    }

#pragma unroll
    for (int mi = 0; mi < 4; mi++)
#pragma unroll
      for (int ni = 0; ni < 4; ni++)
#pragma unroll
        for (int i = 0; i < 4; i++)
          psw[(mi * 16 + quad * 4 + i) * PS_STRIDE + ni * 16 + l15] = f2b(s[mi][ni][i]);

#pragma unroll
    for (int kk = 0; kk < 2; kk++) {
      bf16x8 pf[4];
#pragma unroll
      for (int mi = 0; mi < 4; mi++)
        pf[mi] = *(const bf16x8*)&psw[(mi * 16 + l15) * PS_STRIDE + kk * 32 + quad * 8];
#pragma unroll
      for (int dt = 0; dt < 5; dt++) {
        bf16x8 vf = *(const bf16x8*)&Vt[(dt * 16 + l15) * VT_STRIDE + kk * 32 + quad * 8];
#pragma unroll
        for (int mi = 0; mi < 4; mi++)
          oacc[mi][dt] = __builtin_amdgcn_mfma_f32_16x16x32_bf16(pf[mi], vf, oacc[mi][dt], 0, 0, 0);
      }
    }
  }

#pragma unroll
  for (int mi = 0; mi < 4; mi++) {
#pragma unroll
    for (int i = 0; i < 4; i++) {
      const float inv = 1.f / lrun[mi][i];
      const size_t orow = rowbase + wave * 64 + mi * 16 + quad * 4 + i;
#pragma unroll
      for (int dt = 0; dt < 5; dt++) {
        const int d = dt * 16 + l15;
        if (d < 72) out[orow * 1152 + h * 72 + d] = f2b(oacc[mi][dt][i] * inv);
      }
    }
  }
}

// ---------------- temporal attention (T=16) + fused qk-RMS ----------------
__global__ __launch_bounds__(128) void attn_t_k(
    const uint16_t* __restrict__ qkv, uint16_t* __restrict__ out,
    const float* __restrict__ qn, const float* __restrict__ kn)
{
  const int blk = blockIdx.x;
  const int bl = blk >> 1, hg = blk & 1;
  const int b = bl >> 8, l = bl & 255;
  const int tid = threadIdx.x;
  const int hh = tid >> 4, tq = tid & 15;
  const int h = hg * 8 + hh;
  __shared__ __align__(16) uint16_t kb[8 * 16 * 72];
  __shared__ __align__(16) uint16_t vb[8 * 16 * 72];

#pragma unroll
  for (int it = 0; it < 9; it++) {
    const int idx = tid + it * 128;
    const int rowL = idx / 9, cc = idx % 9;
    const int hhL = rowL >> 4, tL = rowL & 15;
    const size_t grow = (size_t)b * 4096 + (size_t)tL * 256 + l;
    const int colk = 1152 + (hg * 8 + hhL) * 72 + cc * 8;
    ((uint4*)&kb[rowL * 72])[cc] = *(const uint4*)(qkv + grow * 3456 + colk);
    ((uint4*)&vb[rowL * 72])[cc] = *(const uint4*)(qkv + grow * 3456 + colk + 1152);
  }
  __syncthreads();

  // fused K per-head RMS: 128 rows, one thread each
  {
    uint16_t* kr = &kb[tid * 72];
    float ss = 0.f;
#pragma unroll
    for (int i = 0; i < 9; i++) {
      float f[8]; unpack8(((const uint4*)kr)[i], f);
#pragma unroll
      for (int j = 0; j < 8; j++) ss += f[j] * f[j];
    }
    const float rs = rsqrtf(ss * (1.f / 72.f) + 1e-6f);
#pragma unroll
    for (int i = 0; i < 9; i++) {
      float f[8]; unpack8(((const uint4*)kr)[i], f);
#pragma unroll
      for (int j = 0; j < 8; j++) f[j] *= rs * kn[i * 8 + j];
      union { uint4 u; bf16x8 v; } r;
      r.v = pack8(f);
      ((uint4*)kr)[i] = r.u;
    }
  }
  __syncthreads();

  float q[72];
  const size_t qrow = (size_t)b * 4096 + (size_t)tq * 256 + l;
  {
    const uint16_t* qp = qkv + qrow * 3456 + h * 72;
#pragma unroll
    for (int i = 0; i < 9; i++) unpack8(((const uint4*)qp)[i], q + i * 8);
    float ssq = 0.f;
#pragma unroll
    for (int d = 0; d < 72; d++) ssq += q[d] * q[d];
    const float rsq = rsqrtf(ssq * (1.f / 72.f) + 1e-6f);
#pragma unroll
    for (int d = 0; d < 72; d++) q[d] *= rsq * qn[d];
  }
  const float scale = 0.1178511301977579f;
  float s[16];
#pragma unroll
  for (int m = 0; m < 16; m++) {
    const uint4* kr = (const uint4*)&kb[(hh * 16 + m) * 72];
    float a = 0.f;
#pragma unroll
    for (int i = 0; i < 9; i++) {
      float kf[8]; unpack8(kr[i], kf);
#pragma unroll
      for (int j = 0; j < 8; j++) a += q[i * 8 + j] * kf[j];
    }
    s[m] = a * scale;
  }
  float mx = -1e30f;
#pragma unroll
  for (int m = 0; m < 16; m++) mx = fmaxf(mx, s[m]);
  float sum = 0.f;
#pragma unroll
  for (int m = 0; m < 16; m++) { s[m] = __expf(s[m] - mx); sum += s[m]; }
  const float inv = 1.f / sum;
  float o[72];
#pragma unroll
  for (int d = 0; d < 72; d++) o[d] = 0.f;
#pragma unroll
  for (int m = 0; m < 16; m++) {
    const float p = s[m];
    const uint4* vr = (const uint4*)&vb[(hh * 16 + m) * 72];
#pragma unroll
    for (int i = 0; i < 9; i++) {
      float vf[8]; unpack8(vr[i], vf);
#pragma unroll
      for (int j = 0; j < 8; j++) o[i * 8 + j] += p * vf[j];
    }
  }
  uint16_t* op = out + qrow * 1152 + h * 72;
#pragma unroll
  for (int d = 0; d < 72; d++) op[d] = f2b(o[d] * inv);
}

// ---------------- transpose + fp32->bf16: in(KxN) -> out(NxK) ----------------
__global__ __launch_bounds__(256) void transcvt_k(
    const float* __restrict__ in, uint16_t* __restrict__ out, int K, int N)
{
  __shared__ float t[32][33];
  const int n0 = blockIdx.x * 32, k0 = blockIdx.y * 32;
  const int tx = threadIdx.x & 31, ty = threadIdx.x >> 5;
#pragma unroll
  for (int i = 0; i < 32; i += 8)
    t[ty + i][tx] = in[(size_t)(k0 + ty + i) * N + n0 + tx];
  __syncthreads();
#pragma unroll
  for (int i = 0; i < 32; i += 8)
    out[(size_t)(n0 + ty + i) * K + k0 + tx] = f2b(t[tx][ty + i]);
}

// ---------------- transpose + cvt + x1/x2 group-interleave for W12 ----------------
// out row n <- source col s(n) = ((n&32)?3072:0) + (n>>6)*32 + (n&31).
__global__ __launch_bounds__(256) void transcvt_w12i_k(
    const float* __restrict__ in, uint16_t* __restrict__ out)
{
  __shared__ float t[32][33];
  const int n0 = blockIdx.x * 32, k0 = blockIdx.y * 32;
  const int tx = threadIdx.x & 31, ty = threadIdx.x >> 5;
  const int scol = ((n0 & 32) ? 3072 : 0) + ((n0 >> 6) << 5) + tx;
#pragma unroll
  for (int i = 0; i < 32; i += 8)
    t[ty + i][tx] = in[(size_t)(k0 + ty + i) * 6144 + scol];
  __syncthreads();
#pragma unroll
  for (int i = 0; i < 32; i += 8)
    out[(size_t)(n0 + ty + i) * 1152 + k0 + tx] = f2b(t[tx][ty + i]);
}

// ---------------- ada path ----------------
__global__ void siluc_k(const float* __restrict__ c, float* __restrict__ cs) {
  const int i = blockIdx.x * 256 + threadIdx.x;
  if (i < 2304) { const float v = c[i]; cs[i] = v / (1.f + __expf(-v)); }
}

#define ADA_KS 18
#define ADA_RK 64
__global__ __launch_bounds__(256) void ada_part_k(
    const float* __restrict__ cs, const float* __restrict__ W,
    float* __restrict__ part)
{
  const int col = blockIdx.x * 256 + threadIdx.x;
  const int ks = blockIdx.y;
  const int k0 = ks * ADA_RK;
  __shared__ float sc0[ADA_RK], sc1[ADA_RK];
  if (threadIdx.x < ADA_RK) sc0[threadIdx.x] = cs[k0 + threadIdx.x];
  else if (threadIdx.x < 2 * ADA_RK) sc1[threadIdx.x - ADA_RK] = cs[1152 + k0 + threadIdx.x - ADA_RK];
  __syncthreads();
  if (col >= 10368) return;
  const float* Wp = W + (size_t)k0 * 10368 + col;
  float s0 = 0.f, s1 = 0.f;
#pragma unroll 8
  for (int r = 0; r < ADA_RK; r++) {
    const float wv = Wp[(size_t)r * 10368];
    s0 += sc0[r] * wv;
    s1 += sc1[r] * wv;
  }
  part[(size_t)(ks * 2 + 0) * 10368 + col] = s0;
  part[(size_t)(ks * 2 + 1) * 10368 + col] = s1;
}

__global__ __launch_bounds__(256) void ada_reduce_k(
    const float* __restrict__ part, const float* __restrict__ bias,
    float* __restrict__ chv)
{
  const int col = blockIdx.x * 256 + threadIdx.x;
  if (col >= 10368) return;
  float s0 = bias[col], s1 = bias[col];
#pragma unroll
  for (int ks = 0; ks < ADA_KS; ks++) {
    s0 += part[(size_t)(ks * 2 + 0) * 10368 + col];
    s1 += part[(size_t)(ks * 2 + 1) * 10368 + col];
  }
  chv[col] = s0;
  chv[10368 + col] = s1;
}

extern "C" void kernel_launch(void* const* d_in, const int* in_sizes, int n_in,
                              void* d_out, int out_size, void* d_ws, size_t ws_size,
                              hipStream_t stream)
{
  const float* Xin     = (const float*)d_in[0];
  const float* c_in    = (const float*)d_in[1];
  const float* norm1w  = (const float*)d_in[2];
  const float* norm2w  = (const float*)d_in[3];
  const float* norm3w  = (const float*)d_in[4];
  const float* qn_s    = (const float*)d_in[5];
  const float* kn_s    = (const float*)d_in[6];
  const float* qkv_s_w = (const float*)d_in[7];
  const float* qkv_s_b = (const float*)d_in[8];
  const float* proj_s_w= (const float*)d_in[9];
  const float* proj_s_b= (const float*)d_in[10];
  const float* qn_t    = (const float*)d_in[11];
  const float* kn_t    = (const float*)d_in[12];
  const float* qkv_t_w = (const float*)d_in[13];
  const float* qkv_t_b = (const float*)d_in[14];
  const float* proj_t_w= (const float*)d_in[15];
  const float* proj_t_b= (const float*)d_in[16];
  const float* w12_w   = (const float*)d_in[17];
  const float* w12_b   = (const float*)d_in[18];
  const float* w3_w    = (const float*)d_in[19];
  const float* w3_b    = (const float*)d_in[20];
  const float* ada_w   = (const float*)d_in[21];
  const float* ada_b   = (const float*)d_in[22];

  float* X = (float*)d_out;  // fp32 residual accumulator; first written by proj_s

  char* wsb = (char*)d_ws; size_t off = 0;
  auto alloc = [&](size_t bytes) -> void* {
    void* p = wsb + off; off += bytes; off = (off + 255) & ~(size_t)255; return p;
  };
  uint16_t* XN    = (uint16_t*)alloc((size_t)8192 * 1152 * 2);  // xn / attn_out
  uint16_t* QKV   = (uint16_t*)alloc((size_t)8192 * 3456 * 2);  // qkv; later reused as H (8192x3072)
  uint16_t* H     = QKV;
  uint16_t* WqkvS = (uint16_t*)alloc((size_t)3456 * 1152 * 2);
  uint16_t* WprojS= (uint16_t*)alloc((size_t)1152 * 1152 * 2);
  uint16_t* WqkvT = (uint16_t*)alloc((size_t)3456 * 1152 * 2);
  uint16_t* WprojT= (uint16_t*)alloc((size_t)1152 * 1152 * 2);
  uint16_t* W12T  = (uint16_t*)alloc((size_t)6144 * 1152 * 2);  // group-interleaved x1/x2
  uint16_t* W3T   = (uint16_t*)alloc((size_t)1152 * 3072 * 2);
  float* CH = (float*)alloc((size_t)2 * 10368 * 4);
  float* CS = (float*)alloc((size_t)2 * 1152 * 4);
  float* APART = (float*)alloc((size_t)ADA_KS * 2 * 10368 * 4);

  siluc_k<<<9, 256, 0, stream>>>(c_in, CS);
  ada_part_k<<<dim3(41, ADA_KS), 256, 0, stream>>>(CS, ada_w, APART);
  ada_reduce_k<<<41, 256, 0, stream>>>(APART, ada_b, CH);

  transcvt_k<<<dim3(3456 / 32, 1152 / 32), 256, 0, stream>>>(qkv_s_w, WqkvS, 1152, 3456);
  transcvt_k<<<dim3(1152 / 32, 1152 / 32), 256, 0, stream>>>(proj_s_w, WprojS, 1152, 1152);
  transcvt_k<<<dim3(3456 / 32, 1152 / 32), 256, 0, stream>>>(qkv_t_w, WqkvT, 1152, 3456);
  transcvt_k<<<dim3(1152 / 32, 1152 / 32), 256, 0, stream>>>(proj_t_w, WprojT, 1152, 1152);
  transcvt_w12i_k<<<dim3(6144 / 32, 1152 / 32), 256, 0, stream>>>(w12_w, W12T);
  transcvt_k<<<dim3(1152 / 32, 3072 / 32), 256, 0, stream>>>(w3_w, W3T, 3072, 1152);

  // ---- spatial attention ----
  rmsnorm_k<<<8192, 256, 0, stream>>>(Xin, norm1w, CH, 0, 1, XN);
  gemm_k<<<27 * 64, 256, 0, stream>>>(XN, 1152, WqkvS, qkv_s_b, QKV, nullptr, nullptr, nullptr,
                                      3456, 1152, 0);
  attn_s_k<<<512, 256, 0, stream>>>(QKV, XN, qn_s, kn_s);
  gemm_k<<<9 * 64, 256, 0, stream>>>(XN, 1152, WprojS, proj_s_b, nullptr, X, Xin, CH + 2 * 1152,
                                     1152, 1152, 1);

  // ---- temporal attention ----
  rmsnorm_k<<<8192, 256, 0, stream>>>(X, norm2w, CH, 3, 4, XN);
  gemm_k<<<27 * 64, 256, 0, stream>>>(XN, 1152, WqkvT, qkv_t_b, QKV, nullptr, nullptr, nullptr,
                                      3456, 1152, 0);
  attn_t_k<<<1024, 128, 0, stream>>>(QKV, XN, qn_t, kn_t);
  gemm_k<<<9 * 64, 256, 0, stream>>>(XN, 1152, WprojT, proj_t_b, nullptr, X, X, CH + 5 * 1152,
                                     1152, 1152, 1);

  // ---- MLP: fused w12+swiglu (H = silu(x1)*x2, 8192x3072), then w3 ----
  rmsnorm_k<<<8192, 256, 0, stream>>>(X, norm3w, CH, 6, 7, XN);
  gemm256_sw_k<<<32 * 24, 512, 0, stream>>>(XN, 1152, W12T, w12_b, H, 1152);
  gemm_k<<<9 * 64, 256, 0, stream>>>(H, 3072, W3T, w3_b, nullptr, X, X, CH + 8 * 1152,
                                     1152, 3072, 1);
}

// Round 7
// 882.531 us; speedup vs baseline: 1.6200x; 1.0377x over previous
//
#include <hip/hip_runtime.h>
#include <stdint.h>

typedef __bf16 bf16x8 __attribute__((ext_vector_type(8)));
typedef float f32x4 __attribute__((ext_vector_type(4)));

__device__ __forceinline__ float b2f(uint32_t u) {
  union { uint32_t i; float f; } v; v.i = u << 16; return v.f;
}
__device__ __forceinline__ uint16_t f2b(float f) {
  union { float f; uint32_t i; } v; v.f = f;
  uint32_t r = (v.i + 0x7fffu + ((v.i >> 16) & 1u)) >> 16;
  return (uint16_t)r;
}
__device__ __forceinline__ void unpack8(uint4 u, float* f) {
  f[0] = b2f(u.x & 0xffffu); f[1] = b2f(u.x >> 16);
  f[2] = b2f(u.y & 0xffffu); f[3] = b2f(u.y >> 16);
  f[4] = b2f(u.z & 0xffffu); f[5] = b2f(u.z >> 16);
  f[6] = b2f(u.w & 0xffffu); f[7] = b2f(u.w >> 16);
}
__device__ __forceinline__ bf16x8 pack8(const float* f) {
  union { uint4 u; bf16x8 v; } r;
  r.u.x = (uint32_t)f2b(f[0]) | ((uint32_t)f2b(f[1]) << 16);
  r.u.y = (uint32_t)f2b(f[2]) | ((uint32_t)f2b(f[3]) << 16);
  r.u.z = (uint32_t)f2b(f[4]) | ((uint32_t)f2b(f[5]) << 16);
  r.u.w = (uint32_t)f2b(f[6]) | ((uint32_t)f2b(f[7]) << 16);
  return r.v;
}

__device__ __forceinline__ void gl2lds16(const void* g, void* l) {
  __builtin_amdgcn_global_load_lds(
      (const __attribute__((address_space(1))) void*)g,
      (__attribute__((address_space(3))) void*)l, 16, 0, 0);
}

// ---------------- 128x128 bf16 GEMM: C(MxN) = A(MxK,lda) * Bt(NxK)^T ----------------
// M fixed at 8192 (64 m-tiles). XCD-aware swizzle. Double-buffered async staging.
// LDS granule XOR-swizzle (2-bit) applied on per-lane GLOBAL source + fragment read.
// mode 0: outb[r*N+c] = bf16(acc + bias[c])
// mode 1: outf[r*N+c] = resid[r*N+c] + gate[(r>>12)*10368 + c] * (acc + bias[c])
__global__ __launch_bounds__(256) void gemm_k(
    const uint16_t* __restrict__ A, int lda,
    const uint16_t* __restrict__ Bt,
    const float* __restrict__ bias,
    uint16_t* __restrict__ outb,
    float* __restrict__ outf, const float* __restrict__ resid,
    const float* __restrict__ gate,
    int N, int K, int mode)
{
  __shared__ __align__(16) uint16_t As[2][128 * 32];
  __shared__ __align__(16) uint16_t Bs[2][128 * 32];
  const int tid = threadIdx.x;
  const int xcd = blockIdx.x & 7;
  const int slot = blockIdx.x >> 3;
  const int mt = xcd * 8 + (slot & 7);
  const int nt = slot >> 3;
  const int row0 = mt * 128, col0 = nt * 128;

  const int lane = tid & 63, wave = tid >> 6;
  const int l15 = lane & 15, quad = lane >> 4;
  const int wm = (wave & 1) * 64, wn = (wave >> 1) * 64;

  f32x4 acc[4][4];
  const f32x4 zero = {0.f, 0.f, 0.f, 0.f};
  for (int i = 0; i < 4; i++)
    for (int j = 0; j < 4; j++)
      acc[i][j] = zero;

  const int rseg = wave * 32 + (lane >> 2);
  const int kseg8 = (((lane & 3) ^ ((lane >> 2) & 3) ^ ((lane >> 4) & 3))) * 8;
  const uint16_t* gA = A + (size_t)(row0 + rseg) * lda + kseg8;
  const uint16_t* gB = Bt + (size_t)(col0 + rseg) * K + kseg8;
  const size_t rowA16 = (size_t)16 * lda;
  const size_t rowB16 = (size_t)16 * K;
  const int woff = wave * 2048;

  const int gsw = ((quad ^ (l15 & 3) ^ ((l15 >> 2) & 3))) * 8;

  gl2lds16(gA,          (char*)As[0] + woff);
  gl2lds16(gA + rowA16, (char*)As[0] + woff + 1024);
  gl2lds16(gB,          (char*)Bs[0] + woff);
  gl2lds16(gB + rowB16, (char*)Bs[0] + woff + 1024);

  for (int k0 = 0; k0 < K; k0 += 32) {
    const int cur = (k0 >> 5) & 1;
    __syncthreads();
    if (k0 + 32 < K) {
      const int nxt = cur ^ 1;
      gl2lds16(gA + k0 + 32,          (char*)As[nxt] + woff);
      gl2lds16(gA + rowA16 + k0 + 32, (char*)As[nxt] + woff + 1024);
      gl2lds16(gB + k0 + 32,          (char*)Bs[nxt] + woff);
      gl2lds16(gB + rowB16 + k0 + 32, (char*)Bs[nxt] + woff + 1024);
    }

    bf16x8 af[4], bfr[4];
#pragma unroll
    for (int i = 0; i < 4; i++) {
      af[i]  = *(const bf16x8*)&As[cur][(wm + i * 16 + l15) * 32 + gsw];
      bfr[i] = *(const bf16x8*)&Bs[cur][(wn + i * 16 + l15) * 32 + gsw];
    }
#pragma unroll
    for (int mi = 0; mi < 4; mi++)
#pragma unroll
      for (int ni = 0; ni < 4; ni++)
        acc[mi][ni] = __builtin_amdgcn_mfma_f32_16x16x32_bf16(af[mi], bfr[ni], acc[mi][ni], 0, 0, 0);
  }

#pragma unroll
  for (int mi = 0; mi < 4; mi++) {
#pragma unroll
    for (int ni = 0; ni < 4; ni++) {
      const int colg = col0 + wn + ni * 16 + l15;
      const float bv = bias ? bias[colg] : 0.f;
#pragma unroll
      for (int i = 0; i < 4; i++) {
        const int rowg = row0 + wm + mi * 16 + quad * 4 + i;
        const float v = acc[mi][ni][i] + bv;
        const size_t idx = (size_t)rowg * N + colg;
        if (mode == 0) {
          outb[idx] = f2b(v);
        } else {
          const int b = rowg >> 12;  // T*L = 4096 rows per batch
          outf[idx] = resid[idx] + gate[b * 10368 + colg] * v;
        }
      }
    }
  }
}

// ================= 256x256 lockstep 8-phase bf16 GEMM, mode-0, N-guarded (qkv) ======
// Grid = 32 m-tiles * NTn n-tiles; B buffer row-padded to NTn*256; stores guarded
// by colg < N (garbage pad rows only reach guarded-out columns).
__global__ __launch_bounds__(512, 2) void gemm256_k(
    const uint16_t* __restrict__ A, int lda,
    const uint16_t* __restrict__ Bt,
    const float* __restrict__ bias,
    uint16_t* __restrict__ outb,
    int N, int K)
{
  __shared__ __align__(16) uint16_t L[65536];
  const int tid = threadIdx.x;
  const int lane = tid & 63, wave = tid >> 6;
  const int l15 = lane & 15, quad = lane >> 4;
  const int wm = (wave >> 2) * 128, wn = (wave & 3) * 64;

  const int xcd = blockIdx.x & 7;
  const int slot = blockIdx.x >> 3;
  const int mt = xcd * 4 + (slot & 3);
  const int nt = slot >> 2;
  const int row0 = mt * 256, col0 = nt * 256;

  const int NTk = K >> 6;

  const uint16_t* Ag = A + (size_t)row0 * lda;
  const uint16_t* Bg = Bt + (size_t)col0 * K;

  const int sX = (lane & 7) ^ (lane >> 3);
  const int laneRowA = lane >> 3;
  const int laneK8A = sX * 8;
  const int laneRowB = 2 * (lane >> 3) + ((sX >> 2) & 1);
  const int laneK8B = (sX & 3) * 8;
  const int rA0 = ((wave * 16) & 63) + (((wave * 16) >> 6) << 7);
  const int rB0 = wave * 32;

#define STAGE_A(BUF, SUB, KT) do { \
    const uint16_t* g_ = Ag + (size_t)(rA0 + (SUB) * 64 + laneRowA) * lda + (size_t)(KT) * 64 + laneK8A; \
    uint16_t* l_ = (uint16_t*)&L[(BUF) * 32768 + (rA0 + (SUB) * 64) * 64]; \
    gl2lds16(g_, l_); \
    gl2lds16(g_ + (size_t)8 * lda, l_ + 512); \
  } while (0)

#define STAGE_B(BUF, HALF, KT) do { \
    const uint16_t* g_ = Bg + (size_t)(rB0 + laneRowB) * K + (size_t)(KT) * 64 + (HALF) * 32 + laneK8B; \
    uint16_t* l_ = (uint16_t*)&L[(BUF) * 32768 + 16384 + (HALF) * 8192 + rB0 * 32]; \
    gl2lds16(g_, l_); \
    gl2lds16(g_ + (size_t)16 * K, l_ + 512); \
  } while (0)

  f32x4 acc[8][4];
#pragma unroll
  for (int i = 0; i < 8; i++)
#pragma unroll
    for (int j = 0; j < 4; j++)
      acc[i][j] = (f32x4){0.f, 0.f, 0.f, 0.f};

  bf16x8 a_[4], b_[4];

#define PHASE(CUR, KK, QM, READB, STAGE_STMT, VM_STMT) do { \
    _Pragma("unroll") for (int mi = 0; mi < 4; mi++) \
      a_[mi] = *(const bf16x8*)&L[(CUR) * 32768 + (wm + (QM) * 64 + mi * 16 + l15) * 64 + \
                                  ((((KK) * 4 + quad) ^ (l15 & 7)) * 8)]; \
    if (READB) { \
      _Pragma("unroll") for (int ni = 0; ni < 4; ni++) \
        b_[ni] = *(const bf16x8*)&L[(CUR) * 32768 + 16384 + (KK) * 8192 + \
                                    ((wn >> 1) + ni * 8 + (l15 >> 1)) * 64 + \
                                    ((((((l15 & 1) << 2) | quad)) ^ (l15 >> 1)) * 8)]; \
    } \
    STAGE_STMT; \
    __builtin_amdgcn_sched_barrier(0); \
    __builtin_amdgcn_s_barrier(); \
    asm volatile("s_waitcnt lgkmcnt(0)" ::: "memory"); \
    __builtin_amdgcn_sched_barrier(0); \
    __builtin_amdgcn_s_setprio(1); \
    _Pragma("unroll") for (int mi = 0; mi < 4; mi++) \
      _Pragma("unroll") for (int ni = 0; ni < 4; ni++) \
        acc[(QM) * 4 + mi][ni] = __builtin_amdgcn_mfma_f32_16x16x32_bf16( \
            a_[mi], b_[ni], acc[(QM) * 4 + mi][ni], 0, 0, 0); \
    __builtin_amdgcn_s_setprio(0); \
    __builtin_amdgcn_sched_barrier(0); \
    VM_STMT; \
    __builtin_amdgcn_sched_barrier(0); \
    __builtin_amdgcn_s_barrier(); \
    __builtin_amdgcn_sched_barrier(0); \
  } while (0)

#define TILE(CUR, T) do { \
    PHASE(CUR, 0, 0, 1, { if ((T) + 1 < NTk) STAGE_B((CUR) ^ 1, 1, (T) + 1); }, {}); \
    PHASE(CUR, 0, 1, 0, { if ((T) + 1 < NTk) STAGE_A((CUR) ^ 1, 1, (T) + 1); }, {}); \
    PHASE(CUR, 1, 0, 1, { if ((T) + 2 < NTk) STAGE_B((CUR), 0, (T) + 2); }, {}); \
    PHASE(CUR, 1, 1, 0, { if ((T) + 2 < NTk) STAGE_A((CUR), 0, (T) + 2); }, \
      { if ((T) + 2 < NTk) { asm volatile("s_waitcnt vmcnt(4)" ::: "memory"); } \
        else               { asm volatile("s_waitcnt vmcnt(0)" ::: "memory"); } }); \
  } while (0)

  STAGE_A(0, 0, 0); STAGE_A(0, 1, 0); STAGE_B(0, 0, 0); STAGE_B(0, 1, 0);
  STAGE_A(1, 0, 1); STAGE_B(1, 0, 1);
  asm volatile("s_waitcnt vmcnt(4)" ::: "memory");
  __builtin_amdgcn_sched_barrier(0);
  __builtin_amdgcn_s_barrier();
  __builtin_amdgcn_sched_barrier(0);

  for (int t = 0; t < NTk; t += 2) {
    TILE(0, t);
    TILE(1, t + 1);
  }

#undef PHASE
#undef TILE
#undef STAGE_A
#undef STAGE_B

#pragma unroll
  for (int mi = 0; mi < 8; mi++) {
#pragma unroll
    for (int ni = 0; ni < 4; ni++) {
      const int colg = col0 + wn + ni * 16 + l15;
      if (colg < N) {
        const float bv = bias[colg];
#pragma unroll
        for (int i = 0; i < 4; i++) {
          const int rowg = row0 + wm + mi * 16 + quad * 4 + i;
          outb[(size_t)rowg * N + colg] = f2b(acc[mi][ni][i] + bv);
        }
      }
    }
  }
}

// ================= 256x256 lockstep 8-phase bf16 GEMM + fused swiglu (w12 only) ======
// W12T row layout: n = group*64 + local; local<32 -> x1 col (group*32+local),
// local>=32 -> x2 col (3072 + group*32 + local-32). A wave's ni in {0,1} frags
// hold x1, ni in {2,3} the MATCHING x2 -> pair in-register, no shfl, no divergence.
__global__ __launch_bounds__(512, 2) void gemm256_sw_k(
    const uint16_t* __restrict__ A, int lda,
    const uint16_t* __restrict__ Bt,
    const float* __restrict__ bias,
    uint16_t* __restrict__ outh,
    int K)
{
  __shared__ __align__(16) uint16_t L[65536];
  const int tid = threadIdx.x;
  const int lane = tid & 63, wave = tid >> 6;
  const int l15 = lane & 15, quad = lane >> 4;
  const int wm = (wave >> 2) * 128, wn = (wave & 3) * 64;

  const int xcd = blockIdx.x & 7;
  const int slot = blockIdx.x >> 3;
  const int mt = xcd * 4 + (slot & 3);
  const int nt = slot >> 2;
  const int row0 = mt * 256, col0 = nt * 256;

  const int NTk = K >> 6;

  const uint16_t* Ag = A + (size_t)row0 * lda;
  const uint16_t* Bg = Bt + (size_t)col0 * K;

  const int sX = (lane & 7) ^ (lane >> 3);
  const int laneRowA = lane >> 3;
  const int laneK8A = sX * 8;
  const int laneRowB = 2 * (lane >> 3) + ((sX >> 2) & 1);
  const int laneK8B = (sX & 3) * 8;
  const int rA0 = ((wave * 16) & 63) + (((wave * 16) >> 6) << 7);
  const int rB0 = wave * 32;

#define STAGE_A(BUF, SUB, KT) do { \
    const uint16_t* g_ = Ag + (size_t)(rA0 + (SUB) * 64 + laneRowA) * lda + (size_t)(KT) * 64 + laneK8A; \
    uint16_t* l_ = (uint16_t*)&L[(BUF) * 32768 + (rA0 + (SUB) * 64) * 64]; \
    gl2lds16(g_, l_); \
    gl2lds16(g_ + (size_t)8 * lda, l_ + 512); \
  } while (0)

#define STAGE_B(BUF, HALF, KT) do { \
    const uint16_t* g_ = Bg + (size_t)(rB0 + laneRowB) * K + (size_t)(KT) * 64 + (HALF) * 32 + laneK8B; \
    uint16_t* l_ = (uint16_t*)&L[(BUF) * 32768 + 16384 + (HALF) * 8192 + rB0 * 32]; \
    gl2lds16(g_, l_); \
    gl2lds16(g_ + (size_t)16 * K, l_ + 512); \
  } while (0)

  f32x4 acc[8][4];
#pragma unroll
  for (int i = 0; i < 8; i++)
#pragma unroll
    for (int j = 0; j < 4; j++)
      acc[i][j] = (f32x4){0.f, 0.f, 0.f, 0.f};

  bf16x8 a_[4], b_[4];

#define PHASE(CUR, KK, QM, READB, STAGE_STMT, VM_STMT) do { \
    _Pragma("unroll") for (int mi = 0; mi < 4; mi++) \
      a_[mi] = *(const bf16x8*)&L[(CUR) * 32768 + (wm + (QM) * 64 + mi * 16 + l15) * 64 + \
                                  ((((KK) * 4 + quad) ^ (l15 & 7)) * 8)]; \
    if (READB) { \
      _Pragma("unroll") for (int ni = 0; ni < 4; ni++) \
        b_[ni] = *(const bf16x8*)&L[(CUR) * 32768 + 16384 + (KK) * 8192 + \
                                    ((wn >> 1) + ni * 8 + (l15 >> 1)) * 64 + \
                                    ((((((l15 & 1) << 2) | quad)) ^ (l15 >> 1)) * 8)]; \
    } \
    STAGE_STMT; \
    __builtin_amdgcn_sched_barrier(0); \
    __builtin_amdgcn_s_barrier(); \
    asm volatile("s_waitcnt lgkmcnt(0)" ::: "memory"); \
    __builtin_amdgcn_sched_barrier(0); \
    __builtin_amdgcn_s_setprio(1); \
    _Pragma("unroll") for (int mi = 0; mi < 4; mi++) \
      _Pragma("unroll") for (int ni = 0; ni < 4; ni++) \
        acc[(QM) * 4 + mi][ni] = __builtin_amdgcn_mfma_f32_16x16x32_bf16( \
            a_[mi], b_[ni], acc[(QM) * 4 + mi][ni], 0, 0, 0); \
    __builtin_amdgcn_s_setprio(0); \
    __builtin_amdgcn_sched_barrier(0); \
    VM_STMT; \
    __builtin_amdgcn_sched_barrier(0); \
    __builtin_amdgcn_s_barrier(); \
    __builtin_amdgcn_sched_barrier(0); \
  } while (0)

#define TILE(CUR, T) do { \
    PHASE(CUR, 0, 0, 1, { if ((T) + 1 < NTk) STAGE_B((CUR) ^ 1, 1, (T) + 1); }, {}); \
    PHASE(CUR, 0, 1, 0, { if ((T) + 1 < NTk) STAGE_A((CUR) ^ 1, 1, (T) + 1); }, {}); \
    PHASE(CUR, 1, 0, 1, { if ((T) + 2 < NTk) STAGE_B((CUR), 0, (T) + 2); }, {}); \
    PHASE(CUR, 1, 1, 0, { if ((T) + 2 < NTk) STAGE_A((CUR), 0, (T) + 2); }, \
      { if ((T) + 2 < NTk) { asm volatile("s_waitcnt vmcnt(4)" ::: "memory"); } \
        else               { asm volatile("s_waitcnt vmcnt(0)" ::: "memory"); } }); \
  } while (0)

  STAGE_A(0, 0, 0); STAGE_A(0, 1, 0); STAGE_B(0, 0, 0); STAGE_B(0, 1, 0);
  STAGE_A(1, 0, 1); STAGE_B(1, 0, 1);
  asm volatile("s_waitcnt vmcnt(4)" ::: "memory");
  __builtin_amdgcn_sched_barrier(0);
  __builtin_amdgcn_s_barrier();
  __builtin_amdgcn_sched_barrier(0);

  for (int t = 0; t < NTk; t += 2) {
    TILE(0, t);
    TILE(1, t + 1);
  }

#undef PHASE
#undef TILE
#undef STAGE_A
#undef STAGE_B

  // epilogue: fused swiglu, x1 in ni, x2 in ni+2 (same thread) -> no shfl/divergence
  const int hbase = ((col0 + wn) >> 6) * 32;
#pragma unroll
  for (int mi = 0; mi < 8; mi++) {
#pragma unroll
    for (int ni = 0; ni < 2; ni++) {
      const int p = hbase + ni * 16 + l15;
      const float b1 = bias[p];
      const float b2 = bias[3072 + p];
#pragma unroll
      for (int i = 0; i < 4; i++) {
        const int rowg = row0 + wm + mi * 16 + quad * 4 + i;
        const float v1 = acc[mi][ni][i] + b1;
        const float v2 = acc[mi][ni + 2][i] + b2;
        const float hres = v1 / (1.f + __expf(-v1)) * v2;
        outh[(size_t)rowg * 3072 + p] = f2b(hres);
      }
    }
  }
}

// ---------------- RMS + adaLN modulate (float4 vectorized) ----------------
__global__ __launch_bounds__(256) void rmsnorm_k(
    const float* __restrict__ x, const float* __restrict__ w,
    const float* __restrict__ chv, int shsel, int scsel,
    uint16_t* __restrict__ xn)
{
  const int row = blockIdx.x;
  const int b = row >> 12;
  const int tid = threadIdx.x;
  const float4* x4 = (const float4*)(x + (size_t)row * 1152);  // 288 float4
  float4 a = x4[tid];
  float ss = a.x * a.x + a.y * a.y + a.z * a.z + a.w * a.w;
  float4 a2 = {0.f, 0.f, 0.f, 0.f};
  if (tid < 32) {
    a2 = x4[256 + tid];
    ss += a2.x * a2.x + a2.y * a2.y + a2.z * a2.z + a2.w * a2.w;
  }
  for (int off = 32; off > 0; off >>= 1) ss += __shfl_down(ss, off);
  __shared__ float red[4];
  if ((tid & 63) == 0) red[tid >> 6] = ss;
  __syncthreads();
  const float tot = red[0] + red[1] + red[2] + red[3];
  const float rs = rsqrtf(tot * (1.f / 1152.f) + 1e-6f);
  const float4* w4 = (const float4*)w;
  const float4* sh4 = (const float4*)(chv + b * 10368 + shsel * 1152);
  const float4* sc4 = (const float4*)(chv + b * 10368 + scsel * 1152);
  uint2* xo = (uint2*)(xn + (size_t)row * 1152);
  auto proc = [&](float4 av, int idx) {
    const float4 wv = w4[idx], shv = sh4[idx], scv = sc4[idx];
    const float r0 = av.x * rs * wv.x * (1.f + scv.x) + shv.x;
    const float r1 = av.y * rs * wv.y * (1.f + scv.y) + shv.y;
    const float r2 = av.z * rs * wv.z * (1.f + scv.z) + shv.z;
    const float r3 = av.w * rs * wv.w * (1.f + scv.w) + shv.w;
    uint2 o;
    o.x = (uint32_t)f2b(r0) | ((uint32_t)f2b(r1) << 16);
    o.y = (uint32_t)f2b(r2) | ((uint32_t)f2b(r3) << 16);
    xo[idx] = o;
  };
  proc(a, tid);
  if (tid < 32) proc(a2, 256 + tid);
}

// ---------------- spatial attention + fused qk-RMS: block=(bt,h), 4 waves x 64 queries ----------------
#define AK_STRIDE 104
#define VT_STRIDE 88
#define PS_STRIDE 72
__global__ __launch_bounds__(256) void attn_s_k(
    const uint16_t* __restrict__ qkv, uint16_t* __restrict__ out,
    const float* __restrict__ qn, const float* __restrict__ kn)
{
  __shared__ __align__(16) uint16_t Ks[64 * AK_STRIDE];
  __shared__ __align__(16) uint16_t Vt[80 * VT_STRIDE];
  __shared__ __align__(16) uint16_t Ps[4 * 64 * PS_STRIDE];
  const int bh = blockIdx.x;
  const int bt = bh >> 4, h = bh & 15;
  const int tid = threadIdx.x;
  const int lane = tid & 63, wave = tid >> 6;
  const int l15 = lane & 15, quad = lane >> 4;
  const size_t rowbase = (size_t)bt * 256;
  const float scale = 0.1178511301977579f;  // 1/sqrt(72)

  union { uint4 u; bf16x8 v; } zu; zu.u = make_uint4(0, 0, 0, 0);
  const bf16x8 zero8 = zu.v;

  float qw0[8], qw1[8], qw2[8];
#pragma unroll
  for (int j = 0; j < 8; j++) {
    qw0[j] = qn[quad * 8 + j];
    qw1[j] = qn[32 + quad * 8 + j];
    qw2[j] = (quad == 0) ? qn[64 + j] : 0.f;
  }
  const int knpart = tid & 3;
  float knw[18];
#pragma unroll
  for (int j = 0; j < 18; j++) knw[j] = kn[knpart * 18 + j];

  bf16x8 qf[4][3];
#pragma unroll
  for (int mi = 0; mi < 4; mi++) {
    const uint16_t* qp = qkv + (rowbase + wave * 64 + mi * 16 + l15) * 3456 + h * 72;
    float f0[8], f1[8], f2[8];
    unpack8(((const uint4*)qp)[quad], f0);
    unpack8(((const uint4*)qp)[4 + quad], f1);
    uint4 u2 = (quad == 0) ? ((const uint4*)qp)[8] : make_uint4(0, 0, 0, 0);
    unpack8(u2, f2);
    float ss = 0.f;
#pragma unroll
    for (int j = 0; j < 8; j++) ss += f0[j] * f0[j] + f1[j] * f1[j] + f2[j] * f2[j];
    ss += __shfl_xor(ss, 16);
    ss += __shfl_xor(ss, 32);
    const float rs = rsqrtf(ss * (1.f / 72.f) + 1e-6f);
#pragma unroll
    for (int j = 0; j < 8; j++) {
      f0[j] *= rs * qw0[j];
      f1[j] *= rs * qw1[j];
      f2[j] *= rs * qw2[j];
    }
    qf[mi][0] = pack8(f0);
    qf[mi][1] = pack8(f1);
    qf[mi][2] = (quad == 0) ? pack8(f2) : zero8;
  }

  f32x4 oacc[4][5];
#pragma unroll
  for (int mi = 0; mi < 4; mi++)
#pragma unroll
    for (int dt = 0; dt < 5; dt++)
      oacc[mi][dt] = (f32x4){0.f, 0.f, 0.f, 0.f};
  float mrun[4][4], lrun[4][4];
#pragma unroll
  for (int mi = 0; mi < 4; mi++)
#pragma unroll
    for (int i = 0; i < 4; i++) { mrun[mi][i] = -1e30f; lrun[mi][i] = 0.f; }

  uint16_t* psw = &Ps[wave * 64 * PS_STRIDE];

  for (int c = 0; c < 4; c++) {
    __syncthreads();
    for (int idx = tid; idx < 576; idx += 256) {
      const int rr = idx / 9, cc = idx - rr * 9;
      const uint16_t* kg = qkv + (rowbase + c * 64 + rr) * 3456 + 1152 + h * 72 + cc * 8;
      *(uint4*)&Ks[rr * AK_STRIDE + cc * 8] = *(const uint4*)kg;
      uint4 vv = *(const uint4*)(kg + 1152);
      const uint16_t* e = (const uint16_t*)&vv;
#pragma unroll
      for (int j = 0; j < 8; j++) Vt[(cc * 8 + j) * VT_STRIDE + rr] = e[j];
    }
    __syncthreads();

    // fused K per-head RMS in LDS: 64 rows, 4 threads/row x 18 elems
    {
      const int r = tid >> 2;
      uint16_t* kr = &Ks[r * AK_STRIDE + knpart * 18];
      float loc[18];
      float ss = 0.f;
#pragma unroll
      for (int j = 0; j < 18; j++) { loc[j] = b2f(kr[j]); ss += loc[j] * loc[j]; }
      ss += __shfl_xor(ss, 1);
      ss += __shfl_xor(ss, 2);
      const float rs = rsqrtf(ss * (1.f / 72.f) + 1e-6f);
#pragma unroll
      for (int j = 0; j < 18; j++) kr[j] = f2b(loc[j] * rs * knw[j]);
    }
    __syncthreads();

    f32x4 s[4][4];
#pragma unroll
    for (int mi = 0; mi < 4; mi++)
#pragma unroll
      for (int ni = 0; ni < 4; ni++)
        s[mi][ni] = (f32x4){0.f, 0.f, 0.f, 0.f};
#pragma unroll
    for (int ni = 0; ni < 4; ni++) {
      bf16x8 kf0 = *(const bf16x8*)&Ks[(ni * 16 + l15) * AK_STRIDE + quad * 8];
      bf16x8 kf1 = *(const bf16x8*)&Ks[(ni * 16 + l15) * AK_STRIDE + 32 + quad * 8];
      bf16x8 kf2 = (quad == 0) ? *(const bf16x8*)&Ks[(ni * 16 + l15) * AK_STRIDE + 64] : zero8;
#pragma unroll
      for (int mi = 0; mi < 4; mi++) {
        s[mi][ni] = __builtin_amdgcn_mfma_f32_16x16x32_bf16(qf[mi][0], kf0, s[mi][ni], 0, 0, 0);
        s[mi][ni] = __builtin_amdgcn_mfma_f32_16x16x32_bf16(qf[mi][1], kf1, s[mi][ni], 0, 0, 0);
        s[mi][ni] = __builtin_amdgcn_mfma_f32_16x16x32_bf16(qf[mi][2], kf2, s[mi][ni], 0, 0, 0);
      }
    }

#pragma unroll
    for (int mi = 0; mi < 4; mi++) {
#pragma unroll
      for (int i = 0; i < 4; i++) {
        float mx = fmaxf(fmaxf(s[mi][0][i], s[mi][1][i]), fmaxf(s[mi][2][i], s[mi][3][i])) * scale;
#pragma unroll
        for (int d = 1; d < 16; d <<= 1) mx = fmaxf(mx, __shfl_xor(mx, d));
        const float mnew = fmaxf(mrun[mi][i], mx);
        const float corr = __expf(mrun[mi][i] - mnew);
        mrun[mi][i] = mnew;
        float psum = 0.f;
#pragma unroll
        for (int ni = 0; ni < 4; ni++) {
          const float p = __expf(s[mi][ni][i] * scale - mnew);
          s[mi][ni][i] = p;
          psum += p;
        }
#pragma unroll
        for (int d = 1; d < 16; d <<= 1) psum += __shfl_xor(psum, d);
        lrun[mi][i] = lrun[mi][i] * corr + psum;
#pragma unroll
        for (int dt = 0; dt < 5; dt++) oacc[mi][dt][i] *= corr;
      }
    }

#pragma unroll
    for (int mi = 0; mi < 4; mi++)
#pragma unroll
      for (int ni = 0; ni < 4; ni++)
#pragma unroll
        for (int i = 0; i < 4; i++)
          psw[(mi * 16 + quad * 4 + i) * PS_STRIDE + ni * 16 + l15] = f2b(s[mi][ni][i]);

#pragma unroll
    for (int kk = 0; kk < 2; kk++) {
      bf16x8 pf[4];
#pragma unroll
      for (int mi = 0; mi < 4; mi++)
        pf[mi] = *(const bf16x8*)&psw[(mi * 16 + l15) * PS_STRIDE + kk * 32 + quad * 8];
#pragma unroll
      for (int dt = 0; dt < 5; dt++) {
        bf16x8 vf = *(const bf16x8*)&Vt[(dt * 16 + l15) * VT_STRIDE + kk * 32 + quad * 8];
#pragma unroll
        for (int mi = 0; mi < 4; mi++)
          oacc[mi][dt] = __builtin_amdgcn_mfma_f32_16x16x32_bf16(pf[mi], vf, oacc[mi][dt], 0, 0, 0);
      }
    }
  }

#pragma unroll
  for (int mi = 0; mi < 4; mi++) {
#pragma unroll
    for (int i = 0; i < 4; i++) {
      const float inv = 1.f / lrun[mi][i];
      const size_t orow = rowbase + wave * 64 + mi * 16 + quad * 4 + i;
#pragma unroll
      for (int dt = 0; dt < 5; dt++) {
        const int d = dt * 16 + l15;
        if (d < 72) out[orow * 1152 + h * 72 + d] = f2b(oacc[mi][dt][i] * inv);
      }
    }
  }
}

// ---------------- temporal attention (T=16) + fused qk-RMS ----------------
__global__ __launch_bounds__(128) void attn_t_k(
    const uint16_t* __restrict__ qkv, uint16_t* __restrict__ out,
    const float* __restrict__ qn, const float* __restrict__ kn)
{
  const int blk = blockIdx.x;
  const int bl = blk >> 1, hg = blk & 1;
  const int b = bl >> 8, l = bl & 255;
  const int tid = threadIdx.x;
  const int hh = tid >> 4, tq = tid & 15;
  const int h = hg * 8 + hh;
  __shared__ __align__(16) uint16_t kb[8 * 16 * 72];
  __shared__ __align__(16) uint16_t vb[8 * 16 * 72];

#pragma unroll
  for (int it = 0; it < 9; it++) {
    const int idx = tid + it * 128;
    const int rowL = idx / 9, cc = idx % 9;
    const int hhL = rowL >> 4, tL = rowL & 15;
    const size_t grow = (size_t)b * 4096 + (size_t)tL * 256 + l;
    const int colk = 1152 + (hg * 8 + hhL) * 72 + cc * 8;
    ((uint4*)&kb[rowL * 72])[cc] = *(const uint4*)(qkv + grow * 3456 + colk);
    ((uint4*)&vb[rowL * 72])[cc] = *(const uint4*)(qkv + grow * 3456 + colk + 1152);
  }
  __syncthreads();

  // fused K per-head RMS: 128 rows, one thread each
  {
    uint16_t* kr = &kb[tid * 72];
    float ss = 0.f;
#pragma unroll
    for (int i = 0; i < 9; i++) {
      float f[8]; unpack8(((const uint4*)kr)[i], f);
#pragma unroll
      for (int j = 0; j < 8; j++) ss += f[j] * f[j];
    }
    const float rs = rsqrtf(ss * (1.f / 72.f) + 1e-6f);
#pragma unroll
    for (int i = 0; i < 9; i++) {
      float f[8]; unpack8(((const uint4*)kr)[i], f);
#pragma unroll
      for (int j = 0; j < 8; j++) f[j] *= rs * kn[i * 8 + j];
      union { uint4 u; bf16x8 v; } r;
      r.v = pack8(f);
      ((uint4*)kr)[i] = r.u;
    }
  }
  __syncthreads();

  float q[72];
  const size_t qrow = (size_t)b * 4096 + (size_t)tq * 256 + l;
  {
    const uint16_t* qp = qkv + qrow * 3456 + h * 72;
#pragma unroll
    for (int i = 0; i < 9; i++) unpack8(((const uint4*)qp)[i], q + i * 8);
    float ssq = 0.f;
#pragma unroll
    for (int d = 0; d < 72; d++) ssq += q[d] * q[d];
    const float rsq = rsqrtf(ssq * (1.f / 72.f) + 1e-6f);
#pragma unroll
    for (int d = 0; d < 72; d++) q[d] *= rsq * qn[d];
  }
  const float scale = 0.1178511301977579f;
  float s[16];
#pragma unroll
  for (int m = 0; m < 16; m++) {
    const uint4* kr = (const uint4*)&kb[(hh * 16 + m) * 72];
    float a = 0.f;
#pragma unroll
    for (int i = 0; i < 9; i++) {
      float kf[8]; unpack8(kr[i], kf);
#pragma unroll
      for (int j = 0; j < 8; j++) a += q[i * 8 + j] * kf[j];
    }
    s[m] = a * scale;
  }
  float mx = -1e30f;
#pragma unroll
  for (int m = 0; m < 16; m++) mx = fmaxf(mx, s[m]);
  float sum = 0.f;
#pragma unroll
  for (int m = 0; m < 16; m++) { s[m] = __expf(s[m] - mx); sum += s[m]; }
  const float inv = 1.f / sum;
  float o[72];
#pragma unroll
  for (int d = 0; d < 72; d++) o[d] = 0.f;
#pragma unroll
  for (int m = 0; m < 16; m++) {
    const float p = s[m];
    const uint4* vr = (const uint4*)&vb[(hh * 16 + m) * 72];
#pragma unroll
    for (int i = 0; i < 9; i++) {
      float vf[8]; unpack8(vr[i], vf);
#pragma unroll
      for (int j = 0; j < 8; j++) o[i * 8 + j] += p * vf[j];
    }
  }
  uint16_t* op = out + qrow * 1152 + h * 72;
#pragma unroll
  for (int d = 0; d < 72; d++) op[d] = f2b(o[d] * inv);
}

// ---------------- transpose + fp32->bf16: in(KxN) -> out(NxK) ----------------
__global__ __launch_bounds__(256) void transcvt_k(
    const float* __restrict__ in, uint16_t* __restrict__ out, int K, int N)
{
  __shared__ float t[32][33];
  const int n0 = blockIdx.x * 32, k0 = blockIdx.y * 32;
  const int tx = threadIdx.x & 31, ty = threadIdx.x >> 5;
#pragma unroll
  for (int i = 0; i < 32; i += 8)
    t[ty + i][tx] = in[(size_t)(k0 + ty + i) * N + n0 + tx];
  __syncthreads();
#pragma unroll
  for (int i = 0; i < 32; i += 8)
    out[(size_t)(n0 + ty + i) * K + k0 + tx] = f2b(t[tx][ty + i]);
}

// ---------------- transpose + cvt + x1/x2 group-interleave for W12 ----------------
// out row n <- source col s(n) = ((n&32)?3072:0) + (n>>6)*32 + (n&31).
__global__ __launch_bounds__(256) void transcvt_w12i_k(
    const float* __restrict__ in, uint16_t* __restrict__ out)
{
  __shared__ float t[32][33];
  const int n0 = blockIdx.x * 32, k0 = blockIdx.y * 32;
  const int tx = threadIdx.x & 31, ty = threadIdx.x >> 5;
  const int scol = ((n0 & 32) ? 3072 : 0) + ((n0 >> 6) << 5) + tx;
#pragma unroll
  for (int i = 0; i < 32; i += 8)
    t[ty + i][tx] = in[(size_t)(k0 + ty + i) * 6144 + scol];
  __syncthreads();
#pragma unroll
  for (int i = 0; i < 32; i += 8)
    out[(size_t)(n0 + ty + i) * 1152 + k0 + tx] = f2b(t[tx][ty + i]);
}

// ---------------- ada path ----------------
__global__ void siluc_k(const float* __restrict__ c, float* __restrict__ cs) {
  const int i = blockIdx.x * 256 + threadIdx.x;
  if (i < 2304) { const float v = c[i]; cs[i] = v / (1.f + __expf(-v)); }
}

#define ADA_KS 18
#define ADA_RK 64
__global__ __launch_bounds__(256) void ada_part_k(
    const float* __restrict__ cs, const float* __restrict__ W,
    float* __restrict__ part)
{
  const int col = blockIdx.x * 256 + threadIdx.x;
  const int ks = blockIdx.y;
  const int k0 = ks * ADA_RK;
  __shared__ float sc0[ADA_RK], sc1[ADA_RK];
  if (threadIdx.x < ADA_RK) sc0[threadIdx.x] = cs[k0 + threadIdx.x];
  else if (threadIdx.x < 2 * ADA_RK) sc1[threadIdx.x - ADA_RK] = cs[1152 + k0 + threadIdx.x - ADA_RK];
  __syncthreads();
  if (col >= 10368) return;
  const float* Wp = W + (size_t)k0 * 10368 + col;
  float s0 = 0.f, s1 = 0.f;
#pragma unroll 8
  for (int r = 0; r < ADA_RK; r++) {
    const float wv = Wp[(size_t)r * 10368];
    s0 += sc0[r] * wv;
    s1 += sc1[r] * wv;
  }
  part[(size_t)(ks * 2 + 0) * 10368 + col] = s0;
  part[(size_t)(ks * 2 + 1) * 10368 + col] = s1;
}

__global__ __launch_bounds__(256) void ada_reduce_k(
    const float* __restrict__ part, const float* __restrict__ bias,
    float* __restrict__ chv)
{
  const int col = blockIdx.x * 256 + threadIdx.x;
  if (col >= 10368) return;
  float s0 = bias[col], s1 = bias[col];
#pragma unroll
  for (int ks = 0; ks < ADA_KS; ks++) {
    s0 += part[(size_t)(ks * 2 + 0) * 10368 + col];
    s1 += part[(size_t)(ks * 2 + 1) * 10368 + col];
  }
  chv[col] = s0;
  chv[10368 + col] = s1;
}

extern "C" void kernel_launch(void* const* d_in, const int* in_sizes, int n_in,
                              void* d_out, int out_size, void* d_ws, size_t ws_size,
                              hipStream_t stream)
{
  const float* Xin     = (const float*)d_in[0];
  const float* c_in    = (const float*)d_in[1];
  const float* norm1w  = (const float*)d_in[2];
  const float* norm2w  = (const float*)d_in[3];
  const float* norm3w  = (const float*)d_in[4];
  const float* qn_s    = (const float*)d_in[5];
  const float* kn_s    = (const float*)d_in[6];
  const float* qkv_s_w = (const float*)d_in[7];
  const float* qkv_s_b = (const float*)d_in[8];
  const float* proj_s_w= (const float*)d_in[9];
  const float* proj_s_b= (const float*)d_in[10];
  const float* qn_t    = (const float*)d_in[11];
  const float* kn_t    = (const float*)d_in[12];
  const float* qkv_t_w = (const float*)d_in[13];
  const float* qkv_t_b = (const float*)d_in[14];
  const float* proj_t_w= (const float*)d_in[15];
  const float* proj_t_b= (const float*)d_in[16];
  const float* w12_w   = (const float*)d_in[17];
  const float* w12_b   = (const float*)d_in[18];
  const float* w3_w    = (const float*)d_in[19];
  const float* w3_b    = (const float*)d_in[20];
  const float* ada_w   = (const float*)d_in[21];
  const float* ada_b   = (const float*)d_in[22];

  float* X = (float*)d_out;  // fp32 residual accumulator; first written by proj_s

  char* wsb = (char*)d_ws; size_t off = 0;
  auto alloc = [&](size_t bytes) -> void* {
    void* p = wsb + off; off += bytes; off = (off + 255) & ~(size_t)255; return p;
  };
  uint16_t* XN    = (uint16_t*)alloc((size_t)8192 * 1152 * 2);  // xn / attn_out
  uint16_t* QKV   = (uint16_t*)alloc((size_t)8192 * 3456 * 2);  // qkv; later reused as H (8192x3072)
  uint16_t* H     = QKV;
  uint16_t* WqkvS = (uint16_t*)alloc((size_t)3584 * 1152 * 2);  // padded to 14*256 rows
  uint16_t* WprojS= (uint16_t*)alloc((size_t)1152 * 1152 * 2);
  uint16_t* WqkvT = (uint16_t*)alloc((size_t)3584 * 1152 * 2);  // padded to 14*256 rows
  uint16_t* WprojT= (uint16_t*)alloc((size_t)1152 * 1152 * 2);
  uint16_t* W12T  = (uint16_t*)alloc((size_t)6144 * 1152 * 2);  // group-interleaved x1/x2
  uint16_t* W3T   = (uint16_t*)alloc((size_t)1152 * 3072 * 2);
  float* CH = (float*)alloc((size_t)2 * 10368 * 4);
  float* CS = (float*)alloc((size_t)2 * 1152 * 4);
  float* APART = (float*)alloc((size_t)ADA_KS * 2 * 10368 * 4);

  siluc_k<<<9, 256, 0, stream>>>(c_in, CS);
  ada_part_k<<<dim3(41, ADA_KS), 256, 0, stream>>>(CS, ada_w, APART);
  ada_reduce_k<<<41, 256, 0, stream>>>(APART, ada_b, CH);

  transcvt_k<<<dim3(3456 / 32, 1152 / 32), 256, 0, stream>>>(qkv_s_w, WqkvS, 1152, 3456);
  transcvt_k<<<dim3(1152 / 32, 1152 / 32), 256, 0, stream>>>(proj_s_w, WprojS, 1152, 1152);
  transcvt_k<<<dim3(3456 / 32, 1152 / 32), 256, 0, stream>>>(qkv_t_w, WqkvT, 1152, 3456);
  transcvt_k<<<dim3(1152 / 32, 1152 / 32), 256, 0, stream>>>(proj_t_w, WprojT, 1152, 1152);
  transcvt_w12i_k<<<dim3(6144 / 32, 1152 / 32), 256, 0, stream>>>(w12_w, W12T);
  transcvt_k<<<dim3(1152 / 32, 3072 / 32), 256, 0, stream>>>(w3_w, W3T, 3072, 1152);

  // ---- spatial attention ----
  rmsnorm_k<<<8192, 256, 0, stream>>>(Xin, norm1w, CH, 0, 1, XN);
  gemm256_k<<<32 * 14, 512, 0, stream>>>(XN, 1152, WqkvS, qkv_s_b, QKV, 3456, 1152);
  attn_s_k<<<512, 256, 0, stream>>>(QKV, XN, qn_s, kn_s);
  gemm_k<<<9 * 64, 256, 0, stream>>>(XN, 1152, WprojS, proj_s_b, nullptr, X, Xin, CH + 2 * 1152,
                                     1152, 1152, 1);

  // ---- temporal attention ----
  rmsnorm_k<<<8192, 256, 0, stream>>>(X, norm2w, CH, 3, 4, XN);
  gemm256_k<<<32 * 14, 512, 0, stream>>>(XN, 1152, WqkvT, qkv_t_b, QKV, 3456, 1152);
  attn_t_k<<<1024, 128, 0, stream>>>(QKV, XN, qn_t, kn_t);
  gemm_k<<<9 * 64, 256, 0, stream>>>(XN, 1152, WprojT, proj_t_b, nullptr, X, X, CH + 5 * 1152,
                                     1152, 1152, 1);

  // ---- MLP: fused w12+swiglu (H = silu(x1)*x2, 8192x3072), then w3 ----
  rmsnorm_k<<<8192, 256, 0, stream>>>(X, norm3w, CH, 6, 7, XN);
  gemm256_sw_k<<<32 * 24, 512, 0, stream>>>(XN, 1152, W12T, w12_b, H, 1152);
  gemm_k<<<9 * 64, 256, 0, stream>>>(H, 3072, W3T, w3_b, nullptr, X, X, CH + 8 * 1152,
                                     1152, 3072, 1);
}

// Round 8
// 867.909 us; speedup vs baseline: 1.6473x; 1.0168x over previous
//
#include <hip/hip_runtime.h>
#include <stdint.h>

typedef __bf16 bf16x8 __attribute__((ext_vector_type(8)));
typedef float f32x4 __attribute__((ext_vector_type(4)));

__device__ __forceinline__ float b2f(uint32_t u) {
  union { uint32_t i; float f; } v; v.i = u << 16; return v.f;
}
__device__ __forceinline__ uint16_t f2b(float f) {
  union { float f; uint32_t i; } v; v.f = f;
  uint32_t r = (v.i + 0x7fffu + ((v.i >> 16) & 1u)) >> 16;
  return (uint16_t)r;
}
__device__ __forceinline__ void unpack8(uint4 u, float* f) {
  f[0] = b2f(u.x & 0xffffu); f[1] = b2f(u.x >> 16);
  f[2] = b2f(u.y & 0xffffu); f[3] = b2f(u.y >> 16);
  f[4] = b2f(u.z & 0xffffu); f[5] = b2f(u.z >> 16);
  f[6] = b2f(u.w & 0xffffu); f[7] = b2f(u.w >> 16);
}
__device__ __forceinline__ bf16x8 pack8(const float* f) {
  union { uint4 u; bf16x8 v; } r;
  r.u.x = (uint32_t)f2b(f[0]) | ((uint32_t)f2b(f[1]) << 16);
  r.u.y = (uint32_t)f2b(f[2]) | ((uint32_t)f2b(f[3]) << 16);
  r.u.z = (uint32_t)f2b(f[4]) | ((uint32_t)f2b(f[5]) << 16);
  r.u.w = (uint32_t)f2b(f[6]) | ((uint32_t)f2b(f[7]) << 16);
  return r.v;
}
__device__ __forceinline__ uint4 pack8u(const float* f) {
  uint4 u;
  u.x = (uint32_t)f2b(f[0]) | ((uint32_t)f2b(f[1]) << 16);
  u.y = (uint32_t)f2b(f[2]) | ((uint32_t)f2b(f[3]) << 16);
  u.z = (uint32_t)f2b(f[4]) | ((uint32_t)f2b(f[5]) << 16);
  u.w = (uint32_t)f2b(f[6]) | ((uint32_t)f2b(f[7]) << 16);
  return u;
}

__device__ __forceinline__ void gl2lds16(const void* g, void* l) {
  __builtin_amdgcn_global_load_lds(
      (const __attribute__((address_space(1))) void*)g,
      (__attribute__((address_space(3))) void*)l, 16, 0, 0);
}

// ---------------- 128x128 bf16 GEMM: C(MxN) = A(MxK,lda) * Bt(NxK)^T ----------------
// mode 0: outb[r*N+c] = bf16(acc + bias[c])
// mode 1: outf[r*N+c] = resid[r*N+c] + gate[(r>>12)*10368 + c] * (acc + bias[c])
__global__ __launch_bounds__(256) void gemm_k(
    const uint16_t* __restrict__ A, int lda,
    const uint16_t* __restrict__ Bt,
    const float* __restrict__ bias,
    uint16_t* __restrict__ outb,
    float* __restrict__ outf, const float* __restrict__ resid,
    const float* __restrict__ gate,
    int N, int K, int mode)
{
  __shared__ __align__(16) uint16_t As[2][128 * 32];
  __shared__ __align__(16) uint16_t Bs[2][128 * 32];
  const int tid = threadIdx.x;
  const int xcd = blockIdx.x & 7;
  const int slot = blockIdx.x >> 3;
  const int mt = xcd * 8 + (slot & 7);
  const int nt = slot >> 3;
  const int row0 = mt * 128, col0 = nt * 128;

  const int lane = tid & 63, wave = tid >> 6;
  const int l15 = lane & 15, quad = lane >> 4;
  const int wm = (wave & 1) * 64, wn = (wave >> 1) * 64;

  f32x4 acc[4][4];
  const f32x4 zero = {0.f, 0.f, 0.f, 0.f};
  for (int i = 0; i < 4; i++)
    for (int j = 0; j < 4; j++)
      acc[i][j] = zero;

  const int rseg = wave * 32 + (lane >> 2);
  const int kseg8 = (((lane & 3) ^ ((lane >> 2) & 3) ^ ((lane >> 4) & 3))) * 8;
  const uint16_t* gA = A + (size_t)(row0 + rseg) * lda + kseg8;
  const uint16_t* gB = Bt + (size_t)(col0 + rseg) * K + kseg8;
  const size_t rowA16 = (size_t)16 * lda;
  const size_t rowB16 = (size_t)16 * K;
  const int woff = wave * 2048;

  const int gsw = ((quad ^ (l15 & 3) ^ ((l15 >> 2) & 3))) * 8;

  gl2lds16(gA,          (char*)As[0] + woff);
  gl2lds16(gA + rowA16, (char*)As[0] + woff + 1024);
  gl2lds16(gB,          (char*)Bs[0] + woff);
  gl2lds16(gB + rowB16, (char*)Bs[0] + woff + 1024);

  for (int k0 = 0; k0 < K; k0 += 32) {
    const int cur = (k0 >> 5) & 1;
    __syncthreads();
    if (k0 + 32 < K) {
      const int nxt = cur ^ 1;
      gl2lds16(gA + k0 + 32,          (char*)As[nxt] + woff);
      gl2lds16(gA + rowA16 + k0 + 32, (char*)As[nxt] + woff + 1024);
      gl2lds16(gB + k0 + 32,          (char*)Bs[nxt] + woff);
      gl2lds16(gB + rowB16 + k0 + 32, (char*)Bs[nxt] + woff + 1024);
    }

    bf16x8 af[4], bfr[4];
#pragma unroll
    for (int i = 0; i < 4; i++) {
      af[i]  = *(const bf16x8*)&As[cur][(wm + i * 16 + l15) * 32 + gsw];
      bfr[i] = *(const bf16x8*)&Bs[cur][(wn + i * 16 + l15) * 32 + gsw];
    }
#pragma unroll
    for (int mi = 0; mi < 4; mi++)
#pragma unroll
      for (int ni = 0; ni < 4; ni++)
        acc[mi][ni] = __builtin_amdgcn_mfma_f32_16x16x32_bf16(af[mi], bfr[ni], acc[mi][ni], 0, 0, 0);
  }

#pragma unroll
  for (int mi = 0; mi < 4; mi++) {
#pragma unroll
    for (int ni = 0; ni < 4; ni++) {
      const int colg = col0 + wn + ni * 16 + l15;
      const float bv = bias ? bias[colg] : 0.f;
#pragma unroll
      for (int i = 0; i < 4; i++) {
        const int rowg = row0 + wm + mi * 16 + quad * 4 + i;
        const float v = acc[mi][ni][i] + bv;
        const size_t idx = (size_t)rowg * N + colg;
        if (mode == 0) {
          outb[idx] = f2b(v);
        } else {
          const int b = rowg >> 12;  // T*L = 4096 rows per batch
          outf[idx] = resid[idx] + gate[b * 10368 + colg] * v;
        }
      }
    }
  }
}

// ================= 256x256 lockstep 8-phase bf16 GEMM, mode-0, N-guarded (qkv) ======
__global__ __launch_bounds__(512, 2) void gemm256_k(
    const uint16_t* __restrict__ A, int lda,
    const uint16_t* __restrict__ Bt,
    const float* __restrict__ bias,
    uint16_t* __restrict__ outb,
    int N, int K)
{
  __shared__ __align__(16) uint16_t L[65536];
  const int tid = threadIdx.x;
  const int lane = tid & 63, wave = tid >> 6;
  const int l15 = lane & 15, quad = lane >> 4;
  const int wm = (wave >> 2) * 128, wn = (wave & 3) * 64;

  const int xcd = blockIdx.x & 7;
  const int slot = blockIdx.x >> 3;
  const int mt = xcd * 4 + (slot & 3);
  const int nt = slot >> 2;
  const int row0 = mt * 256, col0 = nt * 256;

  const int NTk = K >> 6;

  const uint16_t* Ag = A + (size_t)row0 * lda;
  const uint16_t* Bg = Bt + (size_t)col0 * K;

  const int sX = (lane & 7) ^ (lane >> 3);
  const int laneRowA = lane >> 3;
  const int laneK8A = sX * 8;
  const int laneRowB = 2 * (lane >> 3) + ((sX >> 2) & 1);
  const int laneK8B = (sX & 3) * 8;
  const int rA0 = ((wave * 16) & 63) + (((wave * 16) >> 6) << 7);
  const int rB0 = wave * 32;

#define STAGE_A(BUF, SUB, KT) do { \
    const uint16_t* g_ = Ag + (size_t)(rA0 + (SUB) * 64 + laneRowA) * lda + (size_t)(KT) * 64 + laneK8A; \
    uint16_t* l_ = (uint16_t*)&L[(BUF) * 32768 + (rA0 + (SUB) * 64) * 64]; \
    gl2lds16(g_, l_); \
    gl2lds16(g_ + (size_t)8 * lda, l_ + 512); \
  } while (0)

#define STAGE_B(BUF, HALF, KT) do { \
    const uint16_t* g_ = Bg + (size_t)(rB0 + laneRowB) * K + (size_t)(KT) * 64 + (HALF) * 32 + laneK8B; \
    uint16_t* l_ = (uint16_t*)&L[(BUF) * 32768 + 16384 + (HALF) * 8192 + rB0 * 32]; \
    gl2lds16(g_, l_); \
    gl2lds16(g_ + (size_t)16 * K, l_ + 512); \
  } while (0)

  f32x4 acc[8][4];
#pragma unroll
  for (int i = 0; i < 8; i++)
#pragma unroll
    for (int j = 0; j < 4; j++)
      acc[i][j] = (f32x4){0.f, 0.f, 0.f, 0.f};

  bf16x8 a_[4], b_[4];

#define PHASE(CUR, KK, QM, READB, STAGE_STMT, VM_STMT) do { \
    _Pragma("unroll") for (int mi = 0; mi < 4; mi++) \
      a_[mi] = *(const bf16x8*)&L[(CUR) * 32768 + (wm + (QM) * 64 + mi * 16 + l15) * 64 + \
                                  ((((KK) * 4 + quad) ^ (l15 & 7)) * 8)]; \
    if (READB) { \
      _Pragma("unroll") for (int ni = 0; ni < 4; ni++) \
        b_[ni] = *(const bf16x8*)&L[(CUR) * 32768 + 16384 + (KK) * 8192 + \
                                    ((wn >> 1) + ni * 8 + (l15 >> 1)) * 64 + \
                                    ((((((l15 & 1) << 2) | quad)) ^ (l15 >> 1)) * 8)]; \
    } \
    STAGE_STMT; \
    __builtin_amdgcn_sched_barrier(0); \
    __builtin_amdgcn_s_barrier(); \
    asm volatile("s_waitcnt lgkmcnt(0)" ::: "memory"); \
    __builtin_amdgcn_sched_barrier(0); \
    __builtin_amdgcn_s_setprio(1); \
    _Pragma("unroll") for (int mi = 0; mi < 4; mi++) \
      _Pragma("unroll") for (int ni = 0; ni < 4; ni++) \
        acc[(QM) * 4 + mi][ni] = __builtin_amdgcn_mfma_f32_16x16x32_bf16( \
            a_[mi], b_[ni], acc[(QM) * 4 + mi][ni], 0, 0, 0); \
    __builtin_amdgcn_s_setprio(0); \
    __builtin_amdgcn_sched_barrier(0); \
    VM_STMT; \
    __builtin_amdgcn_sched_barrier(0); \
    __builtin_amdgcn_s_barrier(); \
    __builtin_amdgcn_sched_barrier(0); \
  } while (0)

#define TILE(CUR, T) do { \
    PHASE(CUR, 0, 0, 1, { if ((T) + 1 < NTk) STAGE_B((CUR) ^ 1, 1, (T) + 1); }, {}); \
    PHASE(CUR, 0, 1, 0, { if ((T) + 1 < NTk) STAGE_A((CUR) ^ 1, 1, (T) + 1); }, {}); \
    PHASE(CUR, 1, 0, 1, { if ((T) + 2 < NTk) STAGE_B((CUR), 0, (T) + 2); }, {}); \
    PHASE(CUR, 1, 1, 0, { if ((T) + 2 < NTk) STAGE_A((CUR), 0, (T) + 2); }, \
      { if ((T) + 2 < NTk) { asm volatile("s_waitcnt vmcnt(4)" ::: "memory"); } \
        else               { asm volatile("s_waitcnt vmcnt(0)" ::: "memory"); } }); \
  } while (0)

  STAGE_A(0, 0, 0); STAGE_A(0, 1, 0); STAGE_B(0, 0, 0); STAGE_B(0, 1, 0);
  STAGE_A(1, 0, 1); STAGE_B(1, 0, 1);
  asm volatile("s_waitcnt vmcnt(4)" ::: "memory");
  __builtin_amdgcn_sched_barrier(0);
  __builtin_amdgcn_s_barrier();
  __builtin_amdgcn_sched_barrier(0);

  for (int t = 0; t < NTk; t += 2) {
    TILE(0, t);
    TILE(1, t + 1);
  }

#undef PHASE
#undef TILE
#undef STAGE_A
#undef STAGE_B

#pragma unroll
  for (int mi = 0; mi < 8; mi++) {
#pragma unroll
    for (int ni = 0; ni < 4; ni++) {
      const int colg = col0 + wn + ni * 16 + l15;
      if (colg < N) {
        const float bv = bias[colg];
#pragma unroll
        for (int i = 0; i < 4; i++) {
          const int rowg = row0 + wm + mi * 16 + quad * 4 + i;
          outb[(size_t)rowg * N + colg] = f2b(acc[mi][ni][i] + bv);
        }
      }
    }
  }
}

// ================= 256x256 lockstep 8-phase bf16 GEMM + fused swiglu (w12 only) ======
__global__ __launch_bounds__(512, 2) void gemm256_sw_k(
    const uint16_t* __restrict__ A, int lda,
    const uint16_t* __restrict__ Bt,
    const float* __restrict__ bias,
    uint16_t* __restrict__ outh,
    int K)
{
  __shared__ __align__(16) uint16_t L[65536];
  const int tid = threadIdx.x;
  const int lane = tid & 63, wave = tid >> 6;
  const int l15 = lane & 15, quad = lane >> 4;
  const int wm = (wave >> 2) * 128, wn = (wave & 3) * 64;

  const int xcd = blockIdx.x & 7;
  const int slot = blockIdx.x >> 3;
  const int mt = xcd * 4 + (slot & 3);
  const int nt = slot >> 2;
  const int row0 = mt * 256, col0 = nt * 256;

  const int NTk = K >> 6;

  const uint16_t* Ag = A + (size_t)row0 * lda;
  const uint16_t* Bg = Bt + (size_t)col0 * K;

  const int sX = (lane & 7) ^ (lane >> 3);
  const int laneRowA = lane >> 3;
  const int laneK8A = sX * 8;
  const int laneRowB = 2 * (lane >> 3) + ((sX >> 2) & 1);
  const int laneK8B = (sX & 3) * 8;
  const int rA0 = ((wave * 16) & 63) + (((wave * 16) >> 6) << 7);
  const int rB0 = wave * 32;

#define STAGE_A(BUF, SUB, KT) do { \
    const uint16_t* g_ = Ag + (size_t)(rA0 + (SUB) * 64 + laneRowA) * lda + (size_t)(KT) * 64 + laneK8A; \
    uint16_t* l_ = (uint16_t*)&L[(BUF) * 32768 + (rA0 + (SUB) * 64) * 64]; \
    gl2lds16(g_, l_); \
    gl2lds16(g_ + (size_t)8 * lda, l_ + 512); \
  } while (0)

#define STAGE_B(BUF, HALF, KT) do { \
    const uint16_t* g_ = Bg + (size_t)(rB0 + laneRowB) * K + (size_t)(KT) * 64 + (HALF) * 32 + laneK8B; \
    uint16_t* l_ = (uint16_t*)&L[(BUF) * 32768 + 16384 + (HALF) * 8192 + rB0 * 32]; \
    gl2lds16(g_, l_); \
    gl2lds16(g_ + (size_t)16 * K, l_ + 512); \
  } while (0)

  f32x4 acc[8][4];
#pragma unroll
  for (int i = 0; i < 8; i++)
#pragma unroll
    for (int j = 0; j < 4; j++)
      acc[i][j] = (f32x4){0.f, 0.f, 0.f, 0.f};

  bf16x8 a_[4], b_[4];

#define PHASE(CUR, KK, QM, READB, STAGE_STMT, VM_STMT) do { \
    _Pragma("unroll") for (int mi = 0; mi < 4; mi++) \
      a_[mi] = *(const bf16x8*)&L[(CUR) * 32768 + (wm + (QM) * 64 + mi * 16 + l15) * 64 + \
                                  ((((KK) * 4 + quad) ^ (l15 & 7)) * 8)]; \
    if (READB) { \
      _Pragma("unroll") for (int ni = 0; ni < 4; ni++) \
        b_[ni] = *(const bf16x8*)&L[(CUR) * 32768 + 16384 + (KK) * 8192 + \
                                    ((wn >> 1) + ni * 8 + (l15 >> 1)) * 64 + \
                                    ((((((l15 & 1) << 2) | quad)) ^ (l15 >> 1)) * 8)]; \
    } \
    STAGE_STMT; \
    __builtin_amdgcn_sched_barrier(0); \
    __builtin_amdgcn_s_barrier(); \
    asm volatile("s_waitcnt lgkmcnt(0)" ::: "memory"); \
    __builtin_amdgcn_sched_barrier(0); \
    __builtin_amdgcn_s_setprio(1); \
    _Pragma("unroll") for (int mi = 0; mi < 4; mi++) \
      _Pragma("unroll") for (int ni = 0; ni < 4; ni++) \
        acc[(QM) * 4 + mi][ni] = __builtin_amdgcn_mfma_f32_16x16x32_bf16( \
            a_[mi], b_[ni], acc[(QM) * 4 + mi][ni], 0, 0, 0); \
    __builtin_amdgcn_s_setprio(0); \
    __builtin_amdgcn_sched_barrier(0); \
    VM_STMT; \
    __builtin_amdgcn_sched_barrier(0); \
    __builtin_amdgcn_s_barrier(); \
    __builtin_amdgcn_sched_barrier(0); \
  } while (0)

#define TILE(CUR, T) do { \
    PHASE(CUR, 0, 0, 1, { if ((T) + 1 < NTk) STAGE_B((CUR) ^ 1, 1, (T) + 1); }, {}); \
    PHASE(CUR, 0, 1, 0, { if ((T) + 1 < NTk) STAGE_A((CUR) ^ 1, 1, (T) + 1); }, {}); \
    PHASE(CUR, 1, 0, 1, { if ((T) + 2 < NTk) STAGE_B((CUR), 0, (T) + 2); }, {}); \
    PHASE(CUR, 1, 1, 0, { if ((T) + 2 < NTk) STAGE_A((CUR), 0, (T) + 2); }, \
      { if ((T) + 2 < NTk) { asm volatile("s_waitcnt vmcnt(4)" ::: "memory"); } \
        else               { asm volatile("s_waitcnt vmcnt(0)" ::: "memory"); } }); \
  } while (0)

  STAGE_A(0, 0, 0); STAGE_A(0, 1, 0); STAGE_B(0, 0, 0); STAGE_B(0, 1, 0);
  STAGE_A(1, 0, 1); STAGE_B(1, 0, 1);
  asm volatile("s_waitcnt vmcnt(4)" ::: "memory");
  __builtin_amdgcn_sched_barrier(0);
  __builtin_amdgcn_s_barrier();
  __builtin_amdgcn_sched_barrier(0);

  for (int t = 0; t < NTk; t += 2) {
    TILE(0, t);
    TILE(1, t + 1);
  }

#undef PHASE
#undef TILE
#undef STAGE_A
#undef STAGE_B

  // epilogue: fused swiglu, x1 in ni, x2 in ni+2 (same thread) -> no shfl/divergence
  const int hbase = ((col0 + wn) >> 6) * 32;
#pragma unroll
  for (int mi = 0; mi < 8; mi++) {
#pragma unroll
    for (int ni = 0; ni < 2; ni++) {
      const int p = hbase + ni * 16 + l15;
      const float b1 = bias[p];
      const float b2 = bias[3072 + p];
#pragma unroll
      for (int i = 0; i < 4; i++) {
        const int rowg = row0 + wm + mi * 16 + quad * 4 + i;
        const float v1 = acc[mi][ni][i] + b1;
        const float v2 = acc[mi][ni + 2][i] + b2;
        const float hres = v1 / (1.f + __expf(-v1)) * v2;
        outh[(size_t)rowg * 3072 + p] = f2b(hres);
      }
    }
  }
}

// ---------------- RMS + adaLN modulate (float4 vectorized) ----------------
__global__ __launch_bounds__(256) void rmsnorm_k(
    const float* __restrict__ x, const float* __restrict__ w,
    const float* __restrict__ chv, int shsel, int scsel,
    uint16_t* __restrict__ xn)
{
  const int row = blockIdx.x;
  const int b = row >> 12;
  const int tid = threadIdx.x;
  const float4* x4 = (const float4*)(x + (size_t)row * 1152);  // 288 float4
  float4 a = x4[tid];
  float ss = a.x * a.x + a.y * a.y + a.z * a.z + a.w * a.w;
  float4 a2 = {0.f, 0.f, 0.f, 0.f};
  if (tid < 32) {
    a2 = x4[256 + tid];
    ss += a2.x * a2.x + a2.y * a2.y + a2.z * a2.z + a2.w * a2.w;
  }
  for (int off = 32; off > 0; off >>= 1) ss += __shfl_down(ss, off);
  __shared__ float red[4];
  if ((tid & 63) == 0) red[tid >> 6] = ss;
  __syncthreads();
  const float tot = red[0] + red[1] + red[2] + red[3];
  const float rs = rsqrtf(tot * (1.f / 1152.f) + 1e-6f);
  const float4* w4 = (const float4*)w;
  const float4* sh4 = (const float4*)(chv + b * 10368 + shsel * 1152);
  const float4* sc4 = (const float4*)(chv + b * 10368 + scsel * 1152);
  uint2* xo = (uint2*)(xn + (size_t)row * 1152);
  auto proc = [&](float4 av, int idx) {
    const float4 wv = w4[idx], shv = sh4[idx], scv = sc4[idx];
    const float r0 = av.x * rs * wv.x * (1.f + scv.x) + shv.x;
    const float r1 = av.y * rs * wv.y * (1.f + scv.y) + shv.y;
    const float r2 = av.z * rs * wv.z * (1.f + scv.z) + shv.z;
    const float r3 = av.w * rs * wv.w * (1.f + scv.w) + shv.w;
    uint2 o;
    o.x = (uint32_t)f2b(r0) | ((uint32_t)f2b(r1) << 16);
    o.y = (uint32_t)f2b(r2) | ((uint32_t)f2b(r3) << 16);
    xo[idx] = o;
  };
  proc(a, tid);
  if (tid < 32) proc(a2, 256 + tid);
}

// ---------------- spatial attention + fused qk-RMS: block=(bt,h), 4 waves x 64 queries ----------------
// K-RMS fused into staging: 4 threads/row read K/V global, RMS in-register (2 shfl),
// write normalized Ks + scatter V -> no separate LDS RMW pass, 2 barriers per c-iter.
#define AK_STRIDE 104
#define VT_STRIDE 88
#define PS_STRIDE 72
__global__ __launch_bounds__(256) void attn_s_k(
    const uint16_t* __restrict__ qkv, uint16_t* __restrict__ out,
    const float* __restrict__ qn, const float* __restrict__ kn)
{
  __shared__ __align__(16) uint16_t Ks[64 * AK_STRIDE];
  __shared__ __align__(16) uint16_t Vt[80 * VT_STRIDE];
  __shared__ __align__(16) uint16_t Ps[4 * 64 * PS_STRIDE];
  const int bh = blockIdx.x;
  const int bt = bh >> 4, h = bh & 15;
  const int tid = threadIdx.x;
  const int lane = tid & 63, wave = tid >> 6;
  const int l15 = lane & 15, quad = lane >> 4;
  const size_t rowbase = (size_t)bt * 256;
  const float scale = 0.1178511301977579f;  // 1/sqrt(72)

  union { uint4 u; bf16x8 v; } zu; zu.u = make_uint4(0, 0, 0, 0);
  const bf16x8 zero8 = zu.v;

  // per-lane qn weights for Q fragment slots
  float qw0[8], qw1[8], qw2[8];
#pragma unroll
  for (int j = 0; j < 8; j++) {
    qw0[j] = qn[quad * 8 + j];
    qw1[j] = qn[32 + quad * 8 + j];
    qw2[j] = (quad == 0) ? qn[64 + j] : 0.f;
  }
  // kn weights for this thread's staging slots: cc = p, p+4, (p==0: 8)
  const int sp = tid & 3;       // part within row
  const int srow = tid >> 2;    // staged row [0,64)
  float kw0[8], kw1[8], kw2[8];
#pragma unroll
  for (int j = 0; j < 8; j++) {
    kw0[j] = kn[sp * 8 + j];
    kw1[j] = kn[(sp + 4) * 8 + j];
    kw2[j] = (sp == 0) ? kn[64 + j] : 0.f;
  }

  // Q load + fused per-head RMS (row spread across 4 quads; shfl-reduce)
  bf16x8 qf[4][3];
#pragma unroll
  for (int mi = 0; mi < 4; mi++) {
    const uint16_t* qp = qkv + (rowbase + wave * 64 + mi * 16 + l15) * 3456 + h * 72;
    float f0[8], f1[8], f2[8];
    unpack8(((const uint4*)qp)[quad], f0);
    unpack8(((const uint4*)qp)[4 + quad], f1);
    uint4 u2 = (quad == 0) ? ((const uint4*)qp)[8] : make_uint4(0, 0, 0, 0);
    unpack8(u2, f2);
    float ss = 0.f;
#pragma unroll
    for (int j = 0; j < 8; j++) ss += f0[j] * f0[j] + f1[j] * f1[j] + f2[j] * f2[j];
    ss += __shfl_xor(ss, 16);
    ss += __shfl_xor(ss, 32);
    const float rs = rsqrtf(ss * (1.f / 72.f) + 1e-6f);
#pragma unroll
    for (int j = 0; j < 8; j++) {
      f0[j] *= rs * qw0[j];
      f1[j] *= rs * qw1[j];
      f2[j] *= rs * qw2[j];
    }
    qf[mi][0] = pack8(f0);
    qf[mi][1] = pack8(f1);
    qf[mi][2] = (quad == 0) ? pack8(f2) : zero8;
  }

  f32x4 oacc[4][5];
#pragma unroll
  for (int mi = 0; mi < 4; mi++)
#pragma unroll
    for (int dt = 0; dt < 5; dt++)
      oacc[mi][dt] = (f32x4){0.f, 0.f, 0.f, 0.f};
  float mrun[4][4], lrun[4][4];
#pragma unroll
  for (int mi = 0; mi < 4; mi++)
#pragma unroll
    for (int i = 0; i < 4; i++) { mrun[mi][i] = -1e30f; lrun[mi][i] = 0.f; }

  uint16_t* psw = &Ps[wave * 64 * PS_STRIDE];

  for (int c = 0; c < 4; c++) {
    __syncthreads();
    {
      // stage + K-RMS fused: thread (srow, sp) owns uint4 slots {sp, sp+4, [8 if sp==0]}
      const uint16_t* kg = qkv + (rowbase + c * 64 + srow) * 3456 + 1152 + h * 72;
      uint4 ku0 = ((const uint4*)kg)[sp];
      uint4 ku1 = ((const uint4*)kg)[sp + 4];
      uint4 ku2 = (sp == 0) ? ((const uint4*)kg)[8] : make_uint4(0, 0, 0, 0);
      float k0[8], k1[8], k2[8];
      unpack8(ku0, k0); unpack8(ku1, k1); unpack8(ku2, k2);
      float ss = 0.f;
#pragma unroll
      for (int j = 0; j < 8; j++) ss += k0[j] * k0[j] + k1[j] * k1[j] + k2[j] * k2[j];
      ss += __shfl_xor(ss, 1);
      ss += __shfl_xor(ss, 2);
      const float rs = rsqrtf(ss * (1.f / 72.f) + 1e-6f);
#pragma unroll
      for (int j = 0; j < 8; j++) {
        k0[j] *= rs * kw0[j];
        k1[j] *= rs * kw1[j];
        k2[j] *= rs * kw2[j];
      }
      *(uint4*)&Ks[srow * AK_STRIDE + sp * 8] = pack8u(k0);
      *(uint4*)&Ks[srow * AK_STRIDE + (sp + 4) * 8] = pack8u(k1);
      if (sp == 0) *(uint4*)&Ks[srow * AK_STRIDE + 64] = pack8u(k2);

      // V: same ownership, raw bf16 scatter into Vt (transpose)
      const uint16_t* vg = kg + 1152;
      uint4 v0 = ((const uint4*)vg)[sp];
      uint4 v1 = ((const uint4*)vg)[sp + 4];
      const uint16_t* e0 = (const uint16_t*)&v0;
      const uint16_t* e1 = (const uint16_t*)&v1;
#pragma unroll
      for (int j = 0; j < 8; j++) Vt[(sp * 8 + j) * VT_STRIDE + srow] = e0[j];
#pragma unroll
      for (int j = 0; j < 8; j++) Vt[((sp + 4) * 8 + j) * VT_STRIDE + srow] = e1[j];
      if (sp == 0) {
        uint4 v2 = ((const uint4*)vg)[8];
        const uint16_t* e2 = (const uint16_t*)&v2;
#pragma unroll
        for (int j = 0; j < 8; j++) Vt[(64 + j) * VT_STRIDE + srow] = e2[j];
      }
    }
    __syncthreads();

    f32x4 s[4][4];
#pragma unroll
    for (int mi = 0; mi < 4; mi++)
#pragma unroll
      for (int ni = 0; ni < 4; ni++)
        s[mi][ni] = (f32x4){0.f, 0.f, 0.f, 0.f};
#pragma unroll
    for (int ni = 0; ni < 4; ni++) {
      bf16x8 kf0 = *(const bf16x8*)&Ks[(ni * 16 + l15) * AK_STRIDE + quad * 8];
      bf16x8 kf1 = *(const bf16x8*)&Ks[(ni * 16 + l15) * AK_STRIDE + 32 + quad * 8];
      bf16x8 kf2 = (quad == 0) ? *(const bf16x8*)&Ks[(ni * 16 + l15) * AK_STRIDE + 64] : zero8;
#pragma unroll
      for (int mi = 0; mi < 4; mi++) {
        s[mi][ni] = __builtin_amdgcn_mfma_f32_16x16x32_bf16(qf[mi][0], kf0, s[mi][ni], 0, 0, 0);
        s[mi][ni] = __builtin_amdgcn_mfma_f32_16x16x32_bf16(qf[mi][1], kf1, s[mi][ni], 0, 0, 0);
        s[mi][ni] = __builtin_amdgcn_mfma_f32_16x16x32_bf16(qf[mi][2], kf2, s[mi][ni], 0, 0, 0);
      }
    }

#pragma unroll
    for (int mi = 0; mi < 4; mi++) {
#pragma unroll
      for (int i = 0; i < 4; i++) {
        float mx = fmaxf(fmaxf(s[mi][0][i], s[mi][1][i]), fmaxf(s[mi][2][i], s[mi][3][i])) * scale;
#pragma unroll
        for (int d = 1; d < 16; d <<= 1) mx = fmaxf(mx, __shfl_xor(mx, d));
        const float mnew = fmaxf(mrun[mi][i], mx);
        const float corr = __expf(mrun[mi][i] - mnew);
        mrun[mi][i] = mnew;
        float psum = 0.f;
#pragma unroll
        for (int ni = 0; ni < 4; ni++) {
          const float p = __expf(s[mi][ni][i] * scale - mnew);
          s[mi][ni][i] = p;
          psum += p;
        }
#pragma unroll
        for (int d = 1; d < 16; d <<= 1) psum += __shfl_xor(psum, d);
        lrun[mi][i] = lrun[mi][i] * corr + psum;
#pragma unroll
        for (int dt = 0; dt < 5; dt++) oacc[mi][dt][i] *= corr;
      }
    }

#pragma unroll
    for (int mi = 0; mi < 4; mi++)
#pragma unroll
      for (int ni = 0; ni < 4; ni++)
#pragma unroll
        for (int i = 0; i < 4; i++)
          psw[(mi * 16 + quad * 4 + i) * PS_STRIDE + ni * 16 + l15] = f2b(s[mi][ni][i]);

#pragma unroll
    for (int kk = 0; kk < 2; kk++) {
      bf16x8 pf[4];
#pragma unroll
      for (int mi = 0; mi < 4; mi++)
        pf[mi] = *(const bf16x8*)&psw[(mi * 16 + l15) * PS_STRIDE + kk * 32 + quad * 8];
#pragma unroll
      for (int dt = 0; dt < 5; dt++) {
        bf16x8 vf = *(const bf16x8*)&Vt[(dt * 16 + l15) * VT_STRIDE + kk * 32 + quad * 8];
#pragma unroll
        for (int mi = 0; mi < 4; mi++)
          oacc[mi][dt] = __builtin_amdgcn_mfma_f32_16x16x32_bf16(pf[mi], vf, oacc[mi][dt], 0, 0, 0);
      }
    }
  }

#pragma unroll
  for (int mi = 0; mi < 4; mi++) {
#pragma unroll
    for (int i = 0; i < 4; i++) {
      const float inv = 1.f / lrun[mi][i];
      const size_t orow = rowbase + wave * 64 + mi * 16 + quad * 4 + i;
#pragma unroll
      for (int dt = 0; dt < 5; dt++) {
        const int d = dt * 16 + l15;
        if (d < 72) out[orow * 1152 + h * 72 + d] = f2b(oacc[mi][dt][i] * inv);
      }
    }
  }
}

// ---------------- temporal attention (T=16) + fused qk-RMS ----------------
__global__ __launch_bounds__(128) void attn_t_k(
    const uint16_t* __restrict__ qkv, uint16_t* __restrict__ out,
    const float* __restrict__ qn, const float* __restrict__ kn)
{
  const int blk = blockIdx.x;
  const int bl = blk >> 1, hg = blk & 1;
  const int b = bl >> 8, l = bl & 255;
  const int tid = threadIdx.x;
  const int hh = tid >> 4, tq = tid & 15;
  const int h = hg * 8 + hh;
  __shared__ __align__(16) uint16_t kb[8 * 16 * 72];
  __shared__ __align__(16) uint16_t vb[8 * 16 * 72];

#pragma unroll
  for (int it = 0; it < 9; it++) {
    const int idx = tid + it * 128;
    const int rowL = idx / 9, cc = idx % 9;
    const int hhL = rowL >> 4, tL = rowL & 15;
    const size_t grow = (size_t)b * 4096 + (size_t)tL * 256 + l;
    const int colk = 1152 + (hg * 8 + hhL) * 72 + cc * 8;
    ((uint4*)&kb[rowL * 72])[cc] = *(const uint4*)(qkv + grow * 3456 + colk);
    ((uint4*)&vb[rowL * 72])[cc] = *(const uint4*)(qkv + grow * 3456 + colk + 1152);
  }
  __syncthreads();

  // fused K per-head RMS: 128 rows, one thread each
  {
    uint16_t* kr = &kb[tid * 72];
    float ss = 0.f;
#pragma unroll
    for (int i = 0; i < 9; i++) {
      float f[8]; unpack8(((const uint4*)kr)[i], f);
#pragma unroll
      for (int j = 0; j < 8; j++) ss += f[j] * f[j];
    }
    const float rs = rsqrtf(ss * (1.f / 72.f) + 1e-6f);
#pragma unroll
    for (int i = 0; i < 9; i++) {
      float f[8]; unpack8(((const uint4*)kr)[i], f);
#pragma unroll
      for (int j = 0; j < 8; j++) f[j] *= rs * kn[i * 8 + j];
      ((uint4*)kr)[i] = pack8u(f);
    }
  }
  __syncthreads();

  float q[72];
  const size_t qrow = (size_t)b * 4096 + (size_t)tq * 256 + l;
  {
    const uint16_t* qp = qkv + qrow * 3456 + h * 72;
#pragma unroll
    for (int i = 0; i < 9; i++) unpack8(((const uint4*)qp)[i], q + i * 8);
    float ssq = 0.f;
#pragma unroll
    for (int d = 0; d < 72; d++) ssq += q[d] * q[d];
    const float rsq = rsqrtf(ssq * (1.f / 72.f) + 1e-6f);
#pragma unroll
    for (int d = 0; d < 72; d++) q[d] *= rsq * qn[d];
  }
  const float scale = 0.1178511301977579f;
  float s[16];
#pragma unroll
  for (int m = 0; m < 16; m++) {
    const uint4* kr = (const uint4*)&kb[(hh * 16 + m) * 72];
    float a = 0.f;
#pragma unroll
    for (int i = 0; i < 9; i++) {
      float kf[8]; unpack8(kr[i], kf);
#pragma unroll
      for (int j = 0; j < 8; j++) a += q[i * 8 + j] * kf[j];
    }
    s[m] = a * scale;
  }
  float mx = -1e30f;
#pragma unroll
  for (int m = 0; m < 16; m++) mx = fmaxf(mx, s[m]);
  float sum = 0.f;
#pragma unroll
  for (int m = 0; m < 16; m++) { s[m] = __expf(s[m] - mx); sum += s[m]; }
  const float inv = 1.f / sum;
  float o[72];
#pragma unroll
  for (int d = 0; d < 72; d++) o[d] = 0.f;
#pragma unroll
  for (int m = 0; m < 16; m++) {
    const float p = s[m];
    const uint4* vr = (const uint4*)&vb[(hh * 16 + m) * 72];
#pragma unroll
    for (int i = 0; i < 9; i++) {
      float vf[8]; unpack8(vr[i], vf);
#pragma unroll
      for (int j = 0; j < 8; j++) o[i * 8 + j] += p * vf[j];
    }
  }
  uint16_t* op = out + qrow * 1152 + h * 72;
#pragma unroll
  for (int d = 0; d < 72; d++) op[d] = f2b(o[d] * inv);
}

// ---------------- transpose + fp32->bf16: in(KxN) -> out(NxK), dual via blockIdx.z ----
__global__ __launch_bounds__(256) void transcvt2_k(
    const float* __restrict__ inA, uint16_t* __restrict__ outA,
    const float* __restrict__ inB, uint16_t* __restrict__ outB,
    int K, int N)
{
  const float* in = blockIdx.z ? inB : inA;
  uint16_t* out = blockIdx.z ? outB : outA;
  __shared__ float t[32][33];
  const int n0 = blockIdx.x * 32, k0 = blockIdx.y * 32;
  const int tx = threadIdx.x & 31, ty = threadIdx.x >> 5;
#pragma unroll
  for (int i = 0; i < 32; i += 8)
    t[ty + i][tx] = in[(size_t)(k0 + ty + i) * N + n0 + tx];
  __syncthreads();
#pragma unroll
  for (int i = 0; i < 32; i += 8)
    out[(size_t)(n0 + ty + i) * K + k0 + tx] = f2b(t[tx][ty + i]);
}

__global__ __launch_bounds__(256) void transcvt_k(
    const float* __restrict__ in, uint16_t* __restrict__ out, int K, int N)
{
  __shared__ float t[32][33];
  const int n0 = blockIdx.x * 32, k0 = blockIdx.y * 32;
  const int tx = threadIdx.x & 31, ty = threadIdx.x >> 5;
#pragma unroll
  for (int i = 0; i < 32; i += 8)
    t[ty + i][tx] = in[(size_t)(k0 + ty + i) * N + n0 + tx];
  __syncthreads();
#pragma unroll
  for (int i = 0; i < 32; i += 8)
    out[(size_t)(n0 + ty + i) * K + k0 + tx] = f2b(t[tx][ty + i]);
}

// ---------------- transpose + cvt + x1/x2 group-interleave for W12 ----------------
// out row n <- source col s(n) = ((n&32)?3072:0) + (n>>6)*32 + (n&31).
__global__ __launch_bounds__(256) void transcvt_w12i_k(
    const float* __restrict__ in, uint16_t* __restrict__ out)
{
  __shared__ float t[32][33];
  const int n0 = blockIdx.x * 32, k0 = blockIdx.y * 32;
  const int tx = threadIdx.x & 31, ty = threadIdx.x >> 5;
  const int scol = ((n0 & 32) ? 3072 : 0) + ((n0 >> 6) << 5) + tx;
#pragma unroll
  for (int i = 0; i < 32; i += 8)
    t[ty + i][tx] = in[(size_t)(k0 + ty + i) * 6144 + scol];
  __syncthreads();
#pragma unroll
  for (int i = 0; i < 32; i += 8)
    out[(size_t)(n0 + ty + i) * 1152 + k0 + tx] = f2b(t[tx][ty + i]);
}

// ---------------- ada path (silu fused into part stage-1) ----------------
#define ADA_KS 18
#define ADA_RK 64
__global__ __launch_bounds__(256) void ada_part_k(
    const float* __restrict__ c, const float* __restrict__ W,
    float* __restrict__ part)
{
  const int col = blockIdx.x * 256 + threadIdx.x;
  const int ks = blockIdx.y;
  const int k0 = ks * ADA_RK;
  __shared__ float sc0[ADA_RK], sc1[ADA_RK];
  if (threadIdx.x < ADA_RK) {
    const float v = c[k0 + threadIdx.x];
    sc0[threadIdx.x] = v / (1.f + __expf(-v));
  } else if (threadIdx.x < 2 * ADA_RK) {
    const float v = c[1152 + k0 + threadIdx.x - ADA_RK];
    sc1[threadIdx.x - ADA_RK] = v / (1.f + __expf(-v));
  }
  __syncthreads();
  if (col >= 10368) return;
  const float* Wp = W + (size_t)k0 * 10368 + col;
  float s0 = 0.f, s1 = 0.f;
#pragma unroll 8
  for (int r = 0; r < ADA_RK; r++) {
    const float wv = Wp[(size_t)r * 10368];
    s0 += sc0[r] * wv;
    s1 += sc1[r] * wv;
  }
  part[(size_t)(ks * 2 + 0) * 10368 + col] = s0;
  part[(size_t)(ks * 2 + 1) * 10368 + col] = s1;
}

__global__ __launch_bounds__(256) void ada_reduce_k(
    const float* __restrict__ part, const float* __restrict__ bias,
    float* __restrict__ chv)
{
  const int col = blockIdx.x * 256 + threadIdx.x;
  if (col >= 10368) return;
  float s0 = bias[col], s1 = bias[col];
#pragma unroll
  for (int ks = 0; ks < ADA_KS; ks++) {
    s0 += part[(size_t)(ks * 2 + 0) * 10368 + col];
    s1 += part[(size_t)(ks * 2 + 1) * 10368 + col];
  }
  chv[col] = s0;
  chv[10368 + col] = s1;
}

extern "C" void kernel_launch(void* const* d_in, const int* in_sizes, int n_in,
                              void* d_out, int out_size, void* d_ws, size_t ws_size,
                              hipStream_t stream)
{
  const float* Xin     = (const float*)d_in[0];
  const float* c_in    = (const float*)d_in[1];
  const float* norm1w  = (const float*)d_in[2];
  const float* norm2w  = (const float*)d_in[3];
  const float* norm3w  = (const float*)d_in[4];
  const float* qn_s    = (const float*)d_in[5];
  const float* kn_s    = (const float*)d_in[6];
  const float* qkv_s_w = (const float*)d_in[7];
  const float* qkv_s_b = (const float*)d_in[8];
  const float* proj_s_w= (const float*)d_in[9];
  const float* proj_s_b= (const float*)d_in[10];
  const float* qn_t    = (const float*)d_in[11];
  const float* kn_t    = (const float*)d_in[12];
  const float* qkv_t_w = (const float*)d_in[13];
  const float* qkv_t_b = (const float*)d_in[14];
  const float* proj_t_w= (const float*)d_in[15];
  const float* proj_t_b= (const float*)d_in[16];
  const float* w12_w   = (const float*)d_in[17];
  const float* w12_b   = (const float*)d_in[18];
  const float* w3_w    = (const float*)d_in[19];
  const float* w3_b    = (const float*)d_in[20];
  const float* ada_w   = (const float*)d_in[21];
  const float* ada_b   = (const float*)d_in[22];

  float* X = (float*)d_out;  // fp32 residual accumulator; first written by proj_s

  char* wsb = (char*)d_ws; size_t off = 0;
  auto alloc = [&](size_t bytes) -> void* {
    void* p = wsb + off; off += bytes; off = (off + 255) & ~(size_t)255; return p;
  };
  uint16_t* XN    = (uint16_t*)alloc((size_t)8192 * 1152 * 2);  // xn / attn_out
  uint16_t* QKV   = (uint16_t*)alloc((size_t)8192 * 3456 * 2);  // qkv; later reused as H (8192x3072)
  uint16_t* H     = QKV;
  uint16_t* WqkvS = (uint16_t*)alloc((size_t)3584 * 1152 * 2);  // padded to 14*256 rows
  uint16_t* WprojS= (uint16_t*)alloc((size_t)1152 * 1152 * 2);
  uint16_t* WqkvT = (uint16_t*)alloc((size_t)3584 * 1152 * 2);  // padded to 14*256 rows
  uint16_t* WprojT= (uint16_t*)alloc((size_t)1152 * 1152 * 2);
  uint16_t* W12T  = (uint16_t*)alloc((size_t)6144 * 1152 * 2);  // group-interleaved x1/x2
  uint16_t* W3T   = (uint16_t*)alloc((size_t)1152 * 3072 * 2);
  float* CH = (float*)alloc((size_t)2 * 10368 * 4);
  float* APART = (float*)alloc((size_t)ADA_KS * 2 * 10368 * 4);

  ada_part_k<<<dim3(41, ADA_KS), 256, 0, stream>>>(c_in, ada_w, APART);
  ada_reduce_k<<<41, 256, 0, stream>>>(APART, ada_b, CH);

  transcvt2_k<<<dim3(3456 / 32, 1152 / 32, 2), 256, 0, stream>>>(qkv_s_w, WqkvS, qkv_t_w, WqkvT,
                                                                 1152, 3456);
  transcvt2_k<<<dim3(1152 / 32, 1152 / 32, 2), 256, 0, stream>>>(proj_s_w, WprojS, proj_t_w, WprojT,
                                                                 1152, 1152);
  transcvt_w12i_k<<<dim3(6144 / 32, 1152 / 32), 256, 0, stream>>>(w12_w, W12T);
  transcvt_k<<<dim3(1152 / 32, 3072 / 32), 256, 0, stream>>>(w3_w, W3T, 3072, 1152);

  // ---- spatial attention ----
  rmsnorm_k<<<8192, 256, 0, stream>>>(Xin, norm1w, CH, 0, 1, XN);
  gemm256_k<<<32 * 14, 512, 0, stream>>>(XN, 1152, WqkvS, qkv_s_b, QKV, 3456, 1152);
  attn_s_k<<<512, 256, 0, stream>>>(QKV, XN, qn_s, kn_s);
  gemm_k<<<9 * 64, 256, 0, stream>>>(XN, 1152, WprojS, proj_s_b, nullptr, X, Xin, CH + 2 * 1152,
                                     1152, 1152, 1);

  // ---- temporal attention ----
  rmsnorm_k<<<8192, 256, 0, stream>>>(X, norm2w, CH, 3, 4, XN);
  gemm256_k<<<32 * 14, 512, 0, stream>>>(XN, 1152, WqkvT, qkv_t_b, QKV, 3456, 1152);
  attn_t_k<<<1024, 128, 0, stream>>>(QKV, XN, qn_t, kn_t);
  gemm_k<<<9 * 64, 256, 0, stream>>>(XN, 1152, WprojT, proj_t_b, nullptr, X, X, CH + 5 * 1152,
                                     1152, 1152, 1);

  // ---- MLP: fused w12+swiglu (H = silu(x1)*x2, 8192x3072), then w3 ----
  rmsnorm_k<<<8192, 256, 0, stream>>>(X, norm3w, CH, 6, 7, XN);
  gemm256_sw_k<<<32 * 24, 512, 0, stream>>>(XN, 1152, W12T, w12_b, H, 1152);
  gemm_k<<<9 * 64, 256, 0, stream>>>(H, 3072, W3T, w3_b, nullptr, X, X, CH + 8 * 1152,
                                     1152, 3072, 1);
}